// Round 1
// baseline (1432.452 us; speedup 1.0000x reference)
//
#include <hip/hip_runtime.h>
#include <cstdint>
#include <cstddef>

// ---------------------------------------------------------------------------
// GNS model. R16 = R11 + software-pipelined epilogue gathers in k_edge.
// Confirmed design points (14 rounds of A/B evidence):
//  - k_edge: 128-edge tiles, lb(256,3)=3 blocks/CU. The blocks/CU curve is
//    monotone in L2 thrash (lb3: F68/W18 MB; lb4: F130/W120; lb5: F228/W283)
//    -> 3 blocks/CU is the latency-vs-L2-capacity optimum for random gathers.
//  - P hoisted once per dst-run (+bvec folded); permuted-column C layout so a
//    lane's 8 C-cols are contiguous (weight slots: tile nt <-> cols {p*8+nt}).
//  - LDS S-tile with interior plain stores + boundary atomics (no global
//    atomic storm); edges counting-sorted by dst on device.
//  - Node side: fused S@Wtil + h@Wn1a -> V -> h += V@ln_w2 -> P/Q of next
//    layer, one kernel, wave-private LDS (zero barriers), 128-thr/32-row
//    tiles; k_svu re-zeroes consumed S rows (single memset total).
//  - All GEMMs split-bf16 MFMA (AhBh+AlBh+AhBl), edge-U hi-only.
// R16 change (theory: k_edge is MLP-starved, ~3 outstanding misses/CU):
//  - indices for all 8 lane-edges preloaded before the barrier (latency free);
//  - Q rows for edges 0-3 + first P row prefetched into regs right after the
//    barrier (latency hides under staging VALU + MFMA GEMM);
//  - epilogue fused into one 8-edge run-reduce (runs carry across the former
//    mt halves -> fewer flushes/P-loads); after consuming q[r] it reissues
//    q[r] <- Q[src[r+4]] (rotating 32-reg buffer, 4-deep pipeline).
//  - blocks/CU, LDS layout, access footprint unchanged vs R11.
// ---------------------------------------------------------------------------

#define DEVI static __device__ __forceinline__

typedef __bf16 bf16_t;
typedef bf16_t bf16x8 __attribute__((ext_vector_type(8)));
typedef bf16_t bf16x4 __attribute__((ext_vector_type(4)));
typedef float f32x4v __attribute__((ext_vector_type(4)));

DEVI float4 ld4(const float* p) { return *(const float4*)p; }
DEVI void st4(float* p, float4 v) { *(float4*)p = v; }
DEVI float prelu1(float z, float a) { return z > 0.f ? z : a * z; }
DEVI void atomicAddF(float* p, float v) {
  __hip_atomic_fetch_add(p, v, __ATOMIC_RELAXED, __HIP_MEMORY_SCOPE_AGENT);
}
DEVI f32x4v mfma_bf16(bf16x8 a, bf16x8 b, f32x4v c) {
  return __builtin_amdgcn_mfma_f32_16x16x32_bf16(a, b, c, 0, 0, 0);
}
DEVI void mfma3(f32x4v& acc, bf16x8 ah, bf16x8 al, bf16x8 bh, bf16x8 bl) {
  acc = mfma_bf16(ah, bh, acc);
  acc = mfma_bf16(al, bh, acc);
  acc = mfma_bf16(ah, bl, acc);
}
DEVI void split2(float x, bf16_t& h, bf16_t& l) {
  h = (bf16_t)x;
  l = (bf16_t)(x - (float)h);
}
DEVI bf16x8 ldb8(const bf16_t* p) { return *(const bf16x8*)p; }

#define NST 136   // node staging row stride (bf16)
#define EST 72    // edge staging row stride (bf16)

// ============ node building blocks (wave-local; blocks may be 2 waves) ======

DEVI void stage_f32(const float* __restrict__ src, int row0, int M,
                    int lane, int wave, bf16_t* SAh, bf16_t* SAl)
{
  const int row = wave * 16 + (lane >> 2);
  const int grow = row0 + row;
  const int colbase = (lane & 3) * 32;
  #pragma unroll
  for (int j = 0; j < 8; ++j) {
    int kc = colbase + j * 4;
    float4 v = make_float4(0.f, 0.f, 0.f, 0.f);
    if (grow < M) v = ld4(src + (size_t)grow * 128 + kc);
    bf16_t h0,l0,h1,l1,h2,l2,h3,l3;
    split2(v.x,h0,l0); split2(v.y,h1,l1); split2(v.z,h2,l2); split2(v.w,h3,l3);
    *(bf16x4*)(SAh + row * NST + kc) = (bf16x4){h0,h1,h2,h3};
    *(bf16x4*)(SAl + row * NST + kc) = (bf16x4){l0,l1,l2,l3};
  }
}

DEVI void stage_planes(const bf16_t* __restrict__ gh, const bf16_t* __restrict__ gl,
                       int row0, int M, int lane, int wave,
                       bf16_t* SAh, bf16_t* SAl)
{
  const int row = wave * 16 + (lane >> 2);
  const int grow = row0 + row;
  const int colbase = (lane & 3) * 32;
  #pragma unroll
  for (int j = 0; j < 4; ++j) {
    int kc = colbase + j * 8;
    bf16x8 vh = {};
    bf16x8 vl = {};
    if (grow < M) {
      vh = ldb8(gh + (size_t)grow * 128 + kc);
      vl = ldb8(gl + (size_t)grow * 128 + kc);
    }
    *(bf16x8*)(SAh + row * NST + kc) = vh;
    *(bf16x8*)(SAl + row * NST + kc) = vl;
  }
}

DEVI void gemm_lds(const bf16_t* SAh, const bf16_t* SAl,
                   const bf16_t* __restrict__ BT, f32x4v acc[8],
                   int wave, int p, int q)
{
  #pragma unroll
  for (int ks = 0; ks < 4; ++ks) {
    const int k0 = ks * 32 + q * 8;
    bf16x8 aH = ldb8(SAh + (wave * 16 + p) * NST + k0);
    bf16x8 aL = ldb8(SAl + (wave * 16 + p) * NST + k0);
    #pragma unroll
    for (int nt = 0; nt < 8; ++nt) {
      const bf16_t* bp = BT + (size_t)(nt * 16 + p) * 128 + k0;
      mfma3(acc[nt], aH, aL, ldb8(bp), ldb8(bp + 16384));
    }
  }
}

DEVI void store_c(float* __restrict__ O, int row0, int M,
                  const f32x4v acc[8], int wave, int p, int q)
{
  int rb = row0 + wave * 16 + q * 4;
  #pragma unroll
  for (int r = 0; r < 4; ++r) {
    if (rb + r < M) {
      float* op = O + (size_t)(rb + r) * 128 + p * 8;
      st4(op,     make_float4(acc[0][r], acc[1][r], acc[2][r], acc[3][r]));
      st4(op + 4, make_float4(acc[4][r], acc[5][r], acc[6][r], acc[7][r]));
    }
  }
}

DEVI void stage_cregs(const f32x4v acc[8], int wave, int p, int q,
                      bf16_t* SAh, bf16_t* SAl)
{
  #pragma unroll
  for (int r = 0; r < 4; ++r) {
    int row = wave * 16 + q * 4 + r;
    bf16x8 vh, vl;
    #pragma unroll
    for (int nt = 0; nt < 8; ++nt) {
      bf16_t hb, lb;
      split2(acc[nt][r], hb, lb);
      vh[nt] = hb; vl[nt] = lb;
    }
    *(bf16x8*)(SAh + row * NST + p * 8) = vh;
    *(bf16x8*)(SAl + row * NST + p * 8) = vl;
  }
}

DEVI void planes_out(bf16_t* __restrict__ gh, bf16_t* __restrict__ gl,
                     int row0, int M, int lane, int wave,
                     const bf16_t* SAh, const bf16_t* SAl)
{
  const int row = wave * 16 + (lane >> 2);
  const int grow = row0 + row;
  const int colbase = (lane & 3) * 32;
  if (grow < M) {
    #pragma unroll
    for (int j = 0; j < 4; ++j) {
      int kc = colbase + j * 8;
      *(bf16x8*)(gh + (size_t)grow * 128 + kc) = *(const bf16x8*)(SAh + row * NST + kc);
      *(bf16x8*)(gl + (size_t)grow * 128 + kc) = *(const bf16x8*)(SAl + row * NST + kc);
    }
  }
}

DEVI void ld8f(float dst[8], const float* __restrict__ src, int p) {
  *(float4*)(dst)     = ld4(src + p * 8);
  *(float4*)(dst + 4) = ld4(src + p * 8 + 4);
}

// ---------------------------------------------------------------------------
// k_svu: 128 thr / 32-row tiles. Node update + P/Q for next layer; zeroes
// consumed S rows (keeps Sb zeroed for next layer's k_edge).
// ---------------------------------------------------------------------------
__global__ __launch_bounds__(128, 2) void k_svu(
    float* Sbuf,                      // read then zeroed (same buffer)
    bf16_t* __restrict__ hSh, bf16_t* __restrict__ hSl,
    const bf16_t* __restrict__ WtilT, const bf16_t* __restrict__ Wn1aT,
    const bf16_t* __restrict__ lnw2T, const bf16_t* __restrict__ W1nextT,
    const float* __restrict__ ln_b1_l, const float* __restrict__ btil_l,
    const int* __restrict__ deg, const float* __restrict__ ln_a_l,
    const float* __restrict__ ln_b2_l,
    float* __restrict__ P, float* __restrict__ Q, int doPQ, int M)
{
  __shared__ __align__(16) bf16_t SAh[32 * NST];
  __shared__ __align__(16) bf16_t SAl[32 * NST];
  const int t = threadIdx.x, lane = t & 63, wave = t >> 6;
  const int p = lane & 15, q = lane >> 4;
  const int row0 = blockIdx.x * 32;

  f32x4v acc1[8];
  #pragma unroll
  for (int j = 0; j < 8; ++j) acc1[j] = (f32x4v){0.f, 0.f, 0.f, 0.f};

  stage_f32(Sbuf, row0, M, lane, wave, SAh, SAl);
  // zero consumed S rows (per-lane same addresses as the loads -> ordered)
  {
    const int row = wave * 16 + (lane >> 2);
    const int grow = row0 + row;
    const int colbase = (lane & 3) * 32;
    if (grow < M) {
      float4 z4 = make_float4(0.f, 0.f, 0.f, 0.f);
      #pragma unroll
      for (int j = 0; j < 8; ++j)
        st4(Sbuf + (size_t)grow * 128 + colbase + j * 4, z4);
    }
  }
  gemm_lds(SAh, SAl, WtilT, acc1, wave, p, q);
  stage_planes(hSh, hSl, row0, M, lane, wave, SAh, SAl);
  gemm_lds(SAh, SAl, Wn1aT, acc1, wave, p, q);

  // h_old in (permuted) C layout from LDS — vectorized bf16x8 reads
  float hold[8][4];
  #pragma unroll
  for (int r = 0; r < 4; ++r) {
    int row = wave * 16 + q * 4 + r;
    bf16x8 vh = *(const bf16x8*)(SAh + row * NST + p * 8);
    bf16x8 vl = *(const bf16x8*)(SAl + row * NST + p * 8);
    #pragma unroll
    for (int nt = 0; nt < 8; ++nt)
      hold[nt][r] = (float)vh[nt] + (float)vl[nt];
  }
  // V = prelu(acc1 + b1 + deg*btil)
  const float alpha = *ln_a_l;
  float degf[4];
  #pragma unroll
  for (int r = 0; r < 4; ++r) {
    int row = row0 + wave * 16 + q * 4 + r;
    degf[r] = (row < M) ? (float)deg[row] : 0.f;
  }
  float b1c[8], btc[8];
  ld8f(b1c, ln_b1_l, p);
  ld8f(btc, btil_l, p);
  #pragma unroll
  for (int nt = 0; nt < 8; ++nt)
    #pragma unroll
    for (int r = 0; r < 4; ++r)
      acc1[nt][r] = prelu1(acc1[nt][r] + b1c[nt] + degf[r] * btc[nt], alpha);

  stage_cregs(acc1, wave, p, q, SAh, SAl);   // V
  f32x4v acc2[8];
  #pragma unroll
  for (int j = 0; j < 8; ++j) acc2[j] = (f32x4v){0.f, 0.f, 0.f, 0.f};
  gemm_lds(SAh, SAl, lnw2T, acc2, wave, p, q);
  // h_new = h_old + acc2 + b2
  float b2c[8];
  ld8f(b2c, ln_b2_l, p);
  #pragma unroll
  for (int nt = 0; nt < 8; ++nt)
    #pragma unroll
    for (int r = 0; r < 4; ++r)
      acc2[nt][r] = hold[nt][r] + acc2[nt][r] + b2c[nt];

  stage_cregs(acc2, wave, p, q, SAh, SAl);   // h_new
  planes_out(hSh, hSl, row0, M, lane, wave, SAh, SAl);

  if (doPQ) {
    f32x4v acc3[8];
    #pragma unroll
    for (int j = 0; j < 8; ++j) acc3[j] = (f32x4v){0.f, 0.f, 0.f, 0.f};
    gemm_lds(SAh, SAl, W1nextT, acc3, wave, p, q);
    store_c(P, row0, M, acc3, wave, p, q);
    #pragma unroll
    for (int j = 0; j < 8; ++j) acc3[j] = (f32x4v){0.f, 0.f, 0.f, 0.f};
    gemm_lds(SAh, SAl, W1nextT + 32768, acc3, wave, p, q);
    store_c(Q, row0, M, acc3, wave, p, q);
  }
}

// ---------------------------------------------------------------------------
// k_enc: 128 thr / 32-row tiles. h0 = UN@ne_w2 + b2 -> planes; + P/Q layer 0.
// ---------------------------------------------------------------------------
__global__ __launch_bounds__(128, 2) void k_enc(
    const float* __restrict__ UN, const bf16_t* __restrict__ new2T,
    const float* __restrict__ b2, const bf16_t* __restrict__ W1T0,
    bf16_t* __restrict__ hSh, bf16_t* __restrict__ hSl,
    float* __restrict__ P, float* __restrict__ Q, int M)
{
  __shared__ __align__(16) bf16_t SAh[32 * NST];
  __shared__ __align__(16) bf16_t SAl[32 * NST];
  const int t = threadIdx.x, lane = t & 63, wave = t >> 6;
  const int p = lane & 15, q = lane >> 4;
  const int row0 = blockIdx.x * 32;

  f32x4v acc[8];
  #pragma unroll
  for (int j = 0; j < 8; ++j) acc[j] = (f32x4v){0.f, 0.f, 0.f, 0.f};
  stage_f32(UN, row0, M, lane, wave, SAh, SAl);
  gemm_lds(SAh, SAl, new2T, acc, wave, p, q);
  float b2c[8];
  ld8f(b2c, b2, p);
  #pragma unroll
  for (int nt = 0; nt < 8; ++nt)
    #pragma unroll
    for (int r = 0; r < 4; ++r) acc[nt][r] += b2c[nt];
  stage_cregs(acc, wave, p, q, SAh, SAl);
  planes_out(hSh, hSl, row0, M, lane, wave, SAh, SAl);

  f32x4v acc3[8];
  #pragma unroll
  for (int j = 0; j < 8; ++j) acc3[j] = (f32x4v){0.f, 0.f, 0.f, 0.f};
  gemm_lds(SAh, SAl, W1T0, acc3, wave, p, q);
  store_c(P, row0, M, acc3, wave, p, q);
  #pragma unroll
  for (int j = 0; j < 8; ++j) acc3[j] = (f32x4v){0.f, 0.f, 0.f, 0.f};
  gemm_lds(SAh, SAl, W1T0 + 32768, acc3, wave, p, q);
  store_c(Q, row0, M, acc3, wave, p, q);
}

// ---------------------------------------------------------------------------
// k_edge: 128-edge tiles, lb(256,3), 32-row LDS S-tile, pipelined gathers.
// ---------------------------------------------------------------------------
__global__ __launch_bounds__(256, 3) void k_edge(
    const float* __restrict__ sEa, const int* __restrict__ sSrc,
    const int* __restrict__ sDst,
    const int* __restrict__ rowStart, const int* __restrict__ deg,
    const float* __restrict__ ee_w1, const float* __restrict__ ee_b1,
    const float* __restrict__ ee_a,
    const bf16_t* __restrict__ WhatT, const float* __restrict__ bvec,
    const float* __restrict__ alpha_ptr,
    const float* __restrict__ P, const float* __restrict__ Q,
    float* __restrict__ S, int N, int E)
{
  __shared__ __align__(16) float Stile[32 * 132];     // 16.9 KB
  __shared__ __align__(16) float ew[640];             // ee_w1 + ee_b1
  __shared__ __align__(16) bf16_t Ast[128 * EST];     // 18.4 KB

  const int t = threadIdx.x, lane = t & 63, wave = t >> 6;
  const int p = lane & 15, q = lane >> 4;
  const int e0 = blockIdx.x * 128;
  const int dstLo = sDst[e0];

  // --- preload all 8 lane-edge index pairs; latency absorbed by the barrier
  const int ebase = e0 + wave * 32 + q * 4;
  int d_[8], s_[8];
  #pragma unroll
  for (int i = 0; i < 8; ++i) {
    int ed = ebase + (i >> 2) * 16 + (i & 3);
    if (ed >= E) ed = E - 1;               // clamp: safe row, masked later
    d_[i] = sDst[ed];
    s_[i] = sSrc[ed];
  }

  for (int i = t; i < 640; i += 256)
    ew[i] = (i < 512) ? ee_w1[i] : ee_b1[i - 512];
  for (int i = t; i < 32 * 132; i += 256) Stile[i] = 0.f;
  __syncthreads();

  // --- prefetch Q rows for edges 0-3 + first P row; latency hides under
  //     staging VALU + MFMA GEMM (issued after the barrier's vmcnt drain)
  float q0v[8], q1v[8], q2v[8], q3v[8], pvf[8];
  ld8f(q0v, Q + (size_t)s_[0] * 128, p);
  ld8f(q1v, Q + (size_t)s_[1] * 128, p);
  ld8f(q2v, Q + (size_t)s_[2] * 128, p);
  ld8f(q3v, Q + (size_t)s_[3] * 128, p);
  ld8f(pvf, P + (size_t)d_[0] * 128, p);

  const float ua = *ee_a;
  const float alpha = *alpha_ptr;
  float bvc[8];
  ld8f(bvc, bvec, p);

  const int srow = wave * 32 + (lane >> 1);
  const int scb = (lane & 1) * 32;
  float4 eav = make_float4(0.f, 0.f, 0.f, 0.f);
  {
    int ed = e0 + srow;
    if (ed < E) eav = ld4(sEa + (size_t)ed * 4);
  }

  f32x4v acc[2][8];
  #pragma unroll
  for (int i = 0; i < 2; ++i)
    #pragma unroll
    for (int j = 0; j < 8; ++j) acc[i][j] = (f32x4v){0.f, 0.f, 0.f, 0.f};

  for (int c = 0; c < 2; ++c) {
    // stage U chunk (bf16-hi only), wave-private rows -> no barrier
    #pragma unroll
    for (int j = 0; j < 8; ++j) {
      int kc = scb + j * 4;
      int kg = c * 64 + kc;
      float4 w0 = ld4(ew + kg);
      float4 w1 = ld4(ew + 128 + kg);
      float4 w2 = ld4(ew + 256 + kg);
      float4 w3 = ld4(ew + 384 + kg);
      float4 bb = ld4(ew + 512 + kg);
      float ux = bb.x, uy = bb.y, uz = bb.z, uw = bb.w;
      ux = fmaf(eav.x, w0.x, ux); uy = fmaf(eav.x, w0.y, uy);
      uz = fmaf(eav.x, w0.z, uz); uw = fmaf(eav.x, w0.w, uw);
      ux = fmaf(eav.y, w1.x, ux); uy = fmaf(eav.y, w1.y, uy);
      uz = fmaf(eav.y, w1.z, uz); uw = fmaf(eav.y, w1.w, uw);
      ux = fmaf(eav.z, w2.x, ux); uy = fmaf(eav.z, w2.y, uy);
      uz = fmaf(eav.z, w2.z, uz); uw = fmaf(eav.z, w2.w, uw);
      ux = fmaf(eav.w, w3.x, ux); uy = fmaf(eav.w, w3.y, uy);
      uz = fmaf(eav.w, w3.z, uz); uw = fmaf(eav.w, w3.w, uw);
      *(bf16x4*)(Ast + srow * EST + kc) = (bf16x4){
          (bf16_t)prelu1(ux, ua), (bf16_t)prelu1(uy, ua),
          (bf16_t)prelu1(uz, ua), (bf16_t)prelu1(uw, ua)};
    }
    #pragma unroll
    for (int ks = 0; ks < 2; ++ks) {
      const int k0 = ks * 32 + q * 8;
      const int kg = c * 64 + k0;
      bf16x8 aH0 = ldb8(Ast + (wave * 32 + p) * EST + k0);
      bf16x8 aH1 = ldb8(Ast + (wave * 32 + 16 + p) * EST + k0);
      #pragma unroll
      for (int nt = 0; nt < 8; ++nt) {
        const bf16_t* bp = WhatT + (size_t)(nt * 16 + p) * 128 + kg;
        bf16x8 bH = ldb8(bp);
        bf16x8 bL = ldb8(bp + 16384);
        acc[0][nt] = mfma_bf16(aH0, bH, acc[0][nt]);
        acc[0][nt] = mfma_bf16(aH0, bL, acc[0][nt]);
        acc[1][nt] = mfma_bf16(aH1, bH, acc[1][nt]);
        acc[1][nt] = mfma_bf16(aH1, bL, acc[1][nt]);
      }
    }
  }

  // --- fused 8-edge run-reduce with 4-deep rotating Q prefetch pipeline.
  //     Runs carry across the former mt halves (same dst is contiguous) ->
  //     fewer flushes + fewer P loads than the 2x4 split.
  float rs[8];
  #pragma unroll
  for (int nt = 0; nt < 8; ++nt) rs[nt] = 0.f;
  int curd = -1;
  float pv[8];

  #define FLUSH_RS()                                                        \
    if (curd >= 0) {                                                        \
      int rr = curd - dstLo;                                                \
      if (rr < 32) {                                                        \
        _Pragma("unroll")                                                   \
        for (int nt = 0; nt < 8; ++nt)                                      \
          atomicAdd(&Stile[rr * 132 + p * 8 + nt], rs[nt]);                 \
      } else {                                                              \
        _Pragma("unroll")                                                   \
        for (int nt = 0; nt < 8; ++nt)                                      \
          atomicAddF(S + (size_t)curd * 128 + p * 8 + nt, rs[nt]);          \
      }                                                                     \
      _Pragma("unroll")                                                     \
      for (int nt = 0; nt < 8; ++nt) rs[nt] = 0.f;                          \
    }

  #define EDGE_STEP(i, QQ, MT, R)                                           \
    if (ebase + (MT) * 16 + (R) < E) {                                      \
      int d = d_[i];                                                        \
      if (d != curd) {                                                      \
        FLUSH_RS();                                                         \
        curd = d;                                                           \
        ld8f(pv, P + (size_t)d * 128, p);                                   \
        _Pragma("unroll")                                                   \
        for (int nt = 0; nt < 8; ++nt) pv[nt] += bvc[nt];                   \
      }                                                                     \
      _Pragma("unroll")                                                     \
      for (int nt = 0; nt < 8; ++nt)                                        \
        rs[nt] += prelu1(acc[MT][nt][R] + pv[nt] + QQ[nt], alpha);          \
    }

  // edge 0 uses the prefetched first-P row (no dependent load at run start)
  if (ebase < E) {
    curd = d_[0];
    #pragma unroll
    for (int nt = 0; nt < 8; ++nt) pv[nt] = pvf[nt] + bvc[nt];
    #pragma unroll
    for (int nt = 0; nt < 8; ++nt)
      rs[nt] += prelu1(acc[0][nt][0] + pv[nt] + q0v[nt], alpha);
  }
  ld8f(q0v, Q + (size_t)s_[4] * 128, p);      // reissue for edge 4
  EDGE_STEP(1, q1v, 0, 1)
  ld8f(q1v, Q + (size_t)s_[5] * 128, p);      // reissue for edge 5
  EDGE_STEP(2, q2v, 0, 2)
  ld8f(q2v, Q + (size_t)s_[6] * 128, p);      // reissue for edge 6
  EDGE_STEP(3, q3v, 0, 3)
  ld8f(q3v, Q + (size_t)s_[7] * 128, p);      // reissue for edge 7
  EDGE_STEP(4, q0v, 1, 0)
  EDGE_STEP(5, q1v, 1, 1)
  EDGE_STEP(6, q2v, 1, 2)
  EDGE_STEP(7, q3v, 1, 3)
  FLUSH_RS();

  #undef EDGE_STEP
  #undef FLUSH_RS

  __syncthreads();

  // writeback: interior rows plain-stored, boundary rows atomic
  const int lastE = (e0 + 127 < E) ? (e0 + 127) : (E - 1);
  const int dstHi = sDst[lastE];
  const int col4 = (t & 31) * 4;
  #pragma unroll
  for (int rr0 = 0; rr0 < 32; rr0 += 8) {
    int rr = rr0 + (t >> 5);
    int d = dstLo + rr;
    if (d <= dstHi && d < N) {
      float4 v = ld4(&Stile[rr * 132 + col4]);
      bool interior = (rowStart[d] >= e0) && (rowStart[d] + deg[d] <= e0 + 128);
      float* sp = S + (size_t)d * 128 + col4;
      if (interior) {
        st4(sp, v);
      } else {
        atomicAddF(sp + 0, v.x); atomicAddF(sp + 1, v.y);
        atomicAddF(sp + 2, v.z); atomicAddF(sp + 3, v.w);
      }
    }
  }
}

// ---------------------------------------------------------------------------
// k_dec: 128 thr / 32-row tiles. out = prelu(h@de_w1+de_b1)@de_w2 + de_b2.
// ---------------------------------------------------------------------------
__global__ __launch_bounds__(128, 4) void k_dec(
    const bf16_t* __restrict__ hSh, const bf16_t* __restrict__ hSl,
    const bf16_t* __restrict__ dw1T,
    const float* __restrict__ de_b1, const float* __restrict__ de_a,
    const float* __restrict__ de_w2, const float* __restrict__ de_b2,
    float* __restrict__ out, int M)
{
  __shared__ __align__(16) float Cs[32][132];
  __shared__ __align__(16) float w2s[384];
  const int t = threadIdx.x, lane = t & 63, wave = t >> 6;
  const int p = lane & 15, q = lane >> 4;
  const int row0 = blockIdx.x * 32;
  for (int i = t; i < 384; i += 128) w2s[i] = de_w2[i];

  f32x4v acc[8];
  #pragma unroll
  for (int j = 0; j < 8; ++j) acc[j] = (f32x4v){0.f, 0.f, 0.f, 0.f};
  const size_t ra = (size_t)(row0 + wave * 16 + p) * 128;
  #pragma unroll
  for (int ks = 0; ks < 4; ++ks) {
    const int k0 = ks * 32 + q * 8;
    bf16x8 aH = ldb8(hSh + ra + k0);
    bf16x8 aL = ldb8(hSl + ra + k0);
    #pragma unroll
    for (int nt = 0; nt < 8; ++nt) {
      const bf16_t* bp = dw1T + (size_t)(nt * 16 + p) * 128 + k0;
      mfma3(acc[nt], aH, aL, ldb8(bp), ldb8(bp + 16384));
    }
  }
  const float alpha = *de_a;
  float b1c[8];
  ld8f(b1c, de_b1, p);
  #pragma unroll
  for (int r = 0; r < 4; ++r) {
    int row = wave * 16 + q * 4 + r;
    float* cp = &Cs[row][p * 8];
    st4(cp, make_float4(prelu1(acc[0][r] + b1c[0], alpha),
                        prelu1(acc[1][r] + b1c[1], alpha),
                        prelu1(acc[2][r] + b1c[2], alpha),
                        prelu1(acc[3][r] + b1c[3], alpha)));
    st4(cp + 4, make_float4(prelu1(acc[4][r] + b1c[4], alpha),
                            prelu1(acc[5][r] + b1c[5], alpha),
                            prelu1(acc[6][r] + b1c[6], alpha),
                            prelu1(acc[7][r] + b1c[7], alpha)));
  }
  __syncthreads();
  if (t < 32) {
    float s0 = de_b2[0], s1 = de_b2[1], s2 = de_b2[2];
    for (int k = 0; k < 128; ++k) {
      float vv = Cs[t][k];
      s0 = fmaf(vv, w2s[k * 3 + 0], s0);
      s1 = fmaf(vv, w2s[k * 3 + 1], s1);
      s2 = fmaf(vv, w2s[k * 3 + 2], s2);
    }
    int row = row0 + t;
    if (row < M) {
      out[(size_t)row * 3 + 0] = s0;
      out[(size_t)row * 3 + 1] = s1;
      out[(size_t)row * 3 + 2] = s2;
    }
  }
}

// --------- weight prep: transpose+split with PERMUTED col mapping -----------
__global__ __launch_bounds__(256) void k_tsplit(
    const float* __restrict__ ne_w2, const float* __restrict__ de_w1,
    const float* __restrict__ le_w1, const float* __restrict__ ln_w1,
    const float* __restrict__ ln_w2, bf16_t* __restrict__ WT)
{
  int jid = blockIdx.x;
  const float* src; int slot;
  if (jid == 0)      { src = ne_w2; slot = 0; }
  else if (jid == 1) { src = de_w1; slot = 1; }
  else {
    int l = (jid - 2) >> 2, wj = (jid - 2) & 3;
    slot = 2 + l * 6 + wj;
    src = (wj == 0) ? le_w1 + (size_t)l * 49152
        : (wj == 1) ? le_w1 + (size_t)l * 49152 + 16384
        : (wj == 2) ? ln_w1 + (size_t)l * 32768
                    : ln_w2 + (size_t)l * 16384;
  }
  bf16_t* oh = WT + (size_t)slot * 32768;
  bf16_t* ol = oh + 16384;
  for (int idx = threadIdx.x; idx < 16384; idx += 256) {
    int k = idx >> 7, n = idx & 127;
    bf16_t hb, lb;
    split2(src[idx], hb, lb);
    int pos = ((n & 7) * 16 + (n >> 3)) * 128 + k;
    oh[pos] = hb;
    ol[pos] = lb;
  }
}

__global__ __launch_bounds__(256) void k_fold(
    const float* __restrict__ ee_w2, const float* __restrict__ ee_b2,
    const float* __restrict__ le_w1, const float* __restrict__ le_b1,
    const float* __restrict__ le_w2, const float* __restrict__ le_b2,
    const float* __restrict__ ln_w1,
    bf16_t* __restrict__ WT, float* __restrict__ bvec, float* __restrict__ btil)
{
  const int l = blockIdx.x;
  const int which = blockIdx.y;
  const int z = blockIdx.z;
  const float* L; const float* Rm; const float* lb; const float* badd;
  int slot; float* bout;
  if (which == 0) {
    L = ee_w2; Rm = le_w1 + (size_t)l * 49152 + 256 * 128;
    lb = ee_b2; badd = le_b1 + l * 128;
    slot = 2 + l * 6 + 4; bout = bvec + l * 128;
  } else {
    L = le_w2 + (size_t)l * 16384; Rm = ln_w1 + (size_t)l * 32768 + 128 * 128;
    lb = le_b2 + l * 128; badd = nullptr;
    slot = 2 + l * 6 + 5; bout = btil + l * 128;
  }
  bf16_t* oh = WT + (size_t)slot * 32768;
  bf16_t* ol = oh + 16384;
  const int t = threadIdx.x;
  const int base = z * 2048;
  for (int eidx = base + t; eidx < base + 2048; eidx += 256) {
    int k = eidx >> 7, n = eidx & 127;
    float a = 0.f;
    for (int d = 0; d < 128; d += 4) {
      float4 lv = ld4(L + k * 128 + d);
      a = fmaf(lv.x, Rm[(d + 0) * 128 + n], a);
      a = fmaf(lv.y, Rm[(d + 1) * 128 + n], a);
      a = fmaf(lv.z, Rm[(d + 2) * 128 + n], a);
      a = fmaf(lv.w, Rm[(d + 3) * 128 + n], a);
    }
    bf16_t hb, lbv;
    split2(a, hb, lbv);
    int pos = ((n & 7) * 16 + (n >> 3)) * 128 + k;
    oh[pos] = hb;
    ol[pos] = lbv;
  }
  if (z == 0 && t < 128) {
    float a = badd ? badd[t] : 0.f;
    for (int d = 0; d < 128; ++d) a = fmaf(lb[d], Rm[d * 128 + t], a);
    bout[t] = a;
  }
}

__global__ __launch_bounds__(256) void k_node_u(
    const float* __restrict__ x, const float* __restrict__ w1,
    const float* __restrict__ b1, const float* __restrict__ a_ptr,
    float* __restrict__ U, int M)
{
  int gid = blockIdx.x * 256 + threadIdx.x;
  int m = gid >> 5;
  if (m >= M) return;
  int nc = (gid & 31) << 2;
  float a = *a_ptr;
  float4 bb = ld4(b1 + nc);
  float z0 = bb.x, z1 = bb.y, z2 = bb.z, z3 = bb.w;
  const float* xr = x + (size_t)m * 30;
  #pragma unroll
  for (int j = 0; j < 30; ++j) {
    float xv = xr[j];
    float4 wv = ld4(w1 + j * 128 + nc);
    z0 = fmaf(xv, wv.x, z0); z1 = fmaf(xv, wv.y, z1);
    z2 = fmaf(xv, wv.z, z2); z3 = fmaf(xv, wv.w, z3);
  }
  st4(U + (size_t)m * 128 + nc,
      make_float4(prelu1(z0, a), prelu1(z1, a), prelu1(z2, a), prelu1(z3, a)));
}

// --------- counting sort by dst ---------------------------------------------
__global__ void k_hist(const int* __restrict__ dstIdx, int* __restrict__ deg, int E) {
  int i = blockIdx.x * 256 + threadIdx.x;
  if (i < E) atomicAdd(deg + dstIdx[i], 1);
}

__global__ __launch_bounds__(1024) void k_scan(
    const int* __restrict__ deg, int* __restrict__ cursor,
    int* __restrict__ rowStart, int N, int per)
{
  __shared__ int part[1024];
  const int t = threadIdx.x;
  const int base = t * per;
  int local = 0;
  for (int i = 0; i < per; ++i) {
    int idx = base + i;
    if (idx < N) local += deg[idx];
  }
  part[t] = local;
  __syncthreads();
  for (int off = 1; off < 1024; off <<= 1) {
    int v = (t >= off) ? part[t - off] : 0;
    __syncthreads();
    part[t] += v;
    __syncthreads();
  }
  int run = (t == 0) ? 0 : part[t - 1];
  for (int i = 0; i < per; ++i) {
    int idx = base + i;
    if (idx < N) {
      cursor[idx] = run;
      rowStart[idx] = run;
      run += deg[idx];
    }
  }
}

__global__ void k_scatter(const int* __restrict__ srcIdx, const int* __restrict__ dstIdx,
                          const float* __restrict__ ea, int* __restrict__ cursor,
                          int* __restrict__ sSrc, int* __restrict__ sDst,
                          float* __restrict__ sEa, int E)
{
  int e = blockIdx.x * 256 + threadIdx.x;
  if (e < E) {
    int d = dstIdx[e];
    int p = atomicAdd(cursor + d, 1);
    sSrc[p] = srcIdx[e];
    sDst[p] = d;
    st4(sEa + (size_t)p * 4, ld4(ea + (size_t)e * 4));
  }
}

// ---------------------------------------------------------------------------
extern "C" void kernel_launch(void* const* d_in, const int* in_sizes, int n_in,
                              void* d_out, int out_size, void* d_ws, size_t ws_size,
                              hipStream_t stream)
{
  const float* x     = (const float*)d_in[0];
  const float* ea    = (const float*)d_in[1];
  const int*   ei    = (const int*)  d_in[2];
  const float* ne_w1 = (const float*)d_in[3];
  const float* ne_b1 = (const float*)d_in[4];
  const float* ne_a  = (const float*)d_in[5];
  const float* ne_w2 = (const float*)d_in[6];
  const float* ne_b2 = (const float*)d_in[7];
  const float* ee_w1 = (const float*)d_in[8];
  const float* ee_b1 = (const float*)d_in[9];
  const float* ee_a  = (const float*)d_in[10];
  const float* ee_w2 = (const float*)d_in[11];
  const float* ee_b2 = (const float*)d_in[12];
  const float* le_w1 = (const float*)d_in[13];
  const float* le_b1 = (const float*)d_in[14];
  const float* le_a  = (const float*)d_in[15];
  const float* le_w2 = (const float*)d_in[16];
  const float* le_b2 = (const float*)d_in[17];
  const float* ln_w1 = (const float*)d_in[18];
  const float* ln_b1 = (const float*)d_in[19];
  const float* ln_a  = (const float*)d_in[20];
  const float* ln_w2 = (const float*)d_in[21];
  const float* ln_b2 = (const float*)d_in[22];
  const float* de_w1 = (const float*)d_in[23];
  const float* de_b1 = (const float*)d_in[24];
  const float* de_a  = (const float*)d_in[25];
  const float* de_w2 = (const float*)d_in[26];
  const float* de_b2 = (const float*)d_in[27];

  const int N = in_sizes[0] / 30;
  const int E = in_sizes[1] / 4;
  const int* srcIdx = ei;        // edge_index[0] = x_j (source)
  const int* dstIdx = ei + E;    // edge_index[1] = x_i (target / agg index)

  const int g32 = (N + 31) / 32;        // node tiles (128-thr blocks)
  const int gE  = (E + 127) / 128;      // 128-edge tiles
  const int Np = g32 * 32;
  const size_t NNp = (size_t)Np * 128;

  float* w = (float*)d_ws;
  float* Pb   = w; w += NNp;
  float* Qb   = w; w += NNp;
  float* Sb   = w; w += NNp;               // also UN before the loop
  float* bvec = w; w += 5 * 128;
  float* btil = w; w += 5 * 128;
  float* sEa  = w; w += (size_t)E * 4;
  bf16_t* hSh = (bf16_t*)w;
  bf16_t* hSl = hSh + NNp;  w += NNp;      // 2 bf16 planes
  bf16_t* WT  = (bf16_t*)w; w += 32 * 32768 / 2;
  int* ip     = (int*)w;
  int* deg    = ip; ip += N;
  int* cursor = ip; ip += N;
  int* rowStart = ip; ip += N;
  int* sSrc   = ip; ip += E;
  int* sDst   = ip; ip += E;

  float* out = (float*)d_out;

  // weight prep + sort
  k_tsplit<<<dim3(22), dim3(256), 0, stream>>>(ne_w2, de_w1, le_w1, ln_w1, ln_w2, WT);
  k_fold<<<dim3(5, 2, 8), dim3(256), 0, stream>>>(ee_w2, ee_b2, le_w1, le_b1,
                                                  le_w2, le_b2, ln_w1, WT, bvec, btil);
  hipMemsetAsync(deg, 0, (size_t)N * 4, stream);
  k_hist<<<dim3((E + 255) / 256), dim3(256), 0, stream>>>(dstIdx, deg, E);
  k_scan<<<dim3(1), dim3(1024), 0, stream>>>(deg, cursor, rowStart, N,
                                             (N + 1023) / 1024);
  k_scatter<<<dim3((E + 255) / 256), dim3(256), 0, stream>>>(
      srcIdx, dstIdx, ea, cursor, sSrc, sDst, sEa, E);

  // encoder (+ P/Q for layer 0)
  k_node_u<<<dim3((N * 32 + 255) / 256), dim3(256), 0, stream>>>(x, ne_w1, ne_b1, ne_a, Sb, N);
  k_enc<<<dim3(g32), dim3(128), 0, stream>>>(Sb, WT, ne_b2, WT + 2 * 32768,
                                             hSh, hSl, Pb, Qb, N);

  // one-time zero of S (k_svu keeps it zeroed thereafter)
  hipMemsetAsync(Sb, 0, (size_t)N * 128 * 4, stream);

  for (int l = 0; l < 5; ++l) {
    const bf16_t* slotL = WT + (size_t)(2 + l * 6) * 32768;
    k_edge<<<dim3(gE), dim3(256), 0, stream>>>(
        sEa, sSrc, sDst, rowStart, deg, ee_w1, ee_b1, ee_a,
        slotL + 4 * 32768, bvec + l * 128, le_a + l, Pb, Qb, Sb, N, E);
    const bf16_t* W1next = (l < 4) ? (WT + (size_t)(2 + (l + 1) * 6) * 32768) : WT;
    k_svu<<<dim3(g32), dim3(128), 0, stream>>>(
        Sb, hSh, hSl, slotL + 5 * 32768, slotL + 2 * 32768, slotL + 3 * 32768,
        W1next, ln_b1 + (size_t)l * 128, btil + l * 128, deg, ln_a + l,
        ln_b2 + (size_t)l * 128, Pb, Qb, (l < 4) ? 1 : 0, N);
  }

  k_dec<<<dim3(g32), dim3(128), 0, stream>>>(hSh, hSl, WT + 32768, de_b1, de_a,
                                             de_w2, de_b2, out, N);
}

// Round 2
// 1428.700 us; speedup vs baseline: 1.0026x; 1.0026x over previous
//
#include <hip/hip_runtime.h>
#include <cstdint>
#include <cstddef>

// ---------------------------------------------------------------------------
// GNS model. R17 = R11 + LDS-staged epilogue Q gathers in k_edge via
// global_load_lds (async DMA, zero VGPR cost).
// Confirmed design points (15 rounds of A/B evidence):
//  - k_edge: 128-edge tiles, lb(256,3)=3 blocks/CU (L2-thrash optimum).
//  - R16 post-mortem: register-resident Q prefetch SPILLS (WRITE_SIZE
//    18->108 MB = exactly 36 dwords/thread scratch) -> regalloc cannot carry
//    a 4-deep pipeline here. Also: +150 MB traffic changed dur by 3% ->
//    massive BW slack, k_edge is latency-serialization-bound.
//  - R17: Q rows staged into LDS (Ast region reused post-GEMM, grown to
//    32 KB) by 8 global_load_lds_dwordx4 per wave per phase -> MLP=8/wave
//    in flight, 2 exposed latencies per block instead of ~8 serial chains
//    per lane. Epilogue reads Q via ds_read_b128.
//  - P hoisted once per dst-run (+bvec folded); permuted-column C layout.
//  - LDS S-tile, interior plain stores + boundary atomics; dst-sorted edges.
//  - Node side: fused k_svu (S@Wtil + h@Wn1a -> V -> h += V@ln_w2 -> P/Q),
//    wave-private LDS, zero barriers, re-zeroes consumed S rows.
//  - All GEMMs split-bf16 MFMA (AhBh+AlBh+AhBl), edge-U hi-only.
// ---------------------------------------------------------------------------

#define DEVI static __device__ __forceinline__

typedef __bf16 bf16_t;
typedef bf16_t bf16x8 __attribute__((ext_vector_type(8)));
typedef bf16_t bf16x4 __attribute__((ext_vector_type(4)));
typedef float f32x4v __attribute__((ext_vector_type(4)));

DEVI float4 ld4(const float* p) { return *(const float4*)p; }
DEVI void st4(float* p, float4 v) { *(float4*)p = v; }
DEVI float prelu1(float z, float a) { return z > 0.f ? z : a * z; }
DEVI void atomicAddF(float* p, float v) {
  __hip_atomic_fetch_add(p, v, __ATOMIC_RELAXED, __HIP_MEMORY_SCOPE_AGENT);
}
DEVI f32x4v mfma_bf16(bf16x8 a, bf16x8 b, f32x4v c) {
  return __builtin_amdgcn_mfma_f32_16x16x32_bf16(a, b, c, 0, 0, 0);
}
DEVI void mfma3(f32x4v& acc, bf16x8 ah, bf16x8 al, bf16x8 bh, bf16x8 bl) {
  acc = mfma_bf16(ah, bh, acc);
  acc = mfma_bf16(al, bh, acc);
  acc = mfma_bf16(ah, bl, acc);
}
DEVI void split2(float x, bf16_t& h, bf16_t& l) {
  h = (bf16_t)x;
  l = (bf16_t)(x - (float)h);
}
DEVI bf16x8 ldb8(const bf16_t* p) { return *(const bf16x8*)p; }

// async global->LDS DMA, 16 B per lane; dest = uniform base + lane*16
typedef const __attribute__((address_space(1))) unsigned int* gas_u32;
typedef __attribute__((address_space(3))) unsigned int* las_u32;
DEVI void gld_lds16(const float* g, void* l) {
  __builtin_amdgcn_global_load_lds((gas_u32)g, (las_u32)l, 16, 0, 0);
}

#define NST 136   // node staging row stride (bf16)
#define EST 72    // edge staging row stride (bf16)

// ============ node building blocks (wave-local; blocks may be 2 waves) ======

DEVI void stage_f32(const float* __restrict__ src, int row0, int M,
                    int lane, int wave, bf16_t* SAh, bf16_t* SAl)
{
  const int row = wave * 16 + (lane >> 2);
  const int grow = row0 + row;
  const int colbase = (lane & 3) * 32;
  #pragma unroll
  for (int j = 0; j < 8; ++j) {
    int kc = colbase + j * 4;
    float4 v = make_float4(0.f, 0.f, 0.f, 0.f);
    if (grow < M) v = ld4(src + (size_t)grow * 128 + kc);
    bf16_t h0,l0,h1,l1,h2,l2,h3,l3;
    split2(v.x,h0,l0); split2(v.y,h1,l1); split2(v.z,h2,l2); split2(v.w,h3,l3);
    *(bf16x4*)(SAh + row * NST + kc) = (bf16x4){h0,h1,h2,h3};
    *(bf16x4*)(SAl + row * NST + kc) = (bf16x4){l0,l1,l2,l3};
  }
}

DEVI void stage_planes(const bf16_t* __restrict__ gh, const bf16_t* __restrict__ gl,
                       int row0, int M, int lane, int wave,
                       bf16_t* SAh, bf16_t* SAl)
{
  const int row = wave * 16 + (lane >> 2);
  const int grow = row0 + row;
  const int colbase = (lane & 3) * 32;
  #pragma unroll
  for (int j = 0; j < 4; ++j) {
    int kc = colbase + j * 8;
    bf16x8 vh = {};
    bf16x8 vl = {};
    if (grow < M) {
      vh = ldb8(gh + (size_t)grow * 128 + kc);
      vl = ldb8(gl + (size_t)grow * 128 + kc);
    }
    *(bf16x8*)(SAh + row * NST + kc) = vh;
    *(bf16x8*)(SAl + row * NST + kc) = vl;
  }
}

DEVI void gemm_lds(const bf16_t* SAh, const bf16_t* SAl,
                   const bf16_t* __restrict__ BT, f32x4v acc[8],
                   int wave, int p, int q)
{
  #pragma unroll
  for (int ks = 0; ks < 4; ++ks) {
    const int k0 = ks * 32 + q * 8;
    bf16x8 aH = ldb8(SAh + (wave * 16 + p) * NST + k0);
    bf16x8 aL = ldb8(SAl + (wave * 16 + p) * NST + k0);
    #pragma unroll
    for (int nt = 0; nt < 8; ++nt) {
      const bf16_t* bp = BT + (size_t)(nt * 16 + p) * 128 + k0;
      mfma3(acc[nt], aH, aL, ldb8(bp), ldb8(bp + 16384));
    }
  }
}

DEVI void store_c(float* __restrict__ O, int row0, int M,
                  const f32x4v acc[8], int wave, int p, int q)
{
  int rb = row0 + wave * 16 + q * 4;
  #pragma unroll
  for (int r = 0; r < 4; ++r) {
    if (rb + r < M) {
      float* op = O + (size_t)(rb + r) * 128 + p * 8;
      st4(op,     make_float4(acc[0][r], acc[1][r], acc[2][r], acc[3][r]));
      st4(op + 4, make_float4(acc[4][r], acc[5][r], acc[6][r], acc[7][r]));
    }
  }
}

DEVI void stage_cregs(const f32x4v acc[8], int wave, int p, int q,
                      bf16_t* SAh, bf16_t* SAl)
{
  #pragma unroll
  for (int r = 0; r < 4; ++r) {
    int row = wave * 16 + q * 4 + r;
    bf16x8 vh, vl;
    #pragma unroll
    for (int nt = 0; nt < 8; ++nt) {
      bf16_t hb, lb;
      split2(acc[nt][r], hb, lb);
      vh[nt] = hb; vl[nt] = lb;
    }
    *(bf16x8*)(SAh + row * NST + p * 8) = vh;
    *(bf16x8*)(SAl + row * NST + p * 8) = vl;
  }
}

DEVI void planes_out(bf16_t* __restrict__ gh, bf16_t* __restrict__ gl,
                     int row0, int M, int lane, int wave,
                     const bf16_t* SAh, const bf16_t* SAl)
{
  const int row = wave * 16 + (lane >> 2);
  const int grow = row0 + row;
  const int colbase = (lane & 3) * 32;
  if (grow < M) {
    #pragma unroll
    for (int j = 0; j < 4; ++j) {
      int kc = colbase + j * 8;
      *(bf16x8*)(gh + (size_t)grow * 128 + kc) = *(const bf16x8*)(SAh + row * NST + kc);
      *(bf16x8*)(gl + (size_t)grow * 128 + kc) = *(const bf16x8*)(SAl + row * NST + kc);
    }
  }
}

DEVI void ld8f(float dst[8], const float* __restrict__ src, int p) {
  *(float4*)(dst)     = ld4(src + p * 8);
  *(float4*)(dst + 4) = ld4(src + p * 8 + 4);
}

// ---------------------------------------------------------------------------
// k_svu: 128 thr / 32-row tiles. Node update + P/Q for next layer; zeroes
// consumed S rows (keeps Sb zeroed for next layer's k_edge).
// ---------------------------------------------------------------------------
__global__ __launch_bounds__(128, 2) void k_svu(
    float* Sbuf,                      // read then zeroed (same buffer)
    bf16_t* __restrict__ hSh, bf16_t* __restrict__ hSl,
    const bf16_t* __restrict__ WtilT, const bf16_t* __restrict__ Wn1aT,
    const bf16_t* __restrict__ lnw2T, const bf16_t* __restrict__ W1nextT,
    const float* __restrict__ ln_b1_l, const float* __restrict__ btil_l,
    const int* __restrict__ deg, const float* __restrict__ ln_a_l,
    const float* __restrict__ ln_b2_l,
    float* __restrict__ P, float* __restrict__ Q, int doPQ, int M)
{
  __shared__ __align__(16) bf16_t SAh[32 * NST];
  __shared__ __align__(16) bf16_t SAl[32 * NST];
  const int t = threadIdx.x, lane = t & 63, wave = t >> 6;
  const int p = lane & 15, q = lane >> 4;
  const int row0 = blockIdx.x * 32;

  f32x4v acc1[8];
  #pragma unroll
  for (int j = 0; j < 8; ++j) acc1[j] = (f32x4v){0.f, 0.f, 0.f, 0.f};

  stage_f32(Sbuf, row0, M, lane, wave, SAh, SAl);
  // zero consumed S rows (per-lane same addresses as the loads -> ordered)
  {
    const int row = wave * 16 + (lane >> 2);
    const int grow = row0 + row;
    const int colbase = (lane & 3) * 32;
    if (grow < M) {
      float4 z4 = make_float4(0.f, 0.f, 0.f, 0.f);
      #pragma unroll
      for (int j = 0; j < 8; ++j)
        st4(Sbuf + (size_t)grow * 128 + colbase + j * 4, z4);
    }
  }
  gemm_lds(SAh, SAl, WtilT, acc1, wave, p, q);
  stage_planes(hSh, hSl, row0, M, lane, wave, SAh, SAl);
  gemm_lds(SAh, SAl, Wn1aT, acc1, wave, p, q);

  // h_old in (permuted) C layout from LDS — vectorized bf16x8 reads
  float hold[8][4];
  #pragma unroll
  for (int r = 0; r < 4; ++r) {
    int row = wave * 16 + q * 4 + r;
    bf16x8 vh = *(const bf16x8*)(SAh + row * NST + p * 8);
    bf16x8 vl = *(const bf16x8*)(SAl + row * NST + p * 8);
    #pragma unroll
    for (int nt = 0; nt < 8; ++nt)
      hold[nt][r] = (float)vh[nt] + (float)vl[nt];
  }
  // V = prelu(acc1 + b1 + deg*btil)
  const float alpha = *ln_a_l;
  float degf[4];
  #pragma unroll
  for (int r = 0; r < 4; ++r) {
    int row = row0 + wave * 16 + q * 4 + r;
    degf[r] = (row < M) ? (float)deg[row] : 0.f;
  }
  float b1c[8], btc[8];
  ld8f(b1c, ln_b1_l, p);
  ld8f(btc, btil_l, p);
  #pragma unroll
  for (int nt = 0; nt < 8; ++nt)
    #pragma unroll
    for (int r = 0; r < 4; ++r)
      acc1[nt][r] = prelu1(acc1[nt][r] + b1c[nt] + degf[r] * btc[nt], alpha);

  stage_cregs(acc1, wave, p, q, SAh, SAl);   // V
  f32x4v acc2[8];
  #pragma unroll
  for (int j = 0; j < 8; ++j) acc2[j] = (f32x4v){0.f, 0.f, 0.f, 0.f};
  gemm_lds(SAh, SAl, lnw2T, acc2, wave, p, q);
  // h_new = h_old + acc2 + b2
  float b2c[8];
  ld8f(b2c, ln_b2_l, p);
  #pragma unroll
  for (int nt = 0; nt < 8; ++nt)
    #pragma unroll
    for (int r = 0; r < 4; ++r)
      acc2[nt][r] = hold[nt][r] + acc2[nt][r] + b2c[nt];

  stage_cregs(acc2, wave, p, q, SAh, SAl);   // h_new
  planes_out(hSh, hSl, row0, M, lane, wave, SAh, SAl);

  if (doPQ) {
    f32x4v acc3[8];
    #pragma unroll
    for (int j = 0; j < 8; ++j) acc3[j] = (f32x4v){0.f, 0.f, 0.f, 0.f};
    gemm_lds(SAh, SAl, W1nextT, acc3, wave, p, q);
    store_c(P, row0, M, acc3, wave, p, q);
    #pragma unroll
    for (int j = 0; j < 8; ++j) acc3[j] = (f32x4v){0.f, 0.f, 0.f, 0.f};
    gemm_lds(SAh, SAl, W1nextT + 32768, acc3, wave, p, q);
    store_c(Q, row0, M, acc3, wave, p, q);
  }
}

// ---------------------------------------------------------------------------
// k_enc: 128 thr / 32-row tiles. h0 = UN@ne_w2 + b2 -> planes; + P/Q layer 0.
// ---------------------------------------------------------------------------
__global__ __launch_bounds__(128, 2) void k_enc(
    const float* __restrict__ UN, const bf16_t* __restrict__ new2T,
    const float* __restrict__ b2, const bf16_t* __restrict__ W1T0,
    bf16_t* __restrict__ hSh, bf16_t* __restrict__ hSl,
    float* __restrict__ P, float* __restrict__ Q, int M)
{
  __shared__ __align__(16) bf16_t SAh[32 * NST];
  __shared__ __align__(16) bf16_t SAl[32 * NST];
  const int t = threadIdx.x, lane = t & 63, wave = t >> 6;
  const int p = lane & 15, q = lane >> 4;
  const int row0 = blockIdx.x * 32;

  f32x4v acc[8];
  #pragma unroll
  for (int j = 0; j < 8; ++j) acc[j] = (f32x4v){0.f, 0.f, 0.f, 0.f};
  stage_f32(UN, row0, M, lane, wave, SAh, SAl);
  gemm_lds(SAh, SAl, new2T, acc, wave, p, q);
  float b2c[8];
  ld8f(b2c, b2, p);
  #pragma unroll
  for (int nt = 0; nt < 8; ++nt)
    #pragma unroll
    for (int r = 0; r < 4; ++r) acc[nt][r] += b2c[nt];
  stage_cregs(acc, wave, p, q, SAh, SAl);
  planes_out(hSh, hSl, row0, M, lane, wave, SAh, SAl);

  f32x4v acc3[8];
  #pragma unroll
  for (int j = 0; j < 8; ++j) acc3[j] = (f32x4v){0.f, 0.f, 0.f, 0.f};
  gemm_lds(SAh, SAl, W1T0, acc3, wave, p, q);
  store_c(P, row0, M, acc3, wave, p, q);
  #pragma unroll
  for (int j = 0; j < 8; ++j) acc3[j] = (f32x4v){0.f, 0.f, 0.f, 0.f};
  gemm_lds(SAh, SAl, W1T0 + 32768, acc3, wave, p, q);
  store_c(Q, row0, M, acc3, wave, p, q);
}

// ---------------------------------------------------------------------------
// k_edge: 128-edge tiles, lb(256,3), LDS S-tile, LDS-staged Q epilogue.
// ---------------------------------------------------------------------------
__global__ __launch_bounds__(256, 3) void k_edge(
    const float* __restrict__ sEa, const int* __restrict__ sSrc,
    const int* __restrict__ sDst,
    const int* __restrict__ rowStart, const int* __restrict__ deg,
    const float* __restrict__ ee_w1, const float* __restrict__ ee_b1,
    const float* __restrict__ ee_a,
    const bf16_t* __restrict__ WhatT, const float* __restrict__ bvec,
    const float* __restrict__ alpha_ptr,
    const float* __restrict__ P, const float* __restrict__ Q,
    float* __restrict__ S, int N, int E)
{
  __shared__ __align__(16) float Stile[32 * 132];     // 16.9 KB
  __shared__ __align__(16) float ew[640];             // ee_w1 + ee_b1
  // 32 KB union: Ast (18.4 KB) during GEMM; per-wave 8 KB Q-tile after.
  __shared__ __align__(16) char QSmem[32768];
  bf16_t* Ast = (bf16_t*)QSmem;

  const int t = threadIdx.x, lane = t & 63, wave = t >> 6;
  const int p = lane & 15, q = lane >> 4;
  const int e0 = blockIdx.x * 128;
  const int dstLo = sDst[e0];
  const int ebase = e0 + wave * 32 + q * 4;

  // dst indices for this lane's 8 edges (run logic); issued early, latency
  // absorbed by LDS init + barrier
  int d_[8];
  #pragma unroll
  for (int i = 0; i < 8; ++i) {
    int ed = ebase + (i >> 2) * 16 + (i & 3);
    d_[i] = sDst[ed < E ? ed : E - 1];
  }
  // src indices for phase-0 staging: lane L stages 16B chunk (L&31) of
  // phase-edge 2k + (L>>5)
  const int sbase = e0 + wave * 32 + (lane >> 5);
  int sv0[8];
  #pragma unroll
  for (int k = 0; k < 8; ++k) {
    int ed = sbase + 2 * k;
    sv0[k] = sSrc[ed < E ? ed : E - 1];
  }
  // first-P prefetch (latency hides under staging + GEMM)
  float pvf[8];
  ld8f(pvf, P + (size_t)d_[0] * 128, p);

  for (int i = t; i < 640; i += 256)
    ew[i] = (i < 512) ? ee_w1[i] : ee_b1[i - 512];
  for (int i = t; i < 32 * 132; i += 256) Stile[i] = 0.f;
  __syncthreads();

  const float ua = *ee_a;
  const float alpha = *alpha_ptr;
  float bvc[8];
  ld8f(bvc, bvec, p);

  const int srow = wave * 32 + (lane >> 1);
  const int scb = (lane & 1) * 32;
  float4 eav = make_float4(0.f, 0.f, 0.f, 0.f);
  {
    int ed = e0 + srow;
    if (ed < E) eav = ld4(sEa + (size_t)ed * 4);
  }

  f32x4v acc[2][8];
  #pragma unroll
  for (int i = 0; i < 2; ++i)
    #pragma unroll
    for (int j = 0; j < 8; ++j) acc[i][j] = (f32x4v){0.f, 0.f, 0.f, 0.f};

  for (int c = 0; c < 2; ++c) {
    // stage U chunk (bf16-hi only), wave-private rows -> no barrier
    #pragma unroll
    for (int j = 0; j < 8; ++j) {
      int kc = scb + j * 4;
      int kg = c * 64 + kc;
      float4 w0 = ld4(ew + kg);
      float4 w1 = ld4(ew + 128 + kg);
      float4 w2 = ld4(ew + 256 + kg);
      float4 w3 = ld4(ew + 384 + kg);
      float4 bb = ld4(ew + 512 + kg);
      float ux = bb.x, uy = bb.y, uz = bb.z, uw = bb.w;
      ux = fmaf(eav.x, w0.x, ux); uy = fmaf(eav.x, w0.y, uy);
      uz = fmaf(eav.x, w0.z, uz); uw = fmaf(eav.x, w0.w, uw);
      ux = fmaf(eav.y, w1.x, ux); uy = fmaf(eav.y, w1.y, uy);
      uz = fmaf(eav.y, w1.z, uz); uw = fmaf(eav.y, w1.w, uw);
      ux = fmaf(eav.z, w2.x, ux); uy = fmaf(eav.z, w2.y, uy);
      uz = fmaf(eav.z, w2.z, uz); uw = fmaf(eav.z, w2.w, uw);
      ux = fmaf(eav.w, w3.x, ux); uy = fmaf(eav.w, w3.y, uy);
      uz = fmaf(eav.w, w3.z, uz); uw = fmaf(eav.w, w3.w, uw);
      *(bf16x4*)(Ast + srow * EST + kc) = (bf16x4){
          (bf16_t)prelu1(ux, ua), (bf16_t)prelu1(uy, ua),
          (bf16_t)prelu1(uz, ua), (bf16_t)prelu1(uw, ua)};
    }
    #pragma unroll
    for (int ks = 0; ks < 2; ++ks) {
      const int k0 = ks * 32 + q * 8;
      const int kg = c * 64 + k0;
      bf16x8 aH0 = ldb8(Ast + (wave * 32 + p) * EST + k0);
      bf16x8 aH1 = ldb8(Ast + (wave * 32 + 16 + p) * EST + k0);
      #pragma unroll
      for (int nt = 0; nt < 8; ++nt) {
        const bf16_t* bp = WhatT + (size_t)(nt * 16 + p) * 128 + kg;
        bf16x8 bH = ldb8(bp);
        bf16x8 bL = ldb8(bp + 16384);
        acc[0][nt] = mfma_bf16(aH0, bH, acc[0][nt]);
        acc[0][nt] = mfma_bf16(aH0, bL, acc[0][nt]);
        acc[1][nt] = mfma_bf16(aH1, bH, acc[1][nt]);
        acc[1][nt] = mfma_bf16(aH1, bL, acc[1][nt]);
      }
    }
  }

  // ---- all waves done reading Ast; region becomes the Q-tile -------------
  __syncthreads();

  char* qbase = QSmem + wave * 8192;          // wave-private 8 KB slice
  const int cw = (lane & 31) * 4;             // float offset of lane's 16B
  #pragma unroll
  for (int k = 0; k < 8; ++k)
    gld_lds16(Q + (size_t)sv0[k] * 128 + cw, qbase + k * 1024);
  // phase-1 staging indices ride under the vmcnt wait
  int sv1[8];
  #pragma unroll
  for (int k = 0; k < 8; ++k) {
    int ed = sbase + 16 + 2 * k;
    sv1[k] = sSrc[ed < E ? ed : E - 1];
  }
  asm volatile("s_waitcnt vmcnt(0)" ::: "memory");

  const float* qw = (const float*)QSmem + wave * 2048;

  float rs[8];
  #pragma unroll
  for (int nt = 0; nt < 8; ++nt) rs[nt] = 0.f;
  int curd = -1;
  float pv[8];
  if (ebase < E) {                 // seed run state from prefetched first P
    curd = d_[0];
    #pragma unroll
    for (int nt = 0; nt < 8; ++nt) pv[nt] = pvf[nt] + bvc[nt];
  }

  #define FLUSH_RS()                                                        \
    if (curd >= 0) {                                                        \
      int rr = curd - dstLo;                                                \
      if (rr < 32) {                                                        \
        _Pragma("unroll")                                                   \
        for (int nt = 0; nt < 8; ++nt)                                      \
          atomicAdd(&Stile[rr * 132 + p * 8 + nt], rs[nt]);                 \
      } else {                                                              \
        _Pragma("unroll")                                                   \
        for (int nt = 0; nt < 8; ++nt)                                      \
          atomicAddF(S + (size_t)curd * 128 + p * 8 + nt, rs[nt]);          \
      }                                                                     \
      _Pragma("unroll")                                                     \
      for (int nt = 0; nt < 8; ++nt) rs[nt] = 0.f;                          \
    }

  #define QEDGE(MT, R)                                                      \
    if (ebase + (MT) * 16 + (R) < E) {                                      \
      int d = d_[(MT) * 4 + (R)];                                           \
      if (d != curd) {                                                      \
        FLUSH_RS();                                                         \
        curd = d;                                                           \
        ld8f(pv, P + (size_t)d * 128, p);                                   \
        _Pragma("unroll")                                                   \
        for (int nt = 0; nt < 8; ++nt) pv[nt] += bvc[nt];                   \
      }                                                                     \
      const float* qr = qw + (q * 4 + (R)) * 128 + p * 8;                   \
      float4 qa = ld4(qr);                                                  \
      float4 qb = ld4(qr + 4);                                              \
      rs[0] += prelu1(acc[MT][0][(R)] + pv[0] + qa.x, alpha);               \
      rs[1] += prelu1(acc[MT][1][(R)] + pv[1] + qa.y, alpha);               \
      rs[2] += prelu1(acc[MT][2][(R)] + pv[2] + qa.z, alpha);               \
      rs[3] += prelu1(acc[MT][3][(R)] + pv[3] + qa.w, alpha);               \
      rs[4] += prelu1(acc[MT][4][(R)] + pv[4] + qb.x, alpha);               \
      rs[5] += prelu1(acc[MT][5][(R)] + pv[5] + qb.y, alpha);               \
      rs[6] += prelu1(acc[MT][6][(R)] + pv[6] + qb.z, alpha);               \
      rs[7] += prelu1(acc[MT][7][(R)] + pv[7] + qb.w, alpha);               \
    }

  // phase 0: edges wave*32 + 0..15 (lane's q*4 + 0..3)
  QEDGE(0, 0)
  QEDGE(0, 1)
  QEDGE(0, 2)
  QEDGE(0, 3)

  // re-stage slice with phase-1 edges (wave-private; phase-0 ds_reads were
  // issued & consumed before these returns can land)
  #pragma unroll
  for (int k = 0; k < 8; ++k)
    gld_lds16(Q + (size_t)sv1[k] * 128 + cw, qbase + k * 1024);
  asm volatile("s_waitcnt vmcnt(0)" ::: "memory");

  // phase 1: edges wave*32 + 16..31 (run state carries across the boundary)
  QEDGE(1, 0)
  QEDGE(1, 1)
  QEDGE(1, 2)
  QEDGE(1, 3)
  FLUSH_RS();

  #undef QEDGE
  #undef FLUSH_RS

  __syncthreads();

  // writeback: interior rows plain-stored, boundary rows atomic
  const int lastE = (e0 + 127 < E) ? (e0 + 127) : (E - 1);
  const int dstHi = sDst[lastE];
  const int col4 = (t & 31) * 4;
  #pragma unroll
  for (int rr0 = 0; rr0 < 32; rr0 += 8) {
    int rr = rr0 + (t >> 5);
    int d = dstLo + rr;
    if (d <= dstHi && d < N) {
      float4 v = ld4(&Stile[rr * 132 + col4]);
      bool interior = (rowStart[d] >= e0) && (rowStart[d] + deg[d] <= e0 + 128);
      float* sp = S + (size_t)d * 128 + col4;
      if (interior) {
        st4(sp, v);
      } else {
        atomicAddF(sp + 0, v.x); atomicAddF(sp + 1, v.y);
        atomicAddF(sp + 2, v.z); atomicAddF(sp + 3, v.w);
      }
    }
  }
}

// ---------------------------------------------------------------------------
// k_dec: 128 thr / 32-row tiles. out = prelu(h@de_w1+de_b1)@de_w2 + de_b2.
// ---------------------------------------------------------------------------
__global__ __launch_bounds__(128, 4) void k_dec(
    const bf16_t* __restrict__ hSh, const bf16_t* __restrict__ hSl,
    const bf16_t* __restrict__ dw1T,
    const float* __restrict__ de_b1, const float* __restrict__ de_a,
    const float* __restrict__ de_w2, const float* __restrict__ de_b2,
    float* __restrict__ out, int M)
{
  __shared__ __align__(16) float Cs[32][132];
  __shared__ __align__(16) float w2s[384];
  const int t = threadIdx.x, lane = t & 63, wave = t >> 6;
  const int p = lane & 15, q = lane >> 4;
  const int row0 = blockIdx.x * 32;
  for (int i = t; i < 384; i += 128) w2s[i] = de_w2[i];

  f32x4v acc[8];
  #pragma unroll
  for (int j = 0; j < 8; ++j) acc[j] = (f32x4v){0.f, 0.f, 0.f, 0.f};
  const size_t ra = (size_t)(row0 + wave * 16 + p) * 128;
  #pragma unroll
  for (int ks = 0; ks < 4; ++ks) {
    const int k0 = ks * 32 + q * 8;
    bf16x8 aH = ldb8(hSh + ra + k0);
    bf16x8 aL = ldb8(hSl + ra + k0);
    #pragma unroll
    for (int nt = 0; nt < 8; ++nt) {
      const bf16_t* bp = dw1T + (size_t)(nt * 16 + p) * 128 + k0;
      mfma3(acc[nt], aH, aL, ldb8(bp), ldb8(bp + 16384));
    }
  }
  const float alpha = *de_a;
  float b1c[8];
  ld8f(b1c, de_b1, p);
  #pragma unroll
  for (int r = 0; r < 4; ++r) {
    int row = wave * 16 + q * 4 + r;
    float* cp = &Cs[row][p * 8];
    st4(cp, make_float4(prelu1(acc[0][r] + b1c[0], alpha),
                        prelu1(acc[1][r] + b1c[1], alpha),
                        prelu1(acc[2][r] + b1c[2], alpha),
                        prelu1(acc[3][r] + b1c[3], alpha)));
    st4(cp + 4, make_float4(prelu1(acc[4][r] + b1c[4], alpha),
                            prelu1(acc[5][r] + b1c[5], alpha),
                            prelu1(acc[6][r] + b1c[6], alpha),
                            prelu1(acc[7][r] + b1c[7], alpha)));
  }
  __syncthreads();
  if (t < 32) {
    float s0 = de_b2[0], s1 = de_b2[1], s2 = de_b2[2];
    for (int k = 0; k < 128; ++k) {
      float vv = Cs[t][k];
      s0 = fmaf(vv, w2s[k * 3 + 0], s0);
      s1 = fmaf(vv, w2s[k * 3 + 1], s1);
      s2 = fmaf(vv, w2s[k * 3 + 2], s2);
    }
    int row = row0 + t;
    if (row < M) {
      out[(size_t)row * 3 + 0] = s0;
      out[(size_t)row * 3 + 1] = s1;
      out[(size_t)row * 3 + 2] = s2;
    }
  }
}

// --------- weight prep: transpose+split with PERMUTED col mapping -----------
__global__ __launch_bounds__(256) void k_tsplit(
    const float* __restrict__ ne_w2, const float* __restrict__ de_w1,
    const float* __restrict__ le_w1, const float* __restrict__ ln_w1,
    const float* __restrict__ ln_w2, bf16_t* __restrict__ WT)
{
  int jid = blockIdx.x;
  const float* src; int slot;
  if (jid == 0)      { src = ne_w2; slot = 0; }
  else if (jid == 1) { src = de_w1; slot = 1; }
  else {
    int l = (jid - 2) >> 2, wj = (jid - 2) & 3;
    slot = 2 + l * 6 + wj;
    src = (wj == 0) ? le_w1 + (size_t)l * 49152
        : (wj == 1) ? le_w1 + (size_t)l * 49152 + 16384
        : (wj == 2) ? ln_w1 + (size_t)l * 32768
                    : ln_w2 + (size_t)l * 16384;
  }
  bf16_t* oh = WT + (size_t)slot * 32768;
  bf16_t* ol = oh + 16384;
  for (int idx = threadIdx.x; idx < 16384; idx += 256) {
    int k = idx >> 7, n = idx & 127;
    bf16_t hb, lb;
    split2(src[idx], hb, lb);
    int pos = ((n & 7) * 16 + (n >> 3)) * 128 + k;
    oh[pos] = hb;
    ol[pos] = lb;
  }
}

__global__ __launch_bounds__(256) void k_fold(
    const float* __restrict__ ee_w2, const float* __restrict__ ee_b2,
    const float* __restrict__ le_w1, const float* __restrict__ le_b1,
    const float* __restrict__ le_w2, const float* __restrict__ le_b2,
    const float* __restrict__ ln_w1,
    bf16_t* __restrict__ WT, float* __restrict__ bvec, float* __restrict__ btil)
{
  const int l = blockIdx.x;
  const int which = blockIdx.y;
  const int z = blockIdx.z;
  const float* L; const float* Rm; const float* lb; const float* badd;
  int slot; float* bout;
  if (which == 0) {
    L = ee_w2; Rm = le_w1 + (size_t)l * 49152 + 256 * 128;
    lb = ee_b2; badd = le_b1 + l * 128;
    slot = 2 + l * 6 + 4; bout = bvec + l * 128;
  } else {
    L = le_w2 + (size_t)l * 16384; Rm = ln_w1 + (size_t)l * 32768 + 128 * 128;
    lb = le_b2 + l * 128; badd = nullptr;
    slot = 2 + l * 6 + 5; bout = btil + l * 128;
  }
  bf16_t* oh = WT + (size_t)slot * 32768;
  bf16_t* ol = oh + 16384;
  const int t = threadIdx.x;
  const int base = z * 2048;
  for (int eidx = base + t; eidx < base + 2048; eidx += 256) {
    int k = eidx >> 7, n = eidx & 127;
    float a = 0.f;
    for (int d = 0; d < 128; d += 4) {
      float4 lv = ld4(L + k * 128 + d);
      a = fmaf(lv.x, Rm[(d + 0) * 128 + n], a);
      a = fmaf(lv.y, Rm[(d + 1) * 128 + n], a);
      a = fmaf(lv.z, Rm[(d + 2) * 128 + n], a);
      a = fmaf(lv.w, Rm[(d + 3) * 128 + n], a);
    }
    bf16_t hb, lbv;
    split2(a, hb, lbv);
    int pos = ((n & 7) * 16 + (n >> 3)) * 128 + k;
    oh[pos] = hb;
    ol[pos] = lbv;
  }
  if (z == 0 && t < 128) {
    float a = badd ? badd[t] : 0.f;
    for (int d = 0; d < 128; ++d) a = fmaf(lb[d], Rm[d * 128 + t], a);
    bout[t] = a;
  }
}

__global__ __launch_bounds__(256) void k_node_u(
    const float* __restrict__ x, const float* __restrict__ w1,
    const float* __restrict__ b1, const float* __restrict__ a_ptr,
    float* __restrict__ U, int M)
{
  int gid = blockIdx.x * 256 + threadIdx.x;
  int m = gid >> 5;
  if (m >= M) return;
  int nc = (gid & 31) << 2;
  float a = *a_ptr;
  float4 bb = ld4(b1 + nc);
  float z0 = bb.x, z1 = bb.y, z2 = bb.z, z3 = bb.w;
  const float* xr = x + (size_t)m * 30;
  #pragma unroll
  for (int j = 0; j < 30; ++j) {
    float xv = xr[j];
    float4 wv = ld4(w1 + j * 128 + nc);
    z0 = fmaf(xv, wv.x, z0); z1 = fmaf(xv, wv.y, z1);
    z2 = fmaf(xv, wv.z, z2); z3 = fmaf(xv, wv.w, z3);
  }
  st4(U + (size_t)m * 128 + nc,
      make_float4(prelu1(z0, a), prelu1(z1, a), prelu1(z2, a), prelu1(z3, a)));
}

// --------- counting sort by dst ---------------------------------------------
__global__ void k_hist(const int* __restrict__ dstIdx, int* __restrict__ deg, int E) {
  int i = blockIdx.x * 256 + threadIdx.x;
  if (i < E) atomicAdd(deg + dstIdx[i], 1);
}

__global__ __launch_bounds__(1024) void k_scan(
    const int* __restrict__ deg, int* __restrict__ cursor,
    int* __restrict__ rowStart, int N, int per)
{
  __shared__ int part[1024];
  const int t = threadIdx.x;
  const int base = t * per;
  int local = 0;
  for (int i = 0; i < per; ++i) {
    int idx = base + i;
    if (idx < N) local += deg[idx];
  }
  part[t] = local;
  __syncthreads();
  for (int off = 1; off < 1024; off <<= 1) {
    int v = (t >= off) ? part[t - off] : 0;
    __syncthreads();
    part[t] += v;
    __syncthreads();
  }
  int run = (t == 0) ? 0 : part[t - 1];
  for (int i = 0; i < per; ++i) {
    int idx = base + i;
    if (idx < N) {
      cursor[idx] = run;
      rowStart[idx] = run;
      run += deg[idx];
    }
  }
}

__global__ void k_scatter(const int* __restrict__ srcIdx, const int* __restrict__ dstIdx,
                          const float* __restrict__ ea, int* __restrict__ cursor,
                          int* __restrict__ sSrc, int* __restrict__ sDst,
                          float* __restrict__ sEa, int E)
{
  int e = blockIdx.x * 256 + threadIdx.x;
  if (e < E) {
    int d = dstIdx[e];
    int p = atomicAdd(cursor + d, 1);
    sSrc[p] = srcIdx[e];
    sDst[p] = d;
    st4(sEa + (size_t)p * 4, ld4(ea + (size_t)e * 4));
  }
}

// ---------------------------------------------------------------------------
extern "C" void kernel_launch(void* const* d_in, const int* in_sizes, int n_in,
                              void* d_out, int out_size, void* d_ws, size_t ws_size,
                              hipStream_t stream)
{
  const float* x     = (const float*)d_in[0];
  const float* ea    = (const float*)d_in[1];
  const int*   ei    = (const int*)  d_in[2];
  const float* ne_w1 = (const float*)d_in[3];
  const float* ne_b1 = (const float*)d_in[4];
  const float* ne_a  = (const float*)d_in[5];
  const float* ne_w2 = (const float*)d_in[6];
  const float* ne_b2 = (const float*)d_in[7];
  const float* ee_w1 = (const float*)d_in[8];
  const float* ee_b1 = (const float*)d_in[9];
  const float* ee_a  = (const float*)d_in[10];
  const float* ee_w2 = (const float*)d_in[11];
  const float* ee_b2 = (const float*)d_in[12];
  const float* le_w1 = (const float*)d_in[13];
  const float* le_b1 = (const float*)d_in[14];
  const float* le_a  = (const float*)d_in[15];
  const float* le_w2 = (const float*)d_in[16];
  const float* le_b2 = (const float*)d_in[17];
  const float* ln_w1 = (const float*)d_in[18];
  const float* ln_b1 = (const float*)d_in[19];
  const float* ln_a  = (const float*)d_in[20];
  const float* ln_w2 = (const float*)d_in[21];
  const float* ln_b2 = (const float*)d_in[22];
  const float* de_w1 = (const float*)d_in[23];
  const float* de_b1 = (const float*)d_in[24];
  const float* de_a  = (const float*)d_in[25];
  const float* de_w2 = (const float*)d_in[26];
  const float* de_b2 = (const float*)d_in[27];

  const int N = in_sizes[0] / 30;
  const int E = in_sizes[1] / 4;
  const int* srcIdx = ei;        // edge_index[0] = x_j (source)
  const int* dstIdx = ei + E;    // edge_index[1] = x_i (target / agg index)

  const int g32 = (N + 31) / 32;        // node tiles (128-thr blocks)
  const int gE  = (E + 127) / 128;      // 128-edge tiles
  const int Np = g32 * 32;
  const size_t NNp = (size_t)Np * 128;

  float* w = (float*)d_ws;
  float* Pb   = w; w += NNp;
  float* Qb   = w; w += NNp;
  float* Sb   = w; w += NNp;               // also UN before the loop
  float* bvec = w; w += 5 * 128;
  float* btil = w; w += 5 * 128;
  float* sEa  = w; w += (size_t)E * 4;
  bf16_t* hSh = (bf16_t*)w;
  bf16_t* hSl = hSh + NNp;  w += NNp;      // 2 bf16 planes
  bf16_t* WT  = (bf16_t*)w; w += 32 * 32768 / 2;
  int* ip     = (int*)w;
  int* deg    = ip; ip += N;
  int* cursor = ip; ip += N;
  int* rowStart = ip; ip += N;
  int* sSrc   = ip; ip += E;
  int* sDst   = ip; ip += E;

  float* out = (float*)d_out;

  // weight prep + sort
  k_tsplit<<<dim3(22), dim3(256), 0, stream>>>(ne_w2, de_w1, le_w1, ln_w1, ln_w2, WT);
  k_fold<<<dim3(5, 2, 8), dim3(256), 0, stream>>>(ee_w2, ee_b2, le_w1, le_b1,
                                                  le_w2, le_b2, ln_w1, WT, bvec, btil);
  hipMemsetAsync(deg, 0, (size_t)N * 4, stream);
  k_hist<<<dim3((E + 255) / 256), dim3(256), 0, stream>>>(dstIdx, deg, E);
  k_scan<<<dim3(1), dim3(1024), 0, stream>>>(deg, cursor, rowStart, N,
                                             (N + 1023) / 1024);
  k_scatter<<<dim3((E + 255) / 256), dim3(256), 0, stream>>>(
      srcIdx, dstIdx, ea, cursor, sSrc, sDst, sEa, E);

  // encoder (+ P/Q for layer 0)
  k_node_u<<<dim3((N * 32 + 255) / 256), dim3(256), 0, stream>>>(x, ne_w1, ne_b1, ne_a, Sb, N);
  k_enc<<<dim3(g32), dim3(128), 0, stream>>>(Sb, WT, ne_b2, WT + 2 * 32768,
                                             hSh, hSl, Pb, Qb, N);

  // one-time zero of S (k_svu keeps it zeroed thereafter)
  hipMemsetAsync(Sb, 0, (size_t)N * 128 * 4, stream);

  for (int l = 0; l < 5; ++l) {
    const bf16_t* slotL = WT + (size_t)(2 + l * 6) * 32768;
    k_edge<<<dim3(gE), dim3(256), 0, stream>>>(
        sEa, sSrc, sDst, rowStart, deg, ee_w1, ee_b1, ee_a,
        slotL + 4 * 32768, bvec + l * 128, le_a + l, Pb, Qb, Sb, N, E);
    const bf16_t* W1next = (l < 4) ? (WT + (size_t)(2 + (l + 1) * 6) * 32768) : WT;
    k_svu<<<dim3(g32), dim3(128), 0, stream>>>(
        Sb, hSh, hSl, slotL + 5 * 32768, slotL + 2 * 32768, slotL + 3 * 32768,
        W1next, ln_b1 + (size_t)l * 128, btil + l * 128, deg, ln_a + l,
        ln_b2 + (size_t)l * 128, Pb, Qb, (l < 4) ? 1 : 0, N);
  }

  k_dec<<<dim3(g32), dim3(128), 0, stream>>>(hSh, hSl, WT + 32768, de_b1, de_a,
                                             de_w2, de_b2, out, N);
}

// Round 3
// 1367.714 us; speedup vs baseline: 1.0473x; 1.0446x over previous
//
#include <hip/hip_runtime.h>
#include <cstdint>
#include <cstddef>

// ---------------------------------------------------------------------------
// GNS model. R18 = R11 k_edge (verified optimum) + 4-wave nt-split k_svu/k_enc.
// Evidence log:
//  - k_edge: 128-edge tiles, lb(256,3)=3 blocks/CU (L2-thrash optimum).
//    R16 (reg-pipelined gathers): spilled, +3%. R17 (LDS-DMA staged gathers):
//    spilled indices, +3%. Both restructures of the epilogue moved dur ±3%
//    -> epilogue gather chain is NOT the dominant k_edge cost; k_edge stays
//    at the R11 structure (inline gathers, P-per-run, LDS S-tile).
//  - R18 theory: k_svu/k_enc ran 128-thr/2-wave blocks -> 1250 waves chip-wide
//    = 1.2 waves/SIMD, zero latency hiding on 5 serial GEMMs streaming
//    64 KB/wave of B from L2. Split column-tiles across 2 more waves:
//    wave (h=wave&1, cH=wave>>1) owns rows h*16..+15, cols cH*64..+63
//    (nt' = cH*4+nt). Waves double to 2500, per-wave chains halve.
//    Wave-private zero-barrier design -> 8 cheap __syncthreads().
//  - P hoisted once per dst-run (+bvec folded); permuted-column C layout
//    (weight slots: output col n = p*8 + nt').
//  - LDS S-tile, interior plain stores + boundary atomics; dst-sorted edges.
//  - All GEMMs split-bf16 MFMA (AhBh+AlBh+AhBl), edge-U hi-only.
// ---------------------------------------------------------------------------

#define DEVI static __device__ __forceinline__

typedef __bf16 bf16_t;
typedef bf16_t bf16x8 __attribute__((ext_vector_type(8)));
typedef bf16_t bf16x4 __attribute__((ext_vector_type(4)));
typedef float f32x4v __attribute__((ext_vector_type(4)));

DEVI float4 ld4(const float* p) { return *(const float4*)p; }
DEVI void st4(float* p, float4 v) { *(float4*)p = v; }
DEVI float prelu1(float z, float a) { return z > 0.f ? z : a * z; }
DEVI void atomicAddF(float* p, float v) {
  __hip_atomic_fetch_add(p, v, __ATOMIC_RELAXED, __HIP_MEMORY_SCOPE_AGENT);
}
DEVI f32x4v mfma_bf16(bf16x8 a, bf16x8 b, f32x4v c) {
  return __builtin_amdgcn_mfma_f32_16x16x32_bf16(a, b, c, 0, 0, 0);
}
DEVI void mfma3(f32x4v& acc, bf16x8 ah, bf16x8 al, bf16x8 bh, bf16x8 bl) {
  acc = mfma_bf16(ah, bh, acc);
  acc = mfma_bf16(al, bh, acc);
  acc = mfma_bf16(ah, bl, acc);
}
DEVI void split2(float x, bf16_t& h, bf16_t& l) {
  h = (bf16_t)x;
  l = (bf16_t)(x - (float)h);
}
DEVI bf16x8 ldb8(const bf16_t* p) { return *(const bf16x8*)p; }

#define NST 136   // node staging row stride (bf16)
#define EST 72    // edge staging row stride (bf16)

// ======== 4-wave node tile building blocks ================================
// wave (h = wave&1) owns rows h*16..h*16+15; (cH = wave>>1) owns col-half
// cH*64..cH*64+63 (column tiles nt' = cH*4 + nt, nt in 0..3).

DEVI void stage_f32_c4(const float* __restrict__ src, int row0, int M,
                       int lane, int h, int cH, bf16_t* SAh, bf16_t* SAl)
{
  const int row = h * 16 + (lane >> 2);
  const int grow = row0 + row;
  const int colbase = cH * 64 + (lane & 3) * 16;
  #pragma unroll
  for (int j = 0; j < 4; ++j) {
    int kc = colbase + j * 4;
    float4 v = make_float4(0.f, 0.f, 0.f, 0.f);
    if (grow < M) v = ld4(src + (size_t)grow * 128 + kc);
    bf16_t h0,l0,h1,l1,h2,l2,h3,l3;
    split2(v.x,h0,l0); split2(v.y,h1,l1); split2(v.z,h2,l2); split2(v.w,h3,l3);
    *(bf16x4*)(SAh + row * NST + kc) = (bf16x4){h0,h1,h2,h3};
    *(bf16x4*)(SAl + row * NST + kc) = (bf16x4){l0,l1,l2,l3};
  }
}

DEVI void stage_planes_c4(const bf16_t* __restrict__ gh, const bf16_t* __restrict__ gl,
                          int row0, int M, int lane, int h, int cH,
                          bf16_t* SAh, bf16_t* SAl)
{
  const int row = h * 16 + (lane >> 2);
  const int grow = row0 + row;
  const int colbase = cH * 64 + (lane & 3) * 16;
  #pragma unroll
  for (int j = 0; j < 2; ++j) {
    int kc = colbase + j * 8;
    bf16x8 vh = {};
    bf16x8 vl = {};
    if (grow < M) {
      vh = ldb8(gh + (size_t)grow * 128 + kc);
      vl = ldb8(gl + (size_t)grow * 128 + kc);
    }
    *(bf16x8*)(SAh + row * NST + kc) = vh;
    *(bf16x8*)(SAl + row * NST + kc) = vl;
  }
}

// acc[4] over column tiles ntb..ntb+3; A rows h*16..+15 (full K=128)
DEVI void gemm_c4(const bf16_t* SAh, const bf16_t* SAl,
                  const bf16_t* __restrict__ BT, f32x4v acc[4],
                  int h, int ntb, int p, int q)
{
  #pragma unroll
  for (int ks = 0; ks < 4; ++ks) {
    const int k0 = ks * 32 + q * 8;
    bf16x8 aH = ldb8(SAh + (h * 16 + p) * NST + k0);
    bf16x8 aL = ldb8(SAl + (h * 16 + p) * NST + k0);
    #pragma unroll
    for (int nt = 0; nt < 4; ++nt) {
      const bf16_t* bp = BT + (size_t)((ntb + nt) * 16 + p) * 128 + k0;
      mfma3(acc[nt], aH, aL, ldb8(bp), ldb8(bp + 16384));
    }
  }
}

DEVI void store_c4(float* __restrict__ O, int row0, int M,
                   const f32x4v acc[4], int h, int cH, int p, int q)
{
  int rb = row0 + h * 16 + q * 4;
  #pragma unroll
  for (int r = 0; r < 4; ++r) {
    if (rb + r < M) {
      float* op = O + (size_t)(rb + r) * 128 + p * 8 + cH * 4;
      st4(op, make_float4(acc[0][r], acc[1][r], acc[2][r], acc[3][r]));
    }
  }
}

DEVI void stage_cregs_c4(const f32x4v acc[4], int h, int cH, int p, int q,
                         bf16_t* SAh, bf16_t* SAl)
{
  #pragma unroll
  for (int r = 0; r < 4; ++r) {
    int row = h * 16 + q * 4 + r;
    bf16x4 vh, vl;
    #pragma unroll
    for (int nt = 0; nt < 4; ++nt) {
      bf16_t hb, lb;
      split2(acc[nt][r], hb, lb);
      vh[nt] = hb; vl[nt] = lb;
    }
    *(bf16x4*)(SAh + row * NST + p * 8 + cH * 4) = vh;
    *(bf16x4*)(SAl + row * NST + p * 8 + cH * 4) = vl;
  }
}

DEVI void planes_out_c4(bf16_t* __restrict__ gh, bf16_t* __restrict__ gl,
                        int row0, int M, int lane, int h, int cH,
                        const bf16_t* SAh, const bf16_t* SAl)
{
  const int row = h * 16 + (lane >> 2);
  const int grow = row0 + row;
  const int colbase = cH * 64 + (lane & 3) * 16;
  if (grow < M) {
    #pragma unroll
    for (int j = 0; j < 2; ++j) {
      int kc = colbase + j * 8;
      *(bf16x8*)(gh + (size_t)grow * 128 + kc) = *(const bf16x8*)(SAh + row * NST + kc);
      *(bf16x8*)(gl + (size_t)grow * 128 + kc) = *(const bf16x8*)(SAl + row * NST + kc);
    }
  }
}

DEVI void ld8f(float dst[8], const float* __restrict__ src, int p) {
  *(float4*)(dst)     = ld4(src + p * 8);
  *(float4*)(dst + 4) = ld4(src + p * 8 + 4);
}

DEVI void ld4f(float dst[4], const float* __restrict__ src, int p, int cH) {
  *(float4*)(dst) = ld4(src + p * 8 + cH * 4);
}

// ---------------------------------------------------------------------------
// k_svu: 256 thr / 32-row tiles, 4 waves (rows x col-half split). Node update
// + P/Q for next layer; zeroes consumed S rows.
// ---------------------------------------------------------------------------
__global__ __launch_bounds__(256, 2) void k_svu(
    float* Sbuf,                      // read then zeroed (same buffer)
    bf16_t* __restrict__ hSh, bf16_t* __restrict__ hSl,
    const bf16_t* __restrict__ WtilT, const bf16_t* __restrict__ Wn1aT,
    const bf16_t* __restrict__ lnw2T, const bf16_t* __restrict__ W1nextT,
    const float* __restrict__ ln_b1_l, const float* __restrict__ btil_l,
    const int* __restrict__ deg, const float* __restrict__ ln_a_l,
    const float* __restrict__ ln_b2_l,
    float* __restrict__ P, float* __restrict__ Q, int doPQ, int M)
{
  __shared__ __align__(16) bf16_t SAh[32 * NST];
  __shared__ __align__(16) bf16_t SAl[32 * NST];
  const int t = threadIdx.x, lane = t & 63, wave = t >> 6;
  const int h = wave & 1, cH = wave >> 1;
  const int p = lane & 15, q = lane >> 4;
  const int row0 = blockIdx.x * 32;

  f32x4v acc1[4];
  #pragma unroll
  for (int j = 0; j < 4; ++j) acc1[j] = (f32x4v){0.f, 0.f, 0.f, 0.f};

  stage_f32_c4(Sbuf, row0, M, lane, h, cH, SAh, SAl);
  // zero consumed S cells (per-lane same addresses as the loads -> ordered)
  {
    const int row = h * 16 + (lane >> 2);
    const int grow = row0 + row;
    const int colbase = cH * 64 + (lane & 3) * 16;
    if (grow < M) {
      float4 z4 = make_float4(0.f, 0.f, 0.f, 0.f);
      #pragma unroll
      for (int j = 0; j < 4; ++j)
        st4(Sbuf + (size_t)grow * 128 + colbase + j * 4, z4);
    }
  }
  __syncthreads();                       // S tile complete
  gemm_c4(SAh, SAl, WtilT, acc1, h, cH * 4, p, q);
  __syncthreads();                       // all S reads done before h overwrite
  stage_planes_c4(hSh, hSl, row0, M, lane, h, cH, SAh, SAl);
  __syncthreads();                       // h tile complete
  gemm_c4(SAh, SAl, Wn1aT, acc1, h, cH * 4, p, q);

  // h_old (feature-linear layout) from LDS — this wave's 4 cols
  float hold[4][4];
  #pragma unroll
  for (int r = 0; r < 4; ++r) {
    int row = h * 16 + q * 4 + r;
    bf16x4 vh = *(const bf16x4*)(SAh + row * NST + p * 8 + cH * 4);
    bf16x4 vl = *(const bf16x4*)(SAl + row * NST + p * 8 + cH * 4);
    #pragma unroll
    for (int nt = 0; nt < 4; ++nt)
      hold[nt][r] = (float)vh[nt] + (float)vl[nt];
  }
  __syncthreads();                       // all h reads done before V overwrite

  // V = prelu(acc1 + b1 + deg*btil)
  const float alpha = *ln_a_l;
  float degf[4];
  #pragma unroll
  for (int r = 0; r < 4; ++r) {
    int row = row0 + h * 16 + q * 4 + r;
    degf[r] = (row < M) ? (float)deg[row] : 0.f;
  }
  float b1c[4], btc[4];
  ld4f(b1c, ln_b1_l, p, cH);
  ld4f(btc, btil_l, p, cH);
  #pragma unroll
  for (int nt = 0; nt < 4; ++nt)
    #pragma unroll
    for (int r = 0; r < 4; ++r)
      acc1[nt][r] = prelu1(acc1[nt][r] + b1c[nt] + degf[r] * btc[nt], alpha);

  stage_cregs_c4(acc1, h, cH, p, q, SAh, SAl);   // V
  __syncthreads();                       // V tile complete
  f32x4v acc2[4];
  #pragma unroll
  for (int j = 0; j < 4; ++j) acc2[j] = (f32x4v){0.f, 0.f, 0.f, 0.f};
  gemm_c4(SAh, SAl, lnw2T, acc2, h, cH * 4, p, q);
  __syncthreads();                       // all V reads done before h_new overwrite

  // h_new = h_old + acc2 + b2
  float b2c[4];
  ld4f(b2c, ln_b2_l, p, cH);
  #pragma unroll
  for (int nt = 0; nt < 4; ++nt)
    #pragma unroll
    for (int r = 0; r < 4; ++r)
      acc2[nt][r] = hold[nt][r] + acc2[nt][r] + b2c[nt];

  stage_cregs_c4(acc2, h, cH, p, q, SAh, SAl);   // h_new
  __syncthreads();                       // h_new tile complete
  planes_out_c4(hSh, hSl, row0, M, lane, h, cH, SAh, SAl);

  if (doPQ) {
    f32x4v acc3[4];
    #pragma unroll
    for (int j = 0; j < 4; ++j) acc3[j] = (f32x4v){0.f, 0.f, 0.f, 0.f};
    gemm_c4(SAh, SAl, W1nextT, acc3, h, cH * 4, p, q);
    store_c4(P, row0, M, acc3, h, cH, p, q);
    #pragma unroll
    for (int j = 0; j < 4; ++j) acc3[j] = (f32x4v){0.f, 0.f, 0.f, 0.f};
    gemm_c4(SAh, SAl, W1nextT + 32768, acc3, h, cH * 4, p, q);
    store_c4(Q, row0, M, acc3, h, cH, p, q);
  }
}

// ---------------------------------------------------------------------------
// k_enc: 256 thr / 32-row tiles, 4 waves. h0 = UN@ne_w2 + b2 -> planes;
// + P/Q layer 0.
// ---------------------------------------------------------------------------
__global__ __launch_bounds__(256, 2) void k_enc(
    const float* __restrict__ UN, const bf16_t* __restrict__ new2T,
    const float* __restrict__ b2, const bf16_t* __restrict__ W1T0,
    bf16_t* __restrict__ hSh, bf16_t* __restrict__ hSl,
    float* __restrict__ P, float* __restrict__ Q, int M)
{
  __shared__ __align__(16) bf16_t SAh[32 * NST];
  __shared__ __align__(16) bf16_t SAl[32 * NST];
  const int t = threadIdx.x, lane = t & 63, wave = t >> 6;
  const int h = wave & 1, cH = wave >> 1;
  const int p = lane & 15, q = lane >> 4;
  const int row0 = blockIdx.x * 32;

  f32x4v acc[4];
  #pragma unroll
  for (int j = 0; j < 4; ++j) acc[j] = (f32x4v){0.f, 0.f, 0.f, 0.f};
  stage_f32_c4(UN, row0, M, lane, h, cH, SAh, SAl);
  __syncthreads();                       // UN tile complete
  gemm_c4(SAh, SAl, new2T, acc, h, cH * 4, p, q);
  __syncthreads();                       // all UN reads done before h0 overwrite
  float b2c[4];
  ld4f(b2c, b2, p, cH);
  #pragma unroll
  for (int nt = 0; nt < 4; ++nt)
    #pragma unroll
    for (int r = 0; r < 4; ++r) acc[nt][r] += b2c[nt];
  stage_cregs_c4(acc, h, cH, p, q, SAh, SAl);
  __syncthreads();                       // h0 tile complete
  planes_out_c4(hSh, hSl, row0, M, lane, h, cH, SAh, SAl);

  f32x4v acc3[4];
  #pragma unroll
  for (int j = 0; j < 4; ++j) acc3[j] = (f32x4v){0.f, 0.f, 0.f, 0.f};
  gemm_c4(SAh, SAl, W1T0, acc3, h, cH * 4, p, q);
  store_c4(P, row0, M, acc3, h, cH, p, q);
  #pragma unroll
  for (int j = 0; j < 4; ++j) acc3[j] = (f32x4v){0.f, 0.f, 0.f, 0.f};
  gemm_c4(SAh, SAl, W1T0 + 32768, acc3, h, cH * 4, p, q);
  store_c4(Q, row0, M, acc3, h, cH, p, q);
}

// ---------------------------------------------------------------------------
// k_edge: 128-edge tiles, lb(256,3), inline gathers, 32-row LDS S-tile.
// (R11 verbatim — verified optimum.)
// ---------------------------------------------------------------------------
__global__ __launch_bounds__(256, 3) void k_edge(
    const float* __restrict__ sEa, const int* __restrict__ sSrc,
    const int* __restrict__ sDst,
    const int* __restrict__ rowStart, const int* __restrict__ deg,
    const float* __restrict__ ee_w1, const float* __restrict__ ee_b1,
    const float* __restrict__ ee_a,
    const bf16_t* __restrict__ WhatT, const float* __restrict__ bvec,
    const float* __restrict__ alpha_ptr,
    const float* __restrict__ P, const float* __restrict__ Q,
    float* __restrict__ S, int N, int E)
{
  __shared__ __align__(16) float Stile[32 * 132];     // 16.9 KB
  __shared__ __align__(16) float ew[640];             // ee_w1 + ee_b1
  __shared__ __align__(16) bf16_t Ast[128 * EST];     // 18.4 KB

  const int t = threadIdx.x, lane = t & 63, wave = t >> 6;
  const int p = lane & 15, q = lane >> 4;
  const int e0 = blockIdx.x * 128;
  const int dstLo = sDst[e0];

  for (int i = t; i < 640; i += 256)
    ew[i] = (i < 512) ? ee_w1[i] : ee_b1[i - 512];
  for (int i = t; i < 32 * 132; i += 256) Stile[i] = 0.f;
  __syncthreads();

  const float ua = *ee_a;
  const float alpha = *alpha_ptr;
  float bvc[8];
  ld8f(bvc, bvec, p);

  const int srow = wave * 32 + (lane >> 1);
  const int scb = (lane & 1) * 32;
  float4 eav = make_float4(0.f, 0.f, 0.f, 0.f);
  {
    int ed = e0 + srow;
    if (ed < E) eav = ld4(sEa + (size_t)ed * 4);
  }

  f32x4v acc[2][8];
  #pragma unroll
  for (int i = 0; i < 2; ++i)
    #pragma unroll
    for (int j = 0; j < 8; ++j) acc[i][j] = (f32x4v){0.f, 0.f, 0.f, 0.f};

  for (int c = 0; c < 2; ++c) {
    // stage U chunk (bf16-hi only), wave-private rows -> no barrier
    #pragma unroll
    for (int j = 0; j < 8; ++j) {
      int kc = scb + j * 4;
      int kg = c * 64 + kc;
      float4 w0 = ld4(ew + kg);
      float4 w1 = ld4(ew + 128 + kg);
      float4 w2 = ld4(ew + 256 + kg);
      float4 w3 = ld4(ew + 384 + kg);
      float4 bb = ld4(ew + 512 + kg);
      float ux = bb.x, uy = bb.y, uz = bb.z, uw = bb.w;
      ux = fmaf(eav.x, w0.x, ux); uy = fmaf(eav.x, w0.y, uy);
      uz = fmaf(eav.x, w0.z, uz); uw = fmaf(eav.x, w0.w, uw);
      ux = fmaf(eav.y, w1.x, ux); uy = fmaf(eav.y, w1.y, uy);
      uz = fmaf(eav.y, w1.z, uz); uw = fmaf(eav.y, w1.w, uw);
      ux = fmaf(eav.z, w2.x, ux); uy = fmaf(eav.z, w2.y, uy);
      uz = fmaf(eav.z, w2.z, uz); uw = fmaf(eav.z, w2.w, uw);
      ux = fmaf(eav.w, w3.x, ux); uy = fmaf(eav.w, w3.y, uy);
      uz = fmaf(eav.w, w3.z, uz); uw = fmaf(eav.w, w3.w, uw);
      *(bf16x4*)(Ast + srow * EST + kc) = (bf16x4){
          (bf16_t)prelu1(ux, ua), (bf16_t)prelu1(uy, ua),
          (bf16_t)prelu1(uz, ua), (bf16_t)prelu1(uw, ua)};
    }
    #pragma unroll
    for (int ks = 0; ks < 2; ++ks) {
      const int k0 = ks * 32 + q * 8;
      const int kg = c * 64 + k0;
      bf16x8 aH0 = ldb8(Ast + (wave * 32 + p) * EST + k0);
      bf16x8 aH1 = ldb8(Ast + (wave * 32 + 16 + p) * EST + k0);
      #pragma unroll
      for (int nt = 0; nt < 8; ++nt) {
        const bf16_t* bp = WhatT + (size_t)(nt * 16 + p) * 128 + kg;
        bf16x8 bH = ldb8(bp);
        bf16x8 bL = ldb8(bp + 16384);
        acc[0][nt] = mfma_bf16(aH0, bH, acc[0][nt]);
        acc[0][nt] = mfma_bf16(aH0, bL, acc[0][nt]);
        acc[1][nt] = mfma_bf16(aH1, bH, acc[1][nt]);
        acc[1][nt] = mfma_bf16(aH1, bL, acc[1][nt]);
      }
    }
  }

  // epilogue: run-reduce; indices loaded inline; P once per run (+bvec)
  #pragma unroll
  for (int mt = 0; mt < 2; ++mt) {
    float rs[8];
    #pragma unroll
    for (int nt = 0; nt < 8; ++nt) rs[nt] = 0.f;
    int curd = -1;
    float pv[8];
    #pragma unroll
    for (int nt = 0; nt < 8; ++nt) pv[nt] = 0.f;
    #pragma unroll
    for (int r = 0; r < 4; ++r) {
      int ed = e0 + wave * 32 + mt * 16 + q * 4 + r;
      if (ed < E) {
        int d = sDst[ed];
        int s = sSrc[ed];
        if (d != curd) {
          if (curd >= 0) {
            int rr = curd - dstLo;
            if (rr < 32) {
              #pragma unroll
              for (int nt = 0; nt < 8; ++nt)
                atomicAdd(&Stile[rr * 132 + p * 8 + nt], rs[nt]);
            } else {
              #pragma unroll
              for (int nt = 0; nt < 8; ++nt)
                atomicAddF(S + (size_t)curd * 128 + p * 8 + nt, rs[nt]);
            }
            #pragma unroll
            for (int nt = 0; nt < 8; ++nt) rs[nt] = 0.f;
          }
          curd = d;
          ld8f(pv, P + (size_t)d * 128, p);
          #pragma unroll
          for (int nt = 0; nt < 8; ++nt) pv[nt] += bvc[nt];
        }
        float qv[8];
        ld8f(qv, Q + (size_t)s * 128, p);
        #pragma unroll
        for (int nt = 0; nt < 8; ++nt) {
          float z = acc[mt][nt][r] + pv[nt] + qv[nt];
          rs[nt] += prelu1(z, alpha);
        }
      }
    }
    if (curd >= 0) {
      int rr = curd - dstLo;
      if (rr < 32) {
        #pragma unroll
        for (int nt = 0; nt < 8; ++nt)
          atomicAdd(&Stile[rr * 132 + p * 8 + nt], rs[nt]);
      } else {
        #pragma unroll
        for (int nt = 0; nt < 8; ++nt)
          atomicAddF(S + (size_t)curd * 128 + p * 8 + nt, rs[nt]);
      }
    }
  }
  __syncthreads();

  // writeback: interior rows plain-stored, boundary rows atomic
  const int lastE = (e0 + 127 < E) ? (e0 + 127) : (E - 1);
  const int dstHi = sDst[lastE];
  const int col4 = (t & 31) * 4;
  #pragma unroll
  for (int rr0 = 0; rr0 < 32; rr0 += 8) {
    int rr = rr0 + (t >> 5);
    int d = dstLo + rr;
    if (d <= dstHi && d < N) {
      float4 v = ld4(&Stile[rr * 132 + col4]);
      bool interior = (rowStart[d] >= e0) && (rowStart[d] + deg[d] <= e0 + 128);
      float* sp = S + (size_t)d * 128 + col4;
      if (interior) {
        st4(sp, v);
      } else {
        atomicAddF(sp + 0, v.x); atomicAddF(sp + 1, v.y);
        atomicAddF(sp + 2, v.z); atomicAddF(sp + 3, v.w);
      }
    }
  }
}

// ---------------------------------------------------------------------------
// k_dec: 128 thr / 32-row tiles. out = prelu(h@de_w1+de_b1)@de_w2 + de_b2.
// ---------------------------------------------------------------------------
__global__ __launch_bounds__(128, 4) void k_dec(
    const bf16_t* __restrict__ hSh, const bf16_t* __restrict__ hSl,
    const bf16_t* __restrict__ dw1T,
    const float* __restrict__ de_b1, const float* __restrict__ de_a,
    const float* __restrict__ de_w2, const float* __restrict__ de_b2,
    float* __restrict__ out, int M)
{
  __shared__ __align__(16) float Cs[32][132];
  __shared__ __align__(16) float w2s[384];
  const int t = threadIdx.x, lane = t & 63, wave = t >> 6;
  const int p = lane & 15, q = lane >> 4;
  const int row0 = blockIdx.x * 32;
  for (int i = t; i < 384; i += 128) w2s[i] = de_w2[i];

  f32x4v acc[8];
  #pragma unroll
  for (int j = 0; j < 8; ++j) acc[j] = (f32x4v){0.f, 0.f, 0.f, 0.f};
  const size_t ra = (size_t)(row0 + wave * 16 + p) * 128;
  #pragma unroll
  for (int ks = 0; ks < 4; ++ks) {
    const int k0 = ks * 32 + q * 8;
    bf16x8 aH = ldb8(hSh + ra + k0);
    bf16x8 aL = ldb8(hSl + ra + k0);
    #pragma unroll
    for (int nt = 0; nt < 8; ++nt) {
      const bf16_t* bp = dw1T + (size_t)(nt * 16 + p) * 128 + k0;
      mfma3(acc[nt], aH, aL, ldb8(bp), ldb8(bp + 16384));
    }
  }
  const float alpha = *de_a;
  float b1c[8];
  ld8f(b1c, de_b1, p);
  #pragma unroll
  for (int r = 0; r < 4; ++r) {
    int row = wave * 16 + q * 4 + r;
    float* cp = &Cs[row][p * 8];
    st4(cp, make_float4(prelu1(acc[0][r] + b1c[0], alpha),
                        prelu1(acc[1][r] + b1c[1], alpha),
                        prelu1(acc[2][r] + b1c[2], alpha),
                        prelu1(acc[3][r] + b1c[3], alpha)));
    st4(cp + 4, make_float4(prelu1(acc[4][r] + b1c[4], alpha),
                            prelu1(acc[5][r] + b1c[5], alpha),
                            prelu1(acc[6][r] + b1c[6], alpha),
                            prelu1(acc[7][r] + b1c[7], alpha)));
  }
  __syncthreads();
  if (t < 32) {
    float s0 = de_b2[0], s1 = de_b2[1], s2 = de_b2[2];
    for (int k = 0; k < 128; ++k) {
      float vv = Cs[t][k];
      s0 = fmaf(vv, w2s[k * 3 + 0], s0);
      s1 = fmaf(vv, w2s[k * 3 + 1], s1);
      s2 = fmaf(vv, w2s[k * 3 + 2], s2);
    }
    int row = row0 + t;
    if (row < M) {
      out[(size_t)row * 3 + 0] = s0;
      out[(size_t)row * 3 + 1] = s1;
      out[(size_t)row * 3 + 2] = s2;
    }
  }
}

// --------- weight prep: transpose+split with PERMUTED col mapping -----------
__global__ __launch_bounds__(256) void k_tsplit(
    const float* __restrict__ ne_w2, const float* __restrict__ de_w1,
    const float* __restrict__ le_w1, const float* __restrict__ ln_w1,
    const float* __restrict__ ln_w2, bf16_t* __restrict__ WT)
{
  int jid = blockIdx.x;
  const float* src; int slot;
  if (jid == 0)      { src = ne_w2; slot = 0; }
  else if (jid == 1) { src = de_w1; slot = 1; }
  else {
    int l = (jid - 2) >> 2, wj = (jid - 2) & 3;
    slot = 2 + l * 6 + wj;
    src = (wj == 0) ? le_w1 + (size_t)l * 49152
        : (wj == 1) ? le_w1 + (size_t)l * 49152 + 16384
        : (wj == 2) ? ln_w1 + (size_t)l * 32768
                    : ln_w2 + (size_t)l * 16384;
  }
  bf16_t* oh = WT + (size_t)slot * 32768;
  bf16_t* ol = oh + 16384;
  for (int idx = threadIdx.x; idx < 16384; idx += 256) {
    int k = idx >> 7, n = idx & 127;
    bf16_t hb, lb;
    split2(src[idx], hb, lb);
    int pos = ((n & 7) * 16 + (n >> 3)) * 128 + k;
    oh[pos] = hb;
    ol[pos] = lb;
  }
}

__global__ __launch_bounds__(256) void k_fold(
    const float* __restrict__ ee_w2, const float* __restrict__ ee_b2,
    const float* __restrict__ le_w1, const float* __restrict__ le_b1,
    const float* __restrict__ le_w2, const float* __restrict__ le_b2,
    const float* __restrict__ ln_w1,
    bf16_t* __restrict__ WT, float* __restrict__ bvec, float* __restrict__ btil)
{
  const int l = blockIdx.x;
  const int which = blockIdx.y;
  const int z = blockIdx.z;
  const float* L; const float* Rm; const float* lb; const float* badd;
  int slot; float* bout;
  if (which == 0) {
    L = ee_w2; Rm = le_w1 + (size_t)l * 49152 + 256 * 128;
    lb = ee_b2; badd = le_b1 + l * 128;
    slot = 2 + l * 6 + 4; bout = bvec + l * 128;
  } else {
    L = le_w2 + (size_t)l * 16384; Rm = ln_w1 + (size_t)l * 32768 + 128 * 128;
    lb = le_b2 + l * 128; badd = nullptr;
    slot = 2 + l * 6 + 5; bout = btil + l * 128;
  }
  bf16_t* oh = WT + (size_t)slot * 32768;
  bf16_t* ol = oh + 16384;
  const int t = threadIdx.x;
  const int base = z * 2048;
  for (int eidx = base + t; eidx < base + 2048; eidx += 256) {
    int k = eidx >> 7, n = eidx & 127;
    float a = 0.f;
    for (int d = 0; d < 128; d += 4) {
      float4 lv = ld4(L + k * 128 + d);
      a = fmaf(lv.x, Rm[(d + 0) * 128 + n], a);
      a = fmaf(lv.y, Rm[(d + 1) * 128 + n], a);
      a = fmaf(lv.z, Rm[(d + 2) * 128 + n], a);
      a = fmaf(lv.w, Rm[(d + 3) * 128 + n], a);
    }
    bf16_t hb, lbv;
    split2(a, hb, lbv);
    int pos = ((n & 7) * 16 + (n >> 3)) * 128 + k;
    oh[pos] = hb;
    ol[pos] = lbv;
  }
  if (z == 0 && t < 128) {
    float a = badd ? badd[t] : 0.f;
    for (int d = 0; d < 128; ++d) a = fmaf(lb[d], Rm[d * 128 + t], a);
    bout[t] = a;
  }
}

__global__ __launch_bounds__(256) void k_node_u(
    const float* __restrict__ x, const float* __restrict__ w1,
    const float* __restrict__ b1, const float* __restrict__ a_ptr,
    float* __restrict__ U, int M)
{
  int gid = blockIdx.x * 256 + threadIdx.x;
  int m = gid >> 5;
  if (m >= M) return;
  int nc = (gid & 31) << 2;
  float a = *a_ptr;
  float4 bb = ld4(b1 + nc);
  float z0 = bb.x, z1 = bb.y, z2 = bb.z, z3 = bb.w;
  const float* xr = x + (size_t)m * 30;
  #pragma unroll
  for (int j = 0; j < 30; ++j) {
    float xv = xr[j];
    float4 wv = ld4(w1 + j * 128 + nc);
    z0 = fmaf(xv, wv.x, z0); z1 = fmaf(xv, wv.y, z1);
    z2 = fmaf(xv, wv.z, z2); z3 = fmaf(xv, wv.w, z3);
  }
  st4(U + (size_t)m * 128 + nc,
      make_float4(prelu1(z0, a), prelu1(z1, a), prelu1(z2, a), prelu1(z3, a)));
}

// --------- counting sort by dst ---------------------------------------------
__global__ void k_hist(const int* __restrict__ dstIdx, int* __restrict__ deg, int E) {
  int i = blockIdx.x * 256 + threadIdx.x;
  if (i < E) atomicAdd(deg + dstIdx[i], 1);
}

__global__ __launch_bounds__(1024) void k_scan(
    const int* __restrict__ deg, int* __restrict__ cursor,
    int* __restrict__ rowStart, int N, int per)
{
  __shared__ int part[1024];
  const int t = threadIdx.x;
  const int base = t * per;
  int local = 0;
  for (int i = 0; i < per; ++i) {
    int idx = base + i;
    if (idx < N) local += deg[idx];
  }
  part[t] = local;
  __syncthreads();
  for (int off = 1; off < 1024; off <<= 1) {
    int v = (t >= off) ? part[t - off] : 0;
    __syncthreads();
    part[t] += v;
    __syncthreads();
  }
  int run = (t == 0) ? 0 : part[t - 1];
  for (int i = 0; i < per; ++i) {
    int idx = base + i;
    if (idx < N) {
      cursor[idx] = run;
      rowStart[idx] = run;
      run += deg[idx];
    }
  }
}

__global__ void k_scatter(const int* __restrict__ srcIdx, const int* __restrict__ dstIdx,
                          const float* __restrict__ ea, int* __restrict__ cursor,
                          int* __restrict__ sSrc, int* __restrict__ sDst,
                          float* __restrict__ sEa, int E)
{
  int e = blockIdx.x * 256 + threadIdx.x;
  if (e < E) {
    int d = dstIdx[e];
    int p = atomicAdd(cursor + d, 1);
    sSrc[p] = srcIdx[e];
    sDst[p] = d;
    st4(sEa + (size_t)p * 4, ld4(ea + (size_t)e * 4));
  }
}

// ---------------------------------------------------------------------------
extern "C" void kernel_launch(void* const* d_in, const int* in_sizes, int n_in,
                              void* d_out, int out_size, void* d_ws, size_t ws_size,
                              hipStream_t stream)
{
  const float* x     = (const float*)d_in[0];
  const float* ea    = (const float*)d_in[1];
  const int*   ei    = (const int*)  d_in[2];
  const float* ne_w1 = (const float*)d_in[3];
  const float* ne_b1 = (const float*)d_in[4];
  const float* ne_a  = (const float*)d_in[5];
  const float* ne_w2 = (const float*)d_in[6];
  const float* ne_b2 = (const float*)d_in[7];
  const float* ee_w1 = (const float*)d_in[8];
  const float* ee_b1 = (const float*)d_in[9];
  const float* ee_a  = (const float*)d_in[10];
  const float* ee_w2 = (const float*)d_in[11];
  const float* ee_b2 = (const float*)d_in[12];
  const float* le_w1 = (const float*)d_in[13];
  const float* le_b1 = (const float*)d_in[14];
  const float* le_a  = (const float*)d_in[15];
  const float* le_w2 = (const float*)d_in[16];
  const float* le_b2 = (const float*)d_in[17];
  const float* ln_w1 = (const float*)d_in[18];
  const float* ln_b1 = (const float*)d_in[19];
  const float* ln_a  = (const float*)d_in[20];
  const float* ln_w2 = (const float*)d_in[21];
  const float* ln_b2 = (const float*)d_in[22];
  const float* de_w1 = (const float*)d_in[23];
  const float* de_b1 = (const float*)d_in[24];
  const float* de_a  = (const float*)d_in[25];
  const float* de_w2 = (const float*)d_in[26];
  const float* de_b2 = (const float*)d_in[27];

  const int N = in_sizes[0] / 30;
  const int E = in_sizes[1] / 4;
  const int* srcIdx = ei;        // edge_index[0] = x_j (source)
  const int* dstIdx = ei + E;    // edge_index[1] = x_i (target / agg index)

  const int g32 = (N + 31) / 32;        // node tiles
  const int gE  = (E + 127) / 128;      // 128-edge tiles
  const int Np = g32 * 32;
  const size_t NNp = (size_t)Np * 128;

  float* w = (float*)d_ws;
  float* Pb   = w; w += NNp;
  float* Qb   = w; w += NNp;
  float* Sb   = w; w += NNp;               // also UN before the loop
  float* bvec = w; w += 5 * 128;
  float* btil = w; w += 5 * 128;
  float* sEa  = w; w += (size_t)E * 4;
  bf16_t* hSh = (bf16_t*)w;
  bf16_t* hSl = hSh + NNp;  w += NNp;      // 2 bf16 planes
  bf16_t* WT  = (bf16_t*)w; w += 32 * 32768 / 2;
  int* ip     = (int*)w;
  int* deg    = ip; ip += N;
  int* cursor = ip; ip += N;
  int* rowStart = ip; ip += N;
  int* sSrc   = ip; ip += E;
  int* sDst   = ip; ip += E;

  float* out = (float*)d_out;

  // weight prep + sort
  k_tsplit<<<dim3(22), dim3(256), 0, stream>>>(ne_w2, de_w1, le_w1, ln_w1, ln_w2, WT);
  k_fold<<<dim3(5, 2, 8), dim3(256), 0, stream>>>(ee_w2, ee_b2, le_w1, le_b1,
                                                  le_w2, le_b2, ln_w1, WT, bvec, btil);
  hipMemsetAsync(deg, 0, (size_t)N * 4, stream);
  k_hist<<<dim3((E + 255) / 256), dim3(256), 0, stream>>>(dstIdx, deg, E);
  k_scan<<<dim3(1), dim3(1024), 0, stream>>>(deg, cursor, rowStart, N,
                                             (N + 1023) / 1024);
  k_scatter<<<dim3((E + 255) / 256), dim3(256), 0, stream>>>(
      srcIdx, dstIdx, ea, cursor, sSrc, sDst, sEa, E);

  // encoder (+ P/Q for layer 0)
  k_node_u<<<dim3((N * 32 + 255) / 256), dim3(256), 0, stream>>>(x, ne_w1, ne_b1, ne_a, Sb, N);
  k_enc<<<dim3(g32), dim3(256), 0, stream>>>(Sb, WT, ne_b2, WT + 2 * 32768,
                                             hSh, hSl, Pb, Qb, N);

  // one-time zero of S (k_svu keeps it zeroed thereafter)
  hipMemsetAsync(Sb, 0, (size_t)N * 128 * 4, stream);

  for (int l = 0; l < 5; ++l) {
    const bf16_t* slotL = WT + (size_t)(2 + l * 6) * 32768;
    k_edge<<<dim3(gE), dim3(256), 0, stream>>>(
        sEa, sSrc, sDst, rowStart, deg, ee_w1, ee_b1, ee_a,
        slotL + 4 * 32768, bvec + l * 128, le_a + l, Pb, Qb, Sb, N, E);
    const bf16_t* W1next = (l < 4) ? (WT + (size_t)(2 + (l + 1) * 6) * 32768) : WT;
    k_svu<<<dim3(g32), dim3(256), 0, stream>>>(
        Sb, hSh, hSl, slotL + 5 * 32768, slotL + 2 * 32768, slotL + 3 * 32768,
        W1next, ln_b1 + (size_t)l * 128, btil + l * 128, deg, ln_a + l,
        ln_b2 + (size_t)l * 128, Pb, Qb, (l < 4) ? 1 : 0, N);
  }

  k_dec<<<dim3(g32), dim3(128), 0, stream>>>(hSh, hSl, WT + 32768, de_b1, de_a,
                                             de_w2, de_b2, out, N);
}

// Round 4
// 1333.774 us; speedup vs baseline: 1.0740x; 1.0254x over previous
//
#include <hip/hip_runtime.h>
#include <cstdint>
#include <cstddef>

// ---------------------------------------------------------------------------
// GNS model. R19 = R18 + full-grid residency for k_svu/k_enc (lb 2->3) +
// parallelized prep kernels (k_tsplit x8, k_fold x4).
// Evidence log:
//  - k_edge: 128-edge tiles, lb(256,3); R11 structure verbatim (verified
//    optimum: 162 us, F68/W18, VGPR 68). R16 reg-pipeline and R17 LDS-DMA
//    epilogue restructures both spilled and moved dur only +-3% -> epilogue
//    gathers are not the dominant k_edge cost. Do not touch.
//  - R18: k_svu/k_enc 2-wave -> 4-wave (rows x col-half) = +29 us total.
//  - R19a: lb(256,2) gave only 512 resident block slots for a 625-block
//    grid -> 113-block tail generation on all 6 node-side dispatches.
//    lb(256,3) = 768 slots -> whole grid co-resident (VGPR cap 170, safe).
//  - R19b: k_tsplit ran 22 blocks, k_fold 80 blocks (0.1-0.3 waves/SIMD,
//    latency-bound). Repartitioned to 176 / 320 blocks.
//  - P hoisted once per dst-run (+bvec folded); permuted-column C layout
//    (weight slots: output col n = p*8 + nt').
//  - LDS S-tile, interior plain stores + boundary atomics; dst-sorted edges.
//  - All GEMMs split-bf16 MFMA (AhBh+AlBh+AhBl), edge-U hi-only.
// ---------------------------------------------------------------------------

#define DEVI static __device__ __forceinline__

typedef __bf16 bf16_t;
typedef bf16_t bf16x8 __attribute__((ext_vector_type(8)));
typedef bf16_t bf16x4 __attribute__((ext_vector_type(4)));
typedef float f32x4v __attribute__((ext_vector_type(4)));

DEVI float4 ld4(const float* p) { return *(const float4*)p; }
DEVI void st4(float* p, float4 v) { *(float4*)p = v; }
DEVI float prelu1(float z, float a) { return z > 0.f ? z : a * z; }
DEVI void atomicAddF(float* p, float v) {
  __hip_atomic_fetch_add(p, v, __ATOMIC_RELAXED, __HIP_MEMORY_SCOPE_AGENT);
}
DEVI f32x4v mfma_bf16(bf16x8 a, bf16x8 b, f32x4v c) {
  return __builtin_amdgcn_mfma_f32_16x16x32_bf16(a, b, c, 0, 0, 0);
}
DEVI void mfma3(f32x4v& acc, bf16x8 ah, bf16x8 al, bf16x8 bh, bf16x8 bl) {
  acc = mfma_bf16(ah, bh, acc);
  acc = mfma_bf16(al, bh, acc);
  acc = mfma_bf16(ah, bl, acc);
}
DEVI void split2(float x, bf16_t& h, bf16_t& l) {
  h = (bf16_t)x;
  l = (bf16_t)(x - (float)h);
}
DEVI bf16x8 ldb8(const bf16_t* p) { return *(const bf16x8*)p; }

#define NST 136   // node staging row stride (bf16)
#define EST 72    // edge staging row stride (bf16)

// ======== 4-wave node tile building blocks ================================
// wave (h = wave&1) owns rows h*16..h*16+15; (cH = wave>>1) owns col-half
// cH*64..cH*64+63 (column tiles nt' = cH*4 + nt, nt in 0..3).

DEVI void stage_f32_c4(const float* __restrict__ src, int row0, int M,
                       int lane, int h, int cH, bf16_t* SAh, bf16_t* SAl)
{
  const int row = h * 16 + (lane >> 2);
  const int grow = row0 + row;
  const int colbase = cH * 64 + (lane & 3) * 16;
  #pragma unroll
  for (int j = 0; j < 4; ++j) {
    int kc = colbase + j * 4;
    float4 v = make_float4(0.f, 0.f, 0.f, 0.f);
    if (grow < M) v = ld4(src + (size_t)grow * 128 + kc);
    bf16_t h0,l0,h1,l1,h2,l2,h3,l3;
    split2(v.x,h0,l0); split2(v.y,h1,l1); split2(v.z,h2,l2); split2(v.w,h3,l3);
    *(bf16x4*)(SAh + row * NST + kc) = (bf16x4){h0,h1,h2,h3};
    *(bf16x4*)(SAl + row * NST + kc) = (bf16x4){l0,l1,l2,l3};
  }
}

DEVI void stage_planes_c4(const bf16_t* __restrict__ gh, const bf16_t* __restrict__ gl,
                          int row0, int M, int lane, int h, int cH,
                          bf16_t* SAh, bf16_t* SAl)
{
  const int row = h * 16 + (lane >> 2);
  const int grow = row0 + row;
  const int colbase = cH * 64 + (lane & 3) * 16;
  #pragma unroll
  for (int j = 0; j < 2; ++j) {
    int kc = colbase + j * 8;
    bf16x8 vh = {};
    bf16x8 vl = {};
    if (grow < M) {
      vh = ldb8(gh + (size_t)grow * 128 + kc);
      vl = ldb8(gl + (size_t)grow * 128 + kc);
    }
    *(bf16x8*)(SAh + row * NST + kc) = vh;
    *(bf16x8*)(SAl + row * NST + kc) = vl;
  }
}

// acc[4] over column tiles ntb..ntb+3; A rows h*16..+15 (full K=128)
DEVI void gemm_c4(const bf16_t* SAh, const bf16_t* SAl,
                  const bf16_t* __restrict__ BT, f32x4v acc[4],
                  int h, int ntb, int p, int q)
{
  #pragma unroll
  for (int ks = 0; ks < 4; ++ks) {
    const int k0 = ks * 32 + q * 8;
    bf16x8 aH = ldb8(SAh + (h * 16 + p) * NST + k0);
    bf16x8 aL = ldb8(SAl + (h * 16 + p) * NST + k0);
    #pragma unroll
    for (int nt = 0; nt < 4; ++nt) {
      const bf16_t* bp = BT + (size_t)((ntb + nt) * 16 + p) * 128 + k0;
      mfma3(acc[nt], aH, aL, ldb8(bp), ldb8(bp + 16384));
    }
  }
}

DEVI void store_c4(float* __restrict__ O, int row0, int M,
                   const f32x4v acc[4], int h, int cH, int p, int q)
{
  int rb = row0 + h * 16 + q * 4;
  #pragma unroll
  for (int r = 0; r < 4; ++r) {
    if (rb + r < M) {
      float* op = O + (size_t)(rb + r) * 128 + p * 8 + cH * 4;
      st4(op, make_float4(acc[0][r], acc[1][r], acc[2][r], acc[3][r]));
    }
  }
}

DEVI void stage_cregs_c4(const f32x4v acc[4], int h, int cH, int p, int q,
                         bf16_t* SAh, bf16_t* SAl)
{
  #pragma unroll
  for (int r = 0; r < 4; ++r) {
    int row = h * 16 + q * 4 + r;
    bf16x4 vh, vl;
    #pragma unroll
    for (int nt = 0; nt < 4; ++nt) {
      bf16_t hb, lb;
      split2(acc[nt][r], hb, lb);
      vh[nt] = hb; vl[nt] = lb;
    }
    *(bf16x4*)(SAh + row * NST + p * 8 + cH * 4) = vh;
    *(bf16x4*)(SAl + row * NST + p * 8 + cH * 4) = vl;
  }
}

DEVI void planes_out_c4(bf16_t* __restrict__ gh, bf16_t* __restrict__ gl,
                        int row0, int M, int lane, int h, int cH,
                        const bf16_t* SAh, const bf16_t* SAl)
{
  const int row = h * 16 + (lane >> 2);
  const int grow = row0 + row;
  const int colbase = cH * 64 + (lane & 3) * 16;
  if (grow < M) {
    #pragma unroll
    for (int j = 0; j < 2; ++j) {
      int kc = colbase + j * 8;
      *(bf16x8*)(gh + (size_t)grow * 128 + kc) = *(const bf16x8*)(SAh + row * NST + kc);
      *(bf16x8*)(gl + (size_t)grow * 128 + kc) = *(const bf16x8*)(SAl + row * NST + kc);
    }
  }
}

DEVI void ld8f(float dst[8], const float* __restrict__ src, int p) {
  *(float4*)(dst)     = ld4(src + p * 8);
  *(float4*)(dst + 4) = ld4(src + p * 8 + 4);
}

DEVI void ld4f(float dst[4], const float* __restrict__ src, int p, int cH) {
  *(float4*)(dst) = ld4(src + p * 8 + cH * 4);
}

// ---------------------------------------------------------------------------
// k_svu: 256 thr / 32-row tiles, 4 waves (rows x col-half split). Node update
// + P/Q for next layer; zeroes consumed S rows. lb(256,3): 625-block grid
// fully co-resident (768 slots).
// ---------------------------------------------------------------------------
__global__ __launch_bounds__(256, 3) void k_svu(
    float* Sbuf,                      // read then zeroed (same buffer)
    bf16_t* __restrict__ hSh, bf16_t* __restrict__ hSl,
    const bf16_t* __restrict__ WtilT, const bf16_t* __restrict__ Wn1aT,
    const bf16_t* __restrict__ lnw2T, const bf16_t* __restrict__ W1nextT,
    const float* __restrict__ ln_b1_l, const float* __restrict__ btil_l,
    const int* __restrict__ deg, const float* __restrict__ ln_a_l,
    const float* __restrict__ ln_b2_l,
    float* __restrict__ P, float* __restrict__ Q, int doPQ, int M)
{
  __shared__ __align__(16) bf16_t SAh[32 * NST];
  __shared__ __align__(16) bf16_t SAl[32 * NST];
  const int t = threadIdx.x, lane = t & 63, wave = t >> 6;
  const int h = wave & 1, cH = wave >> 1;
  const int p = lane & 15, q = lane >> 4;
  const int row0 = blockIdx.x * 32;

  f32x4v acc1[4];
  #pragma unroll
  for (int j = 0; j < 4; ++j) acc1[j] = (f32x4v){0.f, 0.f, 0.f, 0.f};

  stage_f32_c4(Sbuf, row0, M, lane, h, cH, SAh, SAl);
  // zero consumed S cells (per-lane same addresses as the loads -> ordered)
  {
    const int row = h * 16 + (lane >> 2);
    const int grow = row0 + row;
    const int colbase = cH * 64 + (lane & 3) * 16;
    if (grow < M) {
      float4 z4 = make_float4(0.f, 0.f, 0.f, 0.f);
      #pragma unroll
      for (int j = 0; j < 4; ++j)
        st4(Sbuf + (size_t)grow * 128 + colbase + j * 4, z4);
    }
  }
  __syncthreads();                       // S tile complete
  gemm_c4(SAh, SAl, WtilT, acc1, h, cH * 4, p, q);
  __syncthreads();                       // all S reads done before h overwrite
  stage_planes_c4(hSh, hSl, row0, M, lane, h, cH, SAh, SAl);
  __syncthreads();                       // h tile complete
  gemm_c4(SAh, SAl, Wn1aT, acc1, h, cH * 4, p, q);

  // h_old (feature-linear layout) from LDS — this wave's 4 cols
  float hold[4][4];
  #pragma unroll
  for (int r = 0; r < 4; ++r) {
    int row = h * 16 + q * 4 + r;
    bf16x4 vh = *(const bf16x4*)(SAh + row * NST + p * 8 + cH * 4);
    bf16x4 vl = *(const bf16x4*)(SAl + row * NST + p * 8 + cH * 4);
    #pragma unroll
    for (int nt = 0; nt < 4; ++nt)
      hold[nt][r] = (float)vh[nt] + (float)vl[nt];
  }
  __syncthreads();                       // all h reads done before V overwrite

  // V = prelu(acc1 + b1 + deg*btil)
  const float alpha = *ln_a_l;
  float degf[4];
  #pragma unroll
  for (int r = 0; r < 4; ++r) {
    int row = row0 + h * 16 + q * 4 + r;
    degf[r] = (row < M) ? (float)deg[row] : 0.f;
  }
  float b1c[4], btc[4];
  ld4f(b1c, ln_b1_l, p, cH);
  ld4f(btc, btil_l, p, cH);
  #pragma unroll
  for (int nt = 0; nt < 4; ++nt)
    #pragma unroll
    for (int r = 0; r < 4; ++r)
      acc1[nt][r] = prelu1(acc1[nt][r] + b1c[nt] + degf[r] * btc[nt], alpha);

  stage_cregs_c4(acc1, h, cH, p, q, SAh, SAl);   // V
  __syncthreads();                       // V tile complete
  f32x4v acc2[4];
  #pragma unroll
  for (int j = 0; j < 4; ++j) acc2[j] = (f32x4v){0.f, 0.f, 0.f, 0.f};
  gemm_c4(SAh, SAl, lnw2T, acc2, h, cH * 4, p, q);
  __syncthreads();                       // all V reads done before h_new overwrite

  // h_new = h_old + acc2 + b2
  float b2c[4];
  ld4f(b2c, ln_b2_l, p, cH);
  #pragma unroll
  for (int nt = 0; nt < 4; ++nt)
    #pragma unroll
    for (int r = 0; r < 4; ++r)
      acc2[nt][r] = hold[nt][r] + acc2[nt][r] + b2c[nt];

  stage_cregs_c4(acc2, h, cH, p, q, SAh, SAl);   // h_new
  __syncthreads();                       // h_new tile complete
  planes_out_c4(hSh, hSl, row0, M, lane, h, cH, SAh, SAl);

  if (doPQ) {
    f32x4v acc3[4];
    #pragma unroll
    for (int j = 0; j < 4; ++j) acc3[j] = (f32x4v){0.f, 0.f, 0.f, 0.f};
    gemm_c4(SAh, SAl, W1nextT, acc3, h, cH * 4, p, q);
    store_c4(P, row0, M, acc3, h, cH, p, q);
    #pragma unroll
    for (int j = 0; j < 4; ++j) acc3[j] = (f32x4v){0.f, 0.f, 0.f, 0.f};
    gemm_c4(SAh, SAl, W1nextT + 32768, acc3, h, cH * 4, p, q);
    store_c4(Q, row0, M, acc3, h, cH, p, q);
  }
}

// ---------------------------------------------------------------------------
// k_enc: 256 thr / 32-row tiles, 4 waves, lb(256,3). h0 = UN@ne_w2 + b2 ->
// planes; + P/Q layer 0.
// ---------------------------------------------------------------------------
__global__ __launch_bounds__(256, 3) void k_enc(
    const float* __restrict__ UN, const bf16_t* __restrict__ new2T,
    const float* __restrict__ b2, const bf16_t* __restrict__ W1T0,
    bf16_t* __restrict__ hSh, bf16_t* __restrict__ hSl,
    float* __restrict__ P, float* __restrict__ Q, int M)
{
  __shared__ __align__(16) bf16_t SAh[32 * NST];
  __shared__ __align__(16) bf16_t SAl[32 * NST];
  const int t = threadIdx.x, lane = t & 63, wave = t >> 6;
  const int h = wave & 1, cH = wave >> 1;
  const int p = lane & 15, q = lane >> 4;
  const int row0 = blockIdx.x * 32;

  f32x4v acc[4];
  #pragma unroll
  for (int j = 0; j < 4; ++j) acc[j] = (f32x4v){0.f, 0.f, 0.f, 0.f};
  stage_f32_c4(UN, row0, M, lane, h, cH, SAh, SAl);
  __syncthreads();                       // UN tile complete
  gemm_c4(SAh, SAl, new2T, acc, h, cH * 4, p, q);
  __syncthreads();                       // all UN reads done before h0 overwrite
  float b2c[4];
  ld4f(b2c, b2, p, cH);
  #pragma unroll
  for (int nt = 0; nt < 4; ++nt)
    #pragma unroll
    for (int r = 0; r < 4; ++r) acc[nt][r] += b2c[nt];
  stage_cregs_c4(acc, h, cH, p, q, SAh, SAl);
  __syncthreads();                       // h0 tile complete
  planes_out_c4(hSh, hSl, row0, M, lane, h, cH, SAh, SAl);

  f32x4v acc3[4];
  #pragma unroll
  for (int j = 0; j < 4; ++j) acc3[j] = (f32x4v){0.f, 0.f, 0.f, 0.f};
  gemm_c4(SAh, SAl, W1T0, acc3, h, cH * 4, p, q);
  store_c4(P, row0, M, acc3, h, cH, p, q);
  #pragma unroll
  for (int j = 0; j < 4; ++j) acc3[j] = (f32x4v){0.f, 0.f, 0.f, 0.f};
  gemm_c4(SAh, SAl, W1T0 + 32768, acc3, h, cH * 4, p, q);
  store_c4(Q, row0, M, acc3, h, cH, p, q);
}

// ---------------------------------------------------------------------------
// k_edge: 128-edge tiles, lb(256,3), inline gathers, 32-row LDS S-tile.
// (R11 verbatim — verified optimum. DO NOT TOUCH.)
// ---------------------------------------------------------------------------
__global__ __launch_bounds__(256, 3) void k_edge(
    const float* __restrict__ sEa, const int* __restrict__ sSrc,
    const int* __restrict__ sDst,
    const int* __restrict__ rowStart, const int* __restrict__ deg,
    const float* __restrict__ ee_w1, const float* __restrict__ ee_b1,
    const float* __restrict__ ee_a,
    const bf16_t* __restrict__ WhatT, const float* __restrict__ bvec,
    const float* __restrict__ alpha_ptr,
    const float* __restrict__ P, const float* __restrict__ Q,
    float* __restrict__ S, int N, int E)
{
  __shared__ __align__(16) float Stile[32 * 132];     // 16.9 KB
  __shared__ __align__(16) float ew[640];             // ee_w1 + ee_b1
  __shared__ __align__(16) bf16_t Ast[128 * EST];     // 18.4 KB

  const int t = threadIdx.x, lane = t & 63, wave = t >> 6;
  const int p = lane & 15, q = lane >> 4;
  const int e0 = blockIdx.x * 128;
  const int dstLo = sDst[e0];

  for (int i = t; i < 640; i += 256)
    ew[i] = (i < 512) ? ee_w1[i] : ee_b1[i - 512];
  for (int i = t; i < 32 * 132; i += 256) Stile[i] = 0.f;
  __syncthreads();

  const float ua = *ee_a;
  const float alpha = *alpha_ptr;
  float bvc[8];
  ld8f(bvc, bvec, p);

  const int srow = wave * 32 + (lane >> 1);
  const int scb = (lane & 1) * 32;
  float4 eav = make_float4(0.f, 0.f, 0.f, 0.f);
  {
    int ed = e0 + srow;
    if (ed < E) eav = ld4(sEa + (size_t)ed * 4);
  }

  f32x4v acc[2][8];
  #pragma unroll
  for (int i = 0; i < 2; ++i)
    #pragma unroll
    for (int j = 0; j < 8; ++j) acc[i][j] = (f32x4v){0.f, 0.f, 0.f, 0.f};

  for (int c = 0; c < 2; ++c) {
    // stage U chunk (bf16-hi only), wave-private rows -> no barrier
    #pragma unroll
    for (int j = 0; j < 8; ++j) {
      int kc = scb + j * 4;
      int kg = c * 64 + kc;
      float4 w0 = ld4(ew + kg);
      float4 w1 = ld4(ew + 128 + kg);
      float4 w2 = ld4(ew + 256 + kg);
      float4 w3 = ld4(ew + 384 + kg);
      float4 bb = ld4(ew + 512 + kg);
      float ux = bb.x, uy = bb.y, uz = bb.z, uw = bb.w;
      ux = fmaf(eav.x, w0.x, ux); uy = fmaf(eav.x, w0.y, uy);
      uz = fmaf(eav.x, w0.z, uz); uw = fmaf(eav.x, w0.w, uw);
      ux = fmaf(eav.y, w1.x, ux); uy = fmaf(eav.y, w1.y, uy);
      uz = fmaf(eav.y, w1.z, uz); uw = fmaf(eav.y, w1.w, uw);
      ux = fmaf(eav.z, w2.x, ux); uy = fmaf(eav.z, w2.y, uy);
      uz = fmaf(eav.z, w2.z, uz); uw = fmaf(eav.z, w2.w, uw);
      ux = fmaf(eav.w, w3.x, ux); uy = fmaf(eav.w, w3.y, uy);
      uz = fmaf(eav.w, w3.z, uz); uw = fmaf(eav.w, w3.w, uw);
      *(bf16x4*)(Ast + srow * EST + kc) = (bf16x4){
          (bf16_t)prelu1(ux, ua), (bf16_t)prelu1(uy, ua),
          (bf16_t)prelu1(uz, ua), (bf16_t)prelu1(uw, ua)};
    }
    #pragma unroll
    for (int ks = 0; ks < 2; ++ks) {
      const int k0 = ks * 32 + q * 8;
      const int kg = c * 64 + k0;
      bf16x8 aH0 = ldb8(Ast + (wave * 32 + p) * EST + k0);
      bf16x8 aH1 = ldb8(Ast + (wave * 32 + 16 + p) * EST + k0);
      #pragma unroll
      for (int nt = 0; nt < 8; ++nt) {
        const bf16_t* bp = WhatT + (size_t)(nt * 16 + p) * 128 + kg;
        bf16x8 bH = ldb8(bp);
        bf16x8 bL = ldb8(bp + 16384);
        acc[0][nt] = mfma_bf16(aH0, bH, acc[0][nt]);
        acc[0][nt] = mfma_bf16(aH0, bL, acc[0][nt]);
        acc[1][nt] = mfma_bf16(aH1, bH, acc[1][nt]);
        acc[1][nt] = mfma_bf16(aH1, bL, acc[1][nt]);
      }
    }
  }

  // epilogue: run-reduce; indices loaded inline; P once per run (+bvec)
  #pragma unroll
  for (int mt = 0; mt < 2; ++mt) {
    float rs[8];
    #pragma unroll
    for (int nt = 0; nt < 8; ++nt) rs[nt] = 0.f;
    int curd = -1;
    float pv[8];
    #pragma unroll
    for (int nt = 0; nt < 8; ++nt) pv[nt] = 0.f;
    #pragma unroll
    for (int r = 0; r < 4; ++r) {
      int ed = e0 + wave * 32 + mt * 16 + q * 4 + r;
      if (ed < E) {
        int d = sDst[ed];
        int s = sSrc[ed];
        if (d != curd) {
          if (curd >= 0) {
            int rr = curd - dstLo;
            if (rr < 32) {
              #pragma unroll
              for (int nt = 0; nt < 8; ++nt)
                atomicAdd(&Stile[rr * 132 + p * 8 + nt], rs[nt]);
            } else {
              #pragma unroll
              for (int nt = 0; nt < 8; ++nt)
                atomicAddF(S + (size_t)curd * 128 + p * 8 + nt, rs[nt]);
            }
            #pragma unroll
            for (int nt = 0; nt < 8; ++nt) rs[nt] = 0.f;
          }
          curd = d;
          ld8f(pv, P + (size_t)d * 128, p);
          #pragma unroll
          for (int nt = 0; nt < 8; ++nt) pv[nt] += bvc[nt];
        }
        float qv[8];
        ld8f(qv, Q + (size_t)s * 128, p);
        #pragma unroll
        for (int nt = 0; nt < 8; ++nt) {
          float z = acc[mt][nt][r] + pv[nt] + qv[nt];
          rs[nt] += prelu1(z, alpha);
        }
      }
    }
    if (curd >= 0) {
      int rr = curd - dstLo;
      if (rr < 32) {
        #pragma unroll
        for (int nt = 0; nt < 8; ++nt)
          atomicAdd(&Stile[rr * 132 + p * 8 + nt], rs[nt]);
      } else {
        #pragma unroll
        for (int nt = 0; nt < 8; ++nt)
          atomicAddF(S + (size_t)curd * 128 + p * 8 + nt, rs[nt]);
      }
    }
  }
  __syncthreads();

  // writeback: interior rows plain-stored, boundary rows atomic
  const int lastE = (e0 + 127 < E) ? (e0 + 127) : (E - 1);
  const int dstHi = sDst[lastE];
  const int col4 = (t & 31) * 4;
  #pragma unroll
  for (int rr0 = 0; rr0 < 32; rr0 += 8) {
    int rr = rr0 + (t >> 5);
    int d = dstLo + rr;
    if (d <= dstHi && d < N) {
      float4 v = ld4(&Stile[rr * 132 + col4]);
      bool interior = (rowStart[d] >= e0) && (rowStart[d] + deg[d] <= e0 + 128);
      float* sp = S + (size_t)d * 128 + col4;
      if (interior) {
        st4(sp, v);
      } else {
        atomicAddF(sp + 0, v.x); atomicAddF(sp + 1, v.y);
        atomicAddF(sp + 2, v.z); atomicAddF(sp + 3, v.w);
      }
    }
  }
}

// ---------------------------------------------------------------------------
// k_dec: 128 thr / 32-row tiles. out = prelu(h@de_w1+de_b1)@de_w2 + de_b2.
// ---------------------------------------------------------------------------
__global__ __launch_bounds__(128, 4) void k_dec(
    const bf16_t* __restrict__ hSh, const bf16_t* __restrict__ hSl,
    const bf16_t* __restrict__ dw1T,
    const float* __restrict__ de_b1, const float* __restrict__ de_a,
    const float* __restrict__ de_w2, const float* __restrict__ de_b2,
    float* __restrict__ out, int M)
{
  __shared__ __align__(16) float Cs[32][132];
  __shared__ __align__(16) float w2s[384];
  const int t = threadIdx.x, lane = t & 63, wave = t >> 6;
  const int p = lane & 15, q = lane >> 4;
  const int row0 = blockIdx.x * 32;
  for (int i = t; i < 384; i += 128) w2s[i] = de_w2[i];

  f32x4v acc[8];
  #pragma unroll
  for (int j = 0; j < 8; ++j) acc[j] = (f32x4v){0.f, 0.f, 0.f, 0.f};
  const size_t ra = (size_t)(row0 + wave * 16 + p) * 128;
  #pragma unroll
  for (int ks = 0; ks < 4; ++ks) {
    const int k0 = ks * 32 + q * 8;
    bf16x8 aH = ldb8(hSh + ra + k0);
    bf16x8 aL = ldb8(hSl + ra + k0);
    #pragma unroll
    for (int nt = 0; nt < 8; ++nt) {
      const bf16_t* bp = dw1T + (size_t)(nt * 16 + p) * 128 + k0;
      mfma3(acc[nt], aH, aL, ldb8(bp), ldb8(bp + 16384));
    }
  }
  const float alpha = *de_a;
  float b1c[8];
  ld8f(b1c, de_b1, p);
  #pragma unroll
  for (int r = 0; r < 4; ++r) {
    int row = wave * 16 + q * 4 + r;
    float* cp = &Cs[row][p * 8];
    st4(cp, make_float4(prelu1(acc[0][r] + b1c[0], alpha),
                        prelu1(acc[1][r] + b1c[1], alpha),
                        prelu1(acc[2][r] + b1c[2], alpha),
                        prelu1(acc[3][r] + b1c[3], alpha)));
    st4(cp + 4, make_float4(prelu1(acc[4][r] + b1c[4], alpha),
                            prelu1(acc[5][r] + b1c[5], alpha),
                            prelu1(acc[6][r] + b1c[6], alpha),
                            prelu1(acc[7][r] + b1c[7], alpha)));
  }
  __syncthreads();
  if (t < 32) {
    float s0 = de_b2[0], s1 = de_b2[1], s2 = de_b2[2];
    for (int k = 0; k < 128; ++k) {
      float vv = Cs[t][k];
      s0 = fmaf(vv, w2s[k * 3 + 0], s0);
      s1 = fmaf(vv, w2s[k * 3 + 1], s1);
      s2 = fmaf(vv, w2s[k * 3 + 2], s2);
    }
    int row = row0 + t;
    if (row < M) {
      out[(size_t)row * 3 + 0] = s0;
      out[(size_t)row * 3 + 1] = s1;
      out[(size_t)row * 3 + 2] = s2;
    }
  }
}

// --------- weight prep: transpose+split with PERMUTED col mapping -----------
// R19: parallelized — grid (22, 8); each block handles 2048 elements.
__global__ __launch_bounds__(256) void k_tsplit(
    const float* __restrict__ ne_w2, const float* __restrict__ de_w1,
    const float* __restrict__ le_w1, const float* __restrict__ ln_w1,
    const float* __restrict__ ln_w2, bf16_t* __restrict__ WT)
{
  int jid = blockIdx.x;
  const float* src; int slot;
  if (jid == 0)      { src = ne_w2; slot = 0; }
  else if (jid == 1) { src = de_w1; slot = 1; }
  else {
    int l = (jid - 2) >> 2, wj = (jid - 2) & 3;
    slot = 2 + l * 6 + wj;
    src = (wj == 0) ? le_w1 + (size_t)l * 49152
        : (wj == 1) ? le_w1 + (size_t)l * 49152 + 16384
        : (wj == 2) ? ln_w1 + (size_t)l * 32768
                    : ln_w2 + (size_t)l * 16384;
  }
  bf16_t* oh = WT + (size_t)slot * 32768;
  bf16_t* ol = oh + 16384;
  const int base = blockIdx.y * 2048;
  for (int idx = base + threadIdx.x; idx < base + 2048; idx += 256) {
    int k = idx >> 7, n = idx & 127;
    bf16_t hb, lb;
    split2(src[idx], hb, lb);
    int pos = ((n & 7) * 16 + (n >> 3)) * 128 + k;
    oh[pos] = hb;
    ol[pos] = lb;
  }
}

// R19: parallelized — z dim 8 -> 32; each block computes 512 outputs.
__global__ __launch_bounds__(256) void k_fold(
    const float* __restrict__ ee_w2, const float* __restrict__ ee_b2,
    const float* __restrict__ le_w1, const float* __restrict__ le_b1,
    const float* __restrict__ le_w2, const float* __restrict__ le_b2,
    const float* __restrict__ ln_w1,
    bf16_t* __restrict__ WT, float* __restrict__ bvec, float* __restrict__ btil)
{
  const int l = blockIdx.x;
  const int which = blockIdx.y;
  const int z = blockIdx.z;
  const float* L; const float* Rm; const float* lb; const float* badd;
  int slot; float* bout;
  if (which == 0) {
    L = ee_w2; Rm = le_w1 + (size_t)l * 49152 + 256 * 128;
    lb = ee_b2; badd = le_b1 + l * 128;
    slot = 2 + l * 6 + 4; bout = bvec + l * 128;
  } else {
    L = le_w2 + (size_t)l * 16384; Rm = ln_w1 + (size_t)l * 32768 + 128 * 128;
    lb = le_b2 + l * 128; badd = nullptr;
    slot = 2 + l * 6 + 5; bout = btil + l * 128;
  }
  bf16_t* oh = WT + (size_t)slot * 32768;
  bf16_t* ol = oh + 16384;
  const int t = threadIdx.x;
  const int base = z * 512;
  for (int eidx = base + t; eidx < base + 512; eidx += 256) {
    int k = eidx >> 7, n = eidx & 127;
    float a = 0.f;
    for (int d = 0; d < 128; d += 4) {
      float4 lv = ld4(L + k * 128 + d);
      a = fmaf(lv.x, Rm[(d + 0) * 128 + n], a);
      a = fmaf(lv.y, Rm[(d + 1) * 128 + n], a);
      a = fmaf(lv.z, Rm[(d + 2) * 128 + n], a);
      a = fmaf(lv.w, Rm[(d + 3) * 128 + n], a);
    }
    bf16_t hb, lbv;
    split2(a, hb, lbv);
    int pos = ((n & 7) * 16 + (n >> 3)) * 128 + k;
    oh[pos] = hb;
    ol[pos] = lbv;
  }
  if (z == 0 && t < 128) {
    float a = badd ? badd[t] : 0.f;
    for (int d = 0; d < 128; ++d) a = fmaf(lb[d], Rm[d * 128 + t], a);
    bout[t] = a;
  }
}

__global__ __launch_bounds__(256) void k_node_u(
    const float* __restrict__ x, const float* __restrict__ w1,
    const float* __restrict__ b1, const float* __restrict__ a_ptr,
    float* __restrict__ U, int M)
{
  int gid = blockIdx.x * 256 + threadIdx.x;
  int m = gid >> 5;
  if (m >= M) return;
  int nc = (gid & 31) << 2;
  float a = *a_ptr;
  float4 bb = ld4(b1 + nc);
  float z0 = bb.x, z1 = bb.y, z2 = bb.z, z3 = bb.w;
  const float* xr = x + (size_t)m * 30;
  #pragma unroll
  for (int j = 0; j < 30; ++j) {
    float xv = xr[j];
    float4 wv = ld4(w1 + j * 128 + nc);
    z0 = fmaf(xv, wv.x, z0); z1 = fmaf(xv, wv.y, z1);
    z2 = fmaf(xv, wv.z, z2); z3 = fmaf(xv, wv.w, z3);
  }
  st4(U + (size_t)m * 128 + nc,
      make_float4(prelu1(z0, a), prelu1(z1, a), prelu1(z2, a), prelu1(z3, a)));
}

// --------- counting sort by dst ---------------------------------------------
__global__ void k_hist(const int* __restrict__ dstIdx, int* __restrict__ deg, int E) {
  int i = blockIdx.x * 256 + threadIdx.x;
  if (i < E) atomicAdd(deg + dstIdx[i], 1);
}

__global__ __launch_bounds__(1024) void k_scan(
    const int* __restrict__ deg, int* __restrict__ cursor,
    int* __restrict__ rowStart, int N, int per)
{
  __shared__ int part[1024];
  const int t = threadIdx.x;
  const int base = t * per;
  int local = 0;
  for (int i = 0; i < per; ++i) {
    int idx = base + i;
    if (idx < N) local += deg[idx];
  }
  part[t] = local;
  __syncthreads();
  for (int off = 1; off < 1024; off <<= 1) {
    int v = (t >= off) ? part[t - off] : 0;
    __syncthreads();
    part[t] += v;
    __syncthreads();
  }
  int run = (t == 0) ? 0 : part[t - 1];
  for (int i = 0; i < per; ++i) {
    int idx = base + i;
    if (idx < N) {
      cursor[idx] = run;
      rowStart[idx] = run;
      run += deg[idx];
    }
  }
}

__global__ void k_scatter(const int* __restrict__ srcIdx, const int* __restrict__ dstIdx,
                          const float* __restrict__ ea, int* __restrict__ cursor,
                          int* __restrict__ sSrc, int* __restrict__ sDst,
                          float* __restrict__ sEa, int E)
{
  int e = blockIdx.x * 256 + threadIdx.x;
  if (e < E) {
    int d = dstIdx[e];
    int p = atomicAdd(cursor + d, 1);
    sSrc[p] = srcIdx[e];
    sDst[p] = d;
    st4(sEa + (size_t)p * 4, ld4(ea + (size_t)e * 4));
  }
}

// ---------------------------------------------------------------------------
extern "C" void kernel_launch(void* const* d_in, const int* in_sizes, int n_in,
                              void* d_out, int out_size, void* d_ws, size_t ws_size,
                              hipStream_t stream)
{
  const float* x     = (const float*)d_in[0];
  const float* ea    = (const float*)d_in[1];
  const int*   ei    = (const int*)  d_in[2];
  const float* ne_w1 = (const float*)d_in[3];
  const float* ne_b1 = (const float*)d_in[4];
  const float* ne_a  = (const float*)d_in[5];
  const float* ne_w2 = (const float*)d_in[6];
  const float* ne_b2 = (const float*)d_in[7];
  const float* ee_w1 = (const float*)d_in[8];
  const float* ee_b1 = (const float*)d_in[9];
  const float* ee_a  = (const float*)d_in[10];
  const float* ee_w2 = (const float*)d_in[11];
  const float* ee_b2 = (const float*)d_in[12];
  const float* le_w1 = (const float*)d_in[13];
  const float* le_b1 = (const float*)d_in[14];
  const float* le_a  = (const float*)d_in[15];
  const float* le_w2 = (const float*)d_in[16];
  const float* le_b2 = (const float*)d_in[17];
  const float* ln_w1 = (const float*)d_in[18];
  const float* ln_b1 = (const float*)d_in[19];
  const float* ln_a  = (const float*)d_in[20];
  const float* ln_w2 = (const float*)d_in[21];
  const float* ln_b2 = (const float*)d_in[22];
  const float* de_w1 = (const float*)d_in[23];
  const float* de_b1 = (const float*)d_in[24];
  const float* de_a  = (const float*)d_in[25];
  const float* de_w2 = (const float*)d_in[26];
  const float* de_b2 = (const float*)d_in[27];

  const int N = in_sizes[0] / 30;
  const int E = in_sizes[1] / 4;
  const int* srcIdx = ei;        // edge_index[0] = x_j (source)
  const int* dstIdx = ei + E;    // edge_index[1] = x_i (target / agg index)

  const int g32 = (N + 31) / 32;        // node tiles
  const int gE  = (E + 127) / 128;      // 128-edge tiles
  const int Np = g32 * 32;
  const size_t NNp = (size_t)Np * 128;

  float* w = (float*)d_ws;
  float* Pb   = w; w += NNp;
  float* Qb   = w; w += NNp;
  float* Sb   = w; w += NNp;               // also UN before the loop
  float* bvec = w; w += 5 * 128;
  float* btil = w; w += 5 * 128;
  float* sEa  = w; w += (size_t)E * 4;
  bf16_t* hSh = (bf16_t*)w;
  bf16_t* hSl = hSh + NNp;  w += NNp;      // 2 bf16 planes
  bf16_t* WT  = (bf16_t*)w; w += 32 * 32768 / 2;
  int* ip     = (int*)w;
  int* deg    = ip; ip += N;
  int* cursor = ip; ip += N;
  int* rowStart = ip; ip += N;
  int* sSrc   = ip; ip += E;
  int* sDst   = ip; ip += E;

  float* out = (float*)d_out;

  // weight prep + sort (R19: parallelized grids)
  k_tsplit<<<dim3(22, 8), dim3(256), 0, stream>>>(ne_w2, de_w1, le_w1, ln_w1, ln_w2, WT);
  k_fold<<<dim3(5, 2, 32), dim3(256), 0, stream>>>(ee_w2, ee_b2, le_w1, le_b1,
                                                   le_w2, le_b2, ln_w1, WT, bvec, btil);
  hipMemsetAsync(deg, 0, (size_t)N * 4, stream);
  k_hist<<<dim3((E + 255) / 256), dim3(256), 0, stream>>>(dstIdx, deg, E);
  k_scan<<<dim3(1), dim3(1024), 0, stream>>>(deg, cursor, rowStart, N,
                                             (N + 1023) / 1024);
  k_scatter<<<dim3((E + 255) / 256), dim3(256), 0, stream>>>(
      srcIdx, dstIdx, ea, cursor, sSrc, sDst, sEa, E);

  // encoder (+ P/Q for layer 0)
  k_node_u<<<dim3((N * 32 + 255) / 256), dim3(256), 0, stream>>>(x, ne_w1, ne_b1, ne_a, Sb, N);
  k_enc<<<dim3(g32), dim3(256), 0, stream>>>(Sb, WT, ne_b2, WT + 2 * 32768,
                                             hSh, hSl, Pb, Qb, N);

  // one-time zero of S (k_svu keeps it zeroed thereafter)
  hipMemsetAsync(Sb, 0, (size_t)N * 128 * 4, stream);

  for (int l = 0; l < 5; ++l) {
    const bf16_t* slotL = WT + (size_t)(2 + l * 6) * 32768;
    k_edge<<<dim3(gE), dim3(256), 0, stream>>>(
        sEa, sSrc, sDst, rowStart, deg, ee_w1, ee_b1, ee_a,
        slotL + 4 * 32768, bvec + l * 128, le_a + l, Pb, Qb, Sb, N, E);
    const bf16_t* W1next = (l < 4) ? (WT + (size_t)(2 + (l + 1) * 6) * 32768) : WT;
    k_svu<<<dim3(g32), dim3(256), 0, stream>>>(
        Sb, hSh, hSl, slotL + 5 * 32768, slotL + 2 * 32768, slotL + 3 * 32768,
        W1next, ln_b1 + (size_t)l * 128, btil + l * 128, deg, ln_a + l,
        ln_b2 + (size_t)l * 128, Pb, Qb, (l < 4) ? 1 : 0, N);
  }

  k_dec<<<dim3(g32), dim3(128), 0, stream>>>(hSh, hSl, WT + 32768, de_b1, de_a,
                                             de_w2, de_b2, out, N);
}

// Round 5
// 1327.553 us; speedup vs baseline: 1.0790x; 1.0047x over previous
//
#include <hip/hip_runtime.h>
#include <cstdint>
#include <cstddef>

// ---------------------------------------------------------------------------
// GNS model. R20 = R19 + k_edge lb(256,4) [old lb4 evidence was spill-
// confounded] + k_node_u fused into k_enc + k_dec fused into k_svu(l=4).
// Evidence log:
//  - k_edge: 128-edge tiles, R11 inner structure (inline gathers, P-per-run,
//    LDS S-tile). R16 reg-pipeline / R17 LDS-DMA epilogue: both spilled,
//    +-3% -> epilogue not dominant. lb sweep note (lb4: F130/W120) carries
//    the spill WRITE signature (pure occupancy can't move WRITE_SIZE;
//    kernel writes 18.2 MB deterministically) -> re-test lb4 with the lean
//    68-VGPR kernel (cap 128, LDS 4x37.9=151.5<=160 KB). Canary: VGPR 68 /
//    W 18.2 MB unchanged; revert if dur>=160 with FETCH ballooned.
//  - R18/R19: node side 4-wave nt-split + lb(256,3) full residency = -63 us.
//  - R20 fusions: UN computed inline in k_enc (drop k_node_u dispatch +
//    20 MB); decoder run inside k_svu l=4 from LDS h_new, planes_out
//    skipped (drop k_dec dispatch + 20 MB). Bit-identical math paths.
//  - P hoisted once per dst-run (+bvec folded); permuted-column C layout
//    (weight slots: output col n = p*8 + nt').
//  - All GEMMs split-bf16 MFMA (AhBh+AlBh+AhBl), edge-U hi-only.
// ---------------------------------------------------------------------------

#define DEVI static __device__ __forceinline__

typedef __bf16 bf16_t;
typedef bf16_t bf16x8 __attribute__((ext_vector_type(8)));
typedef bf16_t bf16x4 __attribute__((ext_vector_type(4)));
typedef float f32x4v __attribute__((ext_vector_type(4)));

DEVI float4 ld4(const float* p) { return *(const float4*)p; }
DEVI void st4(float* p, float4 v) { *(float4*)p = v; }
DEVI float prelu1(float z, float a) { return z > 0.f ? z : a * z; }
DEVI void atomicAddF(float* p, float v) {
  __hip_atomic_fetch_add(p, v, __ATOMIC_RELAXED, __HIP_MEMORY_SCOPE_AGENT);
}
DEVI f32x4v mfma_bf16(bf16x8 a, bf16x8 b, f32x4v c) {
  return __builtin_amdgcn_mfma_f32_16x16x32_bf16(a, b, c, 0, 0, 0);
}
DEVI void mfma3(f32x4v& acc, bf16x8 ah, bf16x8 al, bf16x8 bh, bf16x8 bl) {
  acc = mfma_bf16(ah, bh, acc);
  acc = mfma_bf16(al, bh, acc);
  acc = mfma_bf16(ah, bl, acc);
}
DEVI void split2(float x, bf16_t& h, bf16_t& l) {
  h = (bf16_t)x;
  l = (bf16_t)(x - (float)h);
}
DEVI bf16x8 ldb8(const bf16_t* p) { return *(const bf16x8*)p; }

#define NST 136   // node staging row stride (bf16)
#define EST 72    // edge staging row stride (bf16)

// ======== 4-wave node tile building blocks ================================
// wave (h = wave&1) owns rows h*16..h*16+15; (cH = wave>>1) owns col-half
// cH*64..cH*64+63 (column tiles nt' = cH*4 + nt, nt in 0..3).

DEVI void stage_f32_c4(const float* __restrict__ src, int row0, int M,
                       int lane, int h, int cH, bf16_t* SAh, bf16_t* SAl)
{
  const int row = h * 16 + (lane >> 2);
  const int grow = row0 + row;
  const int colbase = cH * 64 + (lane & 3) * 16;
  #pragma unroll
  for (int j = 0; j < 4; ++j) {
    int kc = colbase + j * 4;
    float4 v = make_float4(0.f, 0.f, 0.f, 0.f);
    if (grow < M) v = ld4(src + (size_t)grow * 128 + kc);
    bf16_t h0,l0,h1,l1,h2,l2,h3,l3;
    split2(v.x,h0,l0); split2(v.y,h1,l1); split2(v.z,h2,l2); split2(v.w,h3,l3);
    *(bf16x4*)(SAh + row * NST + kc) = (bf16x4){h0,h1,h2,h3};
    *(bf16x4*)(SAl + row * NST + kc) = (bf16x4){l0,l1,l2,l3};
  }
}

DEVI void stage_planes_c4(const bf16_t* __restrict__ gh, const bf16_t* __restrict__ gl,
                          int row0, int M, int lane, int h, int cH,
                          bf16_t* SAh, bf16_t* SAl)
{
  const int row = h * 16 + (lane >> 2);
  const int grow = row0 + row;
  const int colbase = cH * 64 + (lane & 3) * 16;
  #pragma unroll
  for (int j = 0; j < 2; ++j) {
    int kc = colbase + j * 8;
    bf16x8 vh = {};
    bf16x8 vl = {};
    if (grow < M) {
      vh = ldb8(gh + (size_t)grow * 128 + kc);
      vl = ldb8(gl + (size_t)grow * 128 + kc);
    }
    *(bf16x8*)(SAh + row * NST + kc) = vh;
    *(bf16x8*)(SAl + row * NST + kc) = vl;
  }
}

// acc[4] over column tiles ntb..ntb+3; A rows h*16..+15 (full K=128)
DEVI void gemm_c4(const bf16_t* SAh, const bf16_t* SAl,
                  const bf16_t* __restrict__ BT, f32x4v acc[4],
                  int h, int ntb, int p, int q)
{
  #pragma unroll
  for (int ks = 0; ks < 4; ++ks) {
    const int k0 = ks * 32 + q * 8;
    bf16x8 aH = ldb8(SAh + (h * 16 + p) * NST + k0);
    bf16x8 aL = ldb8(SAl + (h * 16 + p) * NST + k0);
    #pragma unroll
    for (int nt = 0; nt < 4; ++nt) {
      const bf16_t* bp = BT + (size_t)((ntb + nt) * 16 + p) * 128 + k0;
      mfma3(acc[nt], aH, aL, ldb8(bp), ldb8(bp + 16384));
    }
  }
}

DEVI void store_c4(float* __restrict__ O, int row0, int M,
                   const f32x4v acc[4], int h, int cH, int p, int q)
{
  int rb = row0 + h * 16 + q * 4;
  #pragma unroll
  for (int r = 0; r < 4; ++r) {
    if (rb + r < M) {
      float* op = O + (size_t)(rb + r) * 128 + p * 8 + cH * 4;
      st4(op, make_float4(acc[0][r], acc[1][r], acc[2][r], acc[3][r]));
    }
  }
}

DEVI void stage_cregs_c4(const f32x4v acc[4], int h, int cH, int p, int q,
                         bf16_t* SAh, bf16_t* SAl)
{
  #pragma unroll
  for (int r = 0; r < 4; ++r) {
    int row = h * 16 + q * 4 + r;
    bf16x4 vh, vl;
    #pragma unroll
    for (int nt = 0; nt < 4; ++nt) {
      bf16_t hb, lb;
      split2(acc[nt][r], hb, lb);
      vh[nt] = hb; vl[nt] = lb;
    }
    *(bf16x4*)(SAh + row * NST + p * 8 + cH * 4) = vh;
    *(bf16x4*)(SAl + row * NST + p * 8 + cH * 4) = vl;
  }
}

DEVI void planes_out_c4(bf16_t* __restrict__ gh, bf16_t* __restrict__ gl,
                        int row0, int M, int lane, int h, int cH,
                        const bf16_t* SAh, const bf16_t* SAl)
{
  const int row = h * 16 + (lane >> 2);
  const int grow = row0 + row;
  const int colbase = cH * 64 + (lane & 3) * 16;
  if (grow < M) {
    #pragma unroll
    for (int j = 0; j < 2; ++j) {
      int kc = colbase + j * 8;
      *(bf16x8*)(gh + (size_t)grow * 128 + kc) = *(const bf16x8*)(SAh + row * NST + kc);
      *(bf16x8*)(gl + (size_t)grow * 128 + kc) = *(const bf16x8*)(SAl + row * NST + kc);
    }
  }
}

DEVI void ld8f(float dst[8], const float* __restrict__ src, int p) {
  *(float4*)(dst)     = ld4(src + p * 8);
  *(float4*)(dst + 4) = ld4(src + p * 8 + 4);
}

DEVI void ld4f(float dst[4], const float* __restrict__ src, int p, int cH) {
  *(float4*)(dst) = ld4(src + p * 8 + cH * 4);
}

// ---------------------------------------------------------------------------
// k_svu: 256 thr / 32-row tiles, 4 waves. Node update + P/Q for next layer;
// zeroes consumed S rows. l=4 (doDec): decoder fused from LDS h_new,
// planes_out skipped (h planes have no consumer after decode).
// ---------------------------------------------------------------------------
__global__ __launch_bounds__(256, 3) void k_svu(
    float* Sbuf,                      // read then zeroed (same buffer)
    bf16_t* __restrict__ hSh, bf16_t* __restrict__ hSl,
    const bf16_t* __restrict__ WtilT, const bf16_t* __restrict__ Wn1aT,
    const bf16_t* __restrict__ lnw2T, const bf16_t* __restrict__ W1nextT,
    const float* __restrict__ ln_b1_l, const float* __restrict__ btil_l,
    const int* __restrict__ deg, const float* __restrict__ ln_a_l,
    const float* __restrict__ ln_b2_l,
    float* __restrict__ P, float* __restrict__ Q, int doPQ,
    const bf16_t* __restrict__ dw1T, const float* __restrict__ de_b1,
    const float* __restrict__ de_a, const float* __restrict__ de_w2,
    const float* __restrict__ de_b2, float* __restrict__ outp,
    int doDec, int M)
{
  // SA planes; Cs (dec C-tile, 32x132 f32 = 16896 B) overlays them after
  // the dec GEMM has consumed h_new.
  __shared__ __align__(16) char SMEM[2 * 32 * NST * 2];   // 17408 B
  __shared__ __align__(16) float w2s[384];
  bf16_t* SAh = (bf16_t*)SMEM;
  bf16_t* SAl = (bf16_t*)(SMEM + 32 * NST * 2);
  float*  Cs  = (float*)SMEM;

  const int t = threadIdx.x, lane = t & 63, wave = t >> 6;
  const int h = wave & 1, cH = wave >> 1;
  const int p = lane & 15, q = lane >> 4;
  const int row0 = blockIdx.x * 32;

  f32x4v acc1[4];
  #pragma unroll
  for (int j = 0; j < 4; ++j) acc1[j] = (f32x4v){0.f, 0.f, 0.f, 0.f};

  stage_f32_c4(Sbuf, row0, M, lane, h, cH, SAh, SAl);
  // zero consumed S cells (per-lane same addresses as the loads -> ordered)
  {
    const int row = h * 16 + (lane >> 2);
    const int grow = row0 + row;
    const int colbase = cH * 64 + (lane & 3) * 16;
    if (grow < M) {
      float4 z4 = make_float4(0.f, 0.f, 0.f, 0.f);
      #pragma unroll
      for (int j = 0; j < 4; ++j)
        st4(Sbuf + (size_t)grow * 128 + colbase + j * 4, z4);
    }
  }
  __syncthreads();                       // S tile complete
  gemm_c4(SAh, SAl, WtilT, acc1, h, cH * 4, p, q);
  __syncthreads();                       // all S reads done before h overwrite
  stage_planes_c4(hSh, hSl, row0, M, lane, h, cH, SAh, SAl);
  __syncthreads();                       // h tile complete
  gemm_c4(SAh, SAl, Wn1aT, acc1, h, cH * 4, p, q);

  // h_old (feature-linear layout) from LDS — this wave's 4 cols
  float hold[4][4];
  #pragma unroll
  for (int r = 0; r < 4; ++r) {
    int row = h * 16 + q * 4 + r;
    bf16x4 vh = *(const bf16x4*)(SAh + row * NST + p * 8 + cH * 4);
    bf16x4 vl = *(const bf16x4*)(SAl + row * NST + p * 8 + cH * 4);
    #pragma unroll
    for (int nt = 0; nt < 4; ++nt)
      hold[nt][r] = (float)vh[nt] + (float)vl[nt];
  }
  __syncthreads();                       // all h reads done before V overwrite

  // V = prelu(acc1 + b1 + deg*btil)
  const float alpha = *ln_a_l;
  float degf[4];
  #pragma unroll
  for (int r = 0; r < 4; ++r) {
    int row = row0 + h * 16 + q * 4 + r;
    degf[r] = (row < M) ? (float)deg[row] : 0.f;
  }
  float b1c[4], btc[4];
  ld4f(b1c, ln_b1_l, p, cH);
  ld4f(btc, btil_l, p, cH);
  #pragma unroll
  for (int nt = 0; nt < 4; ++nt)
    #pragma unroll
    for (int r = 0; r < 4; ++r)
      acc1[nt][r] = prelu1(acc1[nt][r] + b1c[nt] + degf[r] * btc[nt], alpha);

  stage_cregs_c4(acc1, h, cH, p, q, SAh, SAl);   // V
  __syncthreads();                       // V tile complete
  f32x4v acc2[4];
  #pragma unroll
  for (int j = 0; j < 4; ++j) acc2[j] = (f32x4v){0.f, 0.f, 0.f, 0.f};
  gemm_c4(SAh, SAl, lnw2T, acc2, h, cH * 4, p, q);
  __syncthreads();                       // all V reads done before h_new overwrite

  // h_new = h_old + acc2 + b2
  float b2c[4];
  ld4f(b2c, ln_b2_l, p, cH);
  #pragma unroll
  for (int nt = 0; nt < 4; ++nt)
    #pragma unroll
    for (int r = 0; r < 4; ++r)
      acc2[nt][r] = hold[nt][r] + acc2[nt][r] + b2c[nt];

  stage_cregs_c4(acc2, h, cH, p, q, SAh, SAl);   // h_new

  if (doDec) {
    // ---- fused decoder (l=4): h1 = prelu(h_new@de_w1 + b1); out = h1@de_w2+b2
    if (t < 128) {
      w2s[t] = de_w2[t]; w2s[t + 128] = de_w2[t + 128]; w2s[t + 256] = de_w2[t + 256];
    }
    __syncthreads();                     // h_new tile complete (+ w2s staged)
    f32x4v acc3[4];
    #pragma unroll
    for (int j = 0; j < 4; ++j) acc3[j] = (f32x4v){0.f, 0.f, 0.f, 0.f};
    gemm_c4(SAh, SAl, dw1T, acc3, h, cH * 4, p, q);
    const float da = *de_a;
    float db1[4];
    ld4f(db1, de_b1, p, cH);
    #pragma unroll
    for (int nt = 0; nt < 4; ++nt)
      #pragma unroll
      for (int r = 0; r < 4; ++r)
        acc3[nt][r] = prelu1(acc3[nt][r] + db1[nt], da);
    __syncthreads();                     // all SA reads done before Cs overlay
    #pragma unroll
    for (int r = 0; r < 4; ++r) {
      int row = h * 16 + q * 4 + r;
      st4(&Cs[row * 132 + p * 8 + cH * 4],
          make_float4(acc3[0][r], acc3[1][r], acc3[2][r], acc3[3][r]));
    }
    __syncthreads();                     // Cs complete
    if (t < 32) {
      float s0 = de_b2[0], s1 = de_b2[1], s2 = de_b2[2];
      for (int k = 0; k < 128; ++k) {
        float vv = Cs[t * 132 + k];
        s0 = fmaf(vv, w2s[k * 3 + 0], s0);
        s1 = fmaf(vv, w2s[k * 3 + 1], s1);
        s2 = fmaf(vv, w2s[k * 3 + 2], s2);
      }
      int row = row0 + t;
      if (row < M) {
        outp[(size_t)row * 3 + 0] = s0;
        outp[(size_t)row * 3 + 1] = s1;
        outp[(size_t)row * 3 + 2] = s2;
      }
    }
    return;
  }

  __syncthreads();                       // h_new tile complete
  planes_out_c4(hSh, hSl, row0, M, lane, h, cH, SAh, SAl);

  if (doPQ) {
    f32x4v acc3[4];
    #pragma unroll
    for (int j = 0; j < 4; ++j) acc3[j] = (f32x4v){0.f, 0.f, 0.f, 0.f};
    gemm_c4(SAh, SAl, W1nextT, acc3, h, cH * 4, p, q);
    store_c4(P, row0, M, acc3, h, cH, p, q);
    #pragma unroll
    for (int j = 0; j < 4; ++j) acc3[j] = (f32x4v){0.f, 0.f, 0.f, 0.f};
    gemm_c4(SAh, SAl, W1nextT + 32768, acc3, h, cH * 4, p, q);
    store_c4(Q, row0, M, acc3, h, cH, p, q);
  }
}

// ---------------------------------------------------------------------------
// k_enc: 256 thr / 32-row tiles, 4 waves, lb(256,3). Fused node encoder:
// UN = prelu(x@ne_w1+b1) computed inline (LDS-staged x rows + ne_w1),
// h0 = UN@ne_w2 + b2 -> planes; + P/Q layer 0.
// ---------------------------------------------------------------------------
__global__ __launch_bounds__(256, 3) void k_enc(
    const float* __restrict__ x, const float* __restrict__ ne_w1,
    const float* __restrict__ ne_b1, const float* __restrict__ ne_a,
    const bf16_t* __restrict__ new2T,
    const float* __restrict__ b2, const bf16_t* __restrict__ W1T0,
    bf16_t* __restrict__ hSh, bf16_t* __restrict__ hSl,
    float* __restrict__ P, float* __restrict__ Q, int M)
{
  __shared__ __align__(16) bf16_t SAh[32 * NST];
  __shared__ __align__(16) bf16_t SAl[32 * NST];
  __shared__ __align__(16) float w1s[30 * 128];   // 15 KB
  __shared__ __align__(16) float xs[32 * 30];     // 3.75 KB
  __shared__ __align__(16) float b1s[128];
  const int t = threadIdx.x, lane = t & 63, wave = t >> 6;
  const int h = wave & 1, cH = wave >> 1;
  const int p = lane & 15, q = lane >> 4;
  const int row0 = blockIdx.x * 32;

  // stage ne_w1 / x rows / b1
  for (int i = t; i < 30 * 128; i += 256) w1s[i] = ne_w1[i];
  {
    int nrow = M - row0; if (nrow > 32) nrow = 32;
    int cnt = nrow * 30;
    for (int i = t; i < cnt; i += 256) xs[i] = x[(size_t)row0 * 30 + i];
  }
  if (t < 128) b1s[t] = ne_b1[t];
  __syncthreads();
  const float ua = *ne_a;

  // compute this thread's staged UN cells: row = h*16+(lane>>2), 16 cols
  {
    const int row = h * 16 + (lane >> 2);
    const int grow = row0 + row;
    const int colbase = cH * 64 + (lane & 3) * 16;
    #pragma unroll
    for (int jj = 0; jj < 4; ++jj) {
      int kc = colbase + jj * 4;
      float z0 = 0.f, z1 = 0.f, z2 = 0.f, z3 = 0.f;
      if (grow < M) {
        float4 bb = ld4(b1s + kc);
        z0 = bb.x; z1 = bb.y; z2 = bb.z; z3 = bb.w;
        #pragma unroll
        for (int j = 0; j < 30; ++j) {
          float xv = xs[row * 30 + j];
          float4 wv = ld4(w1s + j * 128 + kc);
          z0 = fmaf(xv, wv.x, z0); z1 = fmaf(xv, wv.y, z1);
          z2 = fmaf(xv, wv.z, z2); z3 = fmaf(xv, wv.w, z3);
        }
        z0 = prelu1(z0, ua); z1 = prelu1(z1, ua);
        z2 = prelu1(z2, ua); z3 = prelu1(z3, ua);
      }
      bf16_t h0,l0,h1,l1,h2,l2,h3,l3;
      split2(z0,h0,l0); split2(z1,h1,l1); split2(z2,h2,l2); split2(z3,h3,l3);
      *(bf16x4*)(SAh + row * NST + kc) = (bf16x4){h0,h1,h2,h3};
      *(bf16x4*)(SAl + row * NST + kc) = (bf16x4){l0,l1,l2,l3};
    }
  }
  __syncthreads();                       // UN tile complete

  f32x4v acc[4];
  #pragma unroll
  for (int j = 0; j < 4; ++j) acc[j] = (f32x4v){0.f, 0.f, 0.f, 0.f};
  gemm_c4(SAh, SAl, new2T, acc, h, cH * 4, p, q);
  __syncthreads();                       // all UN reads done before h0 overwrite
  float b2c[4];
  ld4f(b2c, b2, p, cH);
  #pragma unroll
  for (int nt = 0; nt < 4; ++nt)
    #pragma unroll
    for (int r = 0; r < 4; ++r) acc[nt][r] += b2c[nt];
  stage_cregs_c4(acc, h, cH, p, q, SAh, SAl);
  __syncthreads();                       // h0 tile complete
  planes_out_c4(hSh, hSl, row0, M, lane, h, cH, SAh, SAl);

  f32x4v acc3[4];
  #pragma unroll
  for (int j = 0; j < 4; ++j) acc3[j] = (f32x4v){0.f, 0.f, 0.f, 0.f};
  gemm_c4(SAh, SAl, W1T0, acc3, h, cH * 4, p, q);
  store_c4(P, row0, M, acc3, h, cH, p, q);
  #pragma unroll
  for (int j = 0; j < 4; ++j) acc3[j] = (f32x4v){0.f, 0.f, 0.f, 0.f};
  gemm_c4(SAh, SAl, W1T0 + 32768, acc3, h, cH * 4, p, q);
  store_c4(Q, row0, M, acc3, h, cH, p, q);
}

// ---------------------------------------------------------------------------
// k_edge: 128-edge tiles, lb(256,4) [R20: spill-confound re-test], inline
// gathers, 32-row LDS S-tile. Inner structure = R11 verbatim.
// ---------------------------------------------------------------------------
__global__ __launch_bounds__(256, 4) void k_edge(
    const float* __restrict__ sEa, const int* __restrict__ sSrc,
    const int* __restrict__ sDst,
    const int* __restrict__ rowStart, const int* __restrict__ deg,
    const float* __restrict__ ee_w1, const float* __restrict__ ee_b1,
    const float* __restrict__ ee_a,
    const bf16_t* __restrict__ WhatT, const float* __restrict__ bvec,
    const float* __restrict__ alpha_ptr,
    const float* __restrict__ P, const float* __restrict__ Q,
    float* __restrict__ S, int N, int E)
{
  __shared__ __align__(16) float Stile[32 * 132];     // 16.9 KB
  __shared__ __align__(16) float ew[640];             // ee_w1 + ee_b1
  __shared__ __align__(16) bf16_t Ast[128 * EST];     // 18.4 KB

  const int t = threadIdx.x, lane = t & 63, wave = t >> 6;
  const int p = lane & 15, q = lane >> 4;
  const int e0 = blockIdx.x * 128;
  const int dstLo = sDst[e0];

  for (int i = t; i < 640; i += 256)
    ew[i] = (i < 512) ? ee_w1[i] : ee_b1[i - 512];
  for (int i = t; i < 32 * 132; i += 256) Stile[i] = 0.f;
  __syncthreads();

  const float ua = *ee_a;
  const float alpha = *alpha_ptr;
  float bvc[8];
  ld8f(bvc, bvec, p);

  const int srow = wave * 32 + (lane >> 1);
  const int scb = (lane & 1) * 32;
  float4 eav = make_float4(0.f, 0.f, 0.f, 0.f);
  {
    int ed = e0 + srow;
    if (ed < E) eav = ld4(sEa + (size_t)ed * 4);
  }

  f32x4v acc[2][8];
  #pragma unroll
  for (int i = 0; i < 2; ++i)
    #pragma unroll
    for (int j = 0; j < 8; ++j) acc[i][j] = (f32x4v){0.f, 0.f, 0.f, 0.f};

  for (int c = 0; c < 2; ++c) {
    // stage U chunk (bf16-hi only), wave-private rows -> no barrier
    #pragma unroll
    for (int j = 0; j < 8; ++j) {
      int kc = scb + j * 4;
      int kg = c * 64 + kc;
      float4 w0 = ld4(ew + kg);
      float4 w1 = ld4(ew + 128 + kg);
      float4 w2 = ld4(ew + 256 + kg);
      float4 w3 = ld4(ew + 384 + kg);
      float4 bb = ld4(ew + 512 + kg);
      float ux = bb.x, uy = bb.y, uz = bb.z, uw = bb.w;
      ux = fmaf(eav.x, w0.x, ux); uy = fmaf(eav.x, w0.y, uy);
      uz = fmaf(eav.x, w0.z, uz); uw = fmaf(eav.x, w0.w, uw);
      ux = fmaf(eav.y, w1.x, ux); uy = fmaf(eav.y, w1.y, uy);
      uz = fmaf(eav.y, w1.z, uz); uw = fmaf(eav.y, w1.w, uw);
      ux = fmaf(eav.z, w2.x, ux); uy = fmaf(eav.z, w2.y, uy);
      uz = fmaf(eav.z, w2.z, uz); uw = fmaf(eav.z, w2.w, uw);
      ux = fmaf(eav.w, w3.x, ux); uy = fmaf(eav.w, w3.y, uy);
      uz = fmaf(eav.w, w3.z, uz); uw = fmaf(eav.w, w3.w, uw);
      *(bf16x4*)(Ast + srow * EST + kc) = (bf16x4){
          (bf16_t)prelu1(ux, ua), (bf16_t)prelu1(uy, ua),
          (bf16_t)prelu1(uz, ua), (bf16_t)prelu1(uw, ua)};
    }
    #pragma unroll
    for (int ks = 0; ks < 2; ++ks) {
      const int k0 = ks * 32 + q * 8;
      const int kg = c * 64 + k0;
      bf16x8 aH0 = ldb8(Ast + (wave * 32 + p) * EST + k0);
      bf16x8 aH1 = ldb8(Ast + (wave * 32 + 16 + p) * EST + k0);
      #pragma unroll
      for (int nt = 0; nt < 8; ++nt) {
        const bf16_t* bp = WhatT + (size_t)(nt * 16 + p) * 128 + kg;
        bf16x8 bH = ldb8(bp);
        bf16x8 bL = ldb8(bp + 16384);
        acc[0][nt] = mfma_bf16(aH0, bH, acc[0][nt]);
        acc[0][nt] = mfma_bf16(aH0, bL, acc[0][nt]);
        acc[1][nt] = mfma_bf16(aH1, bH, acc[1][nt]);
        acc[1][nt] = mfma_bf16(aH1, bL, acc[1][nt]);
      }
    }
  }

  // epilogue: run-reduce; indices loaded inline; P once per run (+bvec)
  #pragma unroll
  for (int mt = 0; mt < 2; ++mt) {
    float rs[8];
    #pragma unroll
    for (int nt = 0; nt < 8; ++nt) rs[nt] = 0.f;
    int curd = -1;
    float pv[8];
    #pragma unroll
    for (int nt = 0; nt < 8; ++nt) pv[nt] = 0.f;
    #pragma unroll
    for (int r = 0; r < 4; ++r) {
      int ed = e0 + wave * 32 + mt * 16 + q * 4 + r;
      if (ed < E) {
        int d = sDst[ed];
        int s = sSrc[ed];
        if (d != curd) {
          if (curd >= 0) {
            int rr = curd - dstLo;
            if (rr < 32) {
              #pragma unroll
              for (int nt = 0; nt < 8; ++nt)
                atomicAdd(&Stile[rr * 132 + p * 8 + nt], rs[nt]);
            } else {
              #pragma unroll
              for (int nt = 0; nt < 8; ++nt)
                atomicAddF(S + (size_t)curd * 128 + p * 8 + nt, rs[nt]);
            }
            #pragma unroll
            for (int nt = 0; nt < 8; ++nt) rs[nt] = 0.f;
          }
          curd = d;
          ld8f(pv, P + (size_t)d * 128, p);
          #pragma unroll
          for (int nt = 0; nt < 8; ++nt) pv[nt] += bvc[nt];
        }
        float qv[8];
        ld8f(qv, Q + (size_t)s * 128, p);
        #pragma unroll
        for (int nt = 0; nt < 8; ++nt) {
          float z = acc[mt][nt][r] + pv[nt] + qv[nt];
          rs[nt] += prelu1(z, alpha);
        }
      }
    }
    if (curd >= 0) {
      int rr = curd - dstLo;
      if (rr < 32) {
        #pragma unroll
        for (int nt = 0; nt < 8; ++nt)
          atomicAdd(&Stile[rr * 132 + p * 8 + nt], rs[nt]);
      } else {
        #pragma unroll
        for (int nt = 0; nt < 8; ++nt)
          atomicAddF(S + (size_t)curd * 128 + p * 8 + nt, rs[nt]);
      }
    }
  }
  __syncthreads();

  // writeback: interior rows plain-stored, boundary rows atomic
  const int lastE = (e0 + 127 < E) ? (e0 + 127) : (E - 1);
  const int dstHi = sDst[lastE];
  const int col4 = (t & 31) * 4;
  #pragma unroll
  for (int rr0 = 0; rr0 < 32; rr0 += 8) {
    int rr = rr0 + (t >> 5);
    int d = dstLo + rr;
    if (d <= dstHi && d < N) {
      float4 v = ld4(&Stile[rr * 132 + col4]);
      bool interior = (rowStart[d] >= e0) && (rowStart[d] + deg[d] <= e0 + 128);
      float* sp = S + (size_t)d * 128 + col4;
      if (interior) {
        st4(sp, v);
      } else {
        atomicAddF(sp + 0, v.x); atomicAddF(sp + 1, v.y);
        atomicAddF(sp + 2, v.z); atomicAddF(sp + 3, v.w);
      }
    }
  }
}

// --------- weight prep: transpose+split with PERMUTED col mapping -----------
__global__ __launch_bounds__(256) void k_tsplit(
    const float* __restrict__ ne_w2, const float* __restrict__ de_w1,
    const float* __restrict__ le_w1, const float* __restrict__ ln_w1,
    const float* __restrict__ ln_w2, bf16_t* __restrict__ WT)
{
  int jid = blockIdx.x;
  const float* src; int slot;
  if (jid == 0)      { src = ne_w2; slot = 0; }
  else if (jid == 1) { src = de_w1; slot = 1; }
  else {
    int l = (jid - 2) >> 2, wj = (jid - 2) & 3;
    slot = 2 + l * 6 + wj;
    src = (wj == 0) ? le_w1 + (size_t)l * 49152
        : (wj == 1) ? le_w1 + (size_t)l * 49152 + 16384
        : (wj == 2) ? ln_w1 + (size_t)l * 32768
                    : ln_w2 + (size_t)l * 16384;
  }
  bf16_t* oh = WT + (size_t)slot * 32768;
  bf16_t* ol = oh + 16384;
  const int base = blockIdx.y * 2048;
  for (int idx = base + threadIdx.x; idx < base + 2048; idx += 256) {
    int k = idx >> 7, n = idx & 127;
    bf16_t hb, lb;
    split2(src[idx], hb, lb);
    int pos = ((n & 7) * 16 + (n >> 3)) * 128 + k;
    oh[pos] = hb;
    ol[pos] = lb;
  }
}

__global__ __launch_bounds__(256) void k_fold(
    const float* __restrict__ ee_w2, const float* __restrict__ ee_b2,
    const float* __restrict__ le_w1, const float* __restrict__ le_b1,
    const float* __restrict__ le_w2, const float* __restrict__ le_b2,
    const float* __restrict__ ln_w1,
    bf16_t* __restrict__ WT, float* __restrict__ bvec, float* __restrict__ btil)
{
  const int l = blockIdx.x;
  const int which = blockIdx.y;
  const int z = blockIdx.z;
  const float* L; const float* Rm; const float* lb; const float* badd;
  int slot; float* bout;
  if (which == 0) {
    L = ee_w2; Rm = le_w1 + (size_t)l * 49152 + 256 * 128;
    lb = ee_b2; badd = le_b1 + l * 128;
    slot = 2 + l * 6 + 4; bout = bvec + l * 128;
  } else {
    L = le_w2 + (size_t)l * 16384; Rm = ln_w1 + (size_t)l * 32768 + 128 * 128;
    lb = le_b2 + l * 128; badd = nullptr;
    slot = 2 + l * 6 + 5; bout = btil + l * 128;
  }
  bf16_t* oh = WT + (size_t)slot * 32768;
  bf16_t* ol = oh + 16384;
  const int t = threadIdx.x;
  const int base = z * 512;
  for (int eidx = base + t; eidx < base + 512; eidx += 256) {
    int k = eidx >> 7, n = eidx & 127;
    float a = 0.f;
    for (int d = 0; d < 128; d += 4) {
      float4 lv = ld4(L + k * 128 + d);
      a = fmaf(lv.x, Rm[(d + 0) * 128 + n], a);
      a = fmaf(lv.y, Rm[(d + 1) * 128 + n], a);
      a = fmaf(lv.z, Rm[(d + 2) * 128 + n], a);
      a = fmaf(lv.w, Rm[(d + 3) * 128 + n], a);
    }
    bf16_t hb, lbv;
    split2(a, hb, lbv);
    int pos = ((n & 7) * 16 + (n >> 3)) * 128 + k;
    oh[pos] = hb;
    ol[pos] = lbv;
  }
  if (z == 0 && t < 128) {
    float a = badd ? badd[t] : 0.f;
    for (int d = 0; d < 128; ++d) a = fmaf(lb[d], Rm[d * 128 + t], a);
    bout[t] = a;
  }
}

// --------- counting sort by dst ---------------------------------------------
__global__ void k_hist(const int* __restrict__ dstIdx, int* __restrict__ deg, int E) {
  int i = blockIdx.x * 256 + threadIdx.x;
  if (i < E) atomicAdd(deg + dstIdx[i], 1);
}

__global__ __launch_bounds__(1024) void k_scan(
    const int* __restrict__ deg, int* __restrict__ cursor,
    int* __restrict__ rowStart, int N, int per)
{
  __shared__ int part[1024];
  const int t = threadIdx.x;
  const int base = t * per;
  int local = 0;
  for (int i = 0; i < per; ++i) {
    int idx = base + i;
    if (idx < N) local += deg[idx];
  }
  part[t] = local;
  __syncthreads();
  for (int off = 1; off < 1024; off <<= 1) {
    int v = (t >= off) ? part[t - off] : 0;
    __syncthreads();
    part[t] += v;
    __syncthreads();
  }
  int run = (t == 0) ? 0 : part[t - 1];
  for (int i = 0; i < per; ++i) {
    int idx = base + i;
    if (idx < N) {
      cursor[idx] = run;
      rowStart[idx] = run;
      run += deg[idx];
    }
  }
}

__global__ void k_scatter(const int* __restrict__ srcIdx, const int* __restrict__ dstIdx,
                          const float* __restrict__ ea, int* __restrict__ cursor,
                          int* __restrict__ sSrc, int* __restrict__ sDst,
                          float* __restrict__ sEa, int E)
{
  int e = blockIdx.x * 256 + threadIdx.x;
  if (e < E) {
    int d = dstIdx[e];
    int p = atomicAdd(cursor + d, 1);
    sSrc[p] = srcIdx[e];
    sDst[p] = d;
    st4(sEa + (size_t)p * 4, ld4(ea + (size_t)e * 4));
  }
}

// ---------------------------------------------------------------------------
extern "C" void kernel_launch(void* const* d_in, const int* in_sizes, int n_in,
                              void* d_out, int out_size, void* d_ws, size_t ws_size,
                              hipStream_t stream)
{
  const float* x     = (const float*)d_in[0];
  const float* ea    = (const float*)d_in[1];
  const int*   ei    = (const int*)  d_in[2];
  const float* ne_w1 = (const float*)d_in[3];
  const float* ne_b1 = (const float*)d_in[4];
  const float* ne_a  = (const float*)d_in[5];
  const float* ne_w2 = (const float*)d_in[6];
  const float* ne_b2 = (const float*)d_in[7];
  const float* ee_w1 = (const float*)d_in[8];
  const float* ee_b1 = (const float*)d_in[9];
  const float* ee_a  = (const float*)d_in[10];
  const float* ee_w2 = (const float*)d_in[11];
  const float* ee_b2 = (const float*)d_in[12];
  const float* le_w1 = (const float*)d_in[13];
  const float* le_b1 = (const float*)d_in[14];
  const float* le_a  = (const float*)d_in[15];
  const float* le_w2 = (const float*)d_in[16];
  const float* le_b2 = (const float*)d_in[17];
  const float* ln_w1 = (const float*)d_in[18];
  const float* ln_b1 = (const float*)d_in[19];
  const float* ln_a  = (const float*)d_in[20];
  const float* ln_w2 = (const float*)d_in[21];
  const float* ln_b2 = (const float*)d_in[22];
  const float* de_w1 = (const float*)d_in[23];
  const float* de_b1 = (const float*)d_in[24];
  const float* de_a  = (const float*)d_in[25];
  const float* de_w2 = (const float*)d_in[26];
  const float* de_b2 = (const float*)d_in[27];

  const int N = in_sizes[0] / 30;
  const int E = in_sizes[1] / 4;
  const int* srcIdx = ei;        // edge_index[0] = x_j (source)
  const int* dstIdx = ei + E;    // edge_index[1] = x_i (target / agg index)

  const int g32 = (N + 31) / 32;        // node tiles
  const int gE  = (E + 127) / 128;      // 128-edge tiles
  const int Np = g32 * 32;
  const size_t NNp = (size_t)Np * 128;

  float* w = (float*)d_ws;
  float* Pb   = w; w += NNp;
  float* Qb   = w; w += NNp;
  float* Sb   = w; w += NNp;
  float* bvec = w; w += 5 * 128;
  float* btil = w; w += 5 * 128;
  float* sEa  = w; w += (size_t)E * 4;
  bf16_t* hSh = (bf16_t*)w;
  bf16_t* hSl = hSh + NNp;  w += NNp;      // 2 bf16 planes
  bf16_t* WT  = (bf16_t*)w; w += 32 * 32768 / 2;
  int* ip     = (int*)w;
  int* deg    = ip; ip += N;
  int* cursor = ip; ip += N;
  int* rowStart = ip; ip += N;
  int* sSrc   = ip; ip += E;
  int* sDst   = ip; ip += E;

  float* out = (float*)d_out;

  // weight prep + sort
  k_tsplit<<<dim3(22, 8), dim3(256), 0, stream>>>(ne_w2, de_w1, le_w1, ln_w1, ln_w2, WT);
  k_fold<<<dim3(5, 2, 32), dim3(256), 0, stream>>>(ee_w2, ee_b2, le_w1, le_b1,
                                                   le_w2, le_b2, ln_w1, WT, bvec, btil);
  hipMemsetAsync(deg, 0, (size_t)N * 4, stream);
  k_hist<<<dim3((E + 255) / 256), dim3(256), 0, stream>>>(dstIdx, deg, E);
  k_scan<<<dim3(1), dim3(1024), 0, stream>>>(deg, cursor, rowStart, N,
                                             (N + 1023) / 1024);
  k_scatter<<<dim3((E + 255) / 256), dim3(256), 0, stream>>>(
      srcIdx, dstIdx, ea, cursor, sSrc, sDst, sEa, E);

  // fused encoder (node MLP1 inline) + P/Q for layer 0
  k_enc<<<dim3(g32), dim3(256), 0, stream>>>(x, ne_w1, ne_b1, ne_a,
                                             WT, ne_b2, WT + 2 * 32768,
                                             hSh, hSl, Pb, Qb, N);

  // one-time zero of S (k_svu keeps it zeroed thereafter)
  hipMemsetAsync(Sb, 0, (size_t)N * 128 * 4, stream);

  for (int l = 0; l < 5; ++l) {
    const bf16_t* slotL = WT + (size_t)(2 + l * 6) * 32768;
    k_edge<<<dim3(gE), dim3(256), 0, stream>>>(
        sEa, sSrc, sDst, rowStart, deg, ee_w1, ee_b1, ee_a,
        slotL + 4 * 32768, bvec + l * 128, le_a + l, Pb, Qb, Sb, N, E);
    const bf16_t* W1next = (l < 4) ? (WT + (size_t)(2 + (l + 1) * 6) * 32768) : WT;
    k_svu<<<dim3(g32), dim3(256), 0, stream>>>(
        Sb, hSh, hSl, slotL + 5 * 32768, slotL + 2 * 32768, slotL + 3 * 32768,
        W1next, ln_b1 + (size_t)l * 128, btil + l * 128, deg, ln_a + l,
        ln_b2 + (size_t)l * 128, Pb, Qb, (l < 4) ? 1 : 0,
        WT + 32768, de_b1, de_a, de_w2, de_b2, out,
        (l == 4) ? 1 : 0, N);
  }
}

// Round 8
// 1321.769 us; speedup vs baseline: 1.0837x; 1.0044x over previous
//
#include <hip/hip_runtime.h>
#include <cstdint>
#include <cstddef>

// ---------------------------------------------------------------------------
// GNS model. R23 = R20 verbatim revert (verified best: 1327.6 us).
// Evidence log (final):
//  - k_edge: 128-edge tiles, R11 inner structure, lb(256,4). Latency floor:
//    survived R16 reg-pipeline (spilled, +3%), R17 LDS-DMA staging (spilled,
//    +3%), lb3->lb4 occupancy +33% (dur FLAT), epilogue restructure x2.
//    Counters: MfmaUtil 5%, VALUBusy 12%, HBM 8%, all pipes idle ->
//    distributed latency serialization, no single lever found.
//  - R21/R22 persistent cooperative mega-kernel: compile bug, then absmax
//    4.5e-3 ~= max|output| -> likely swallowed cooperative-launch error
//    under graph capture (or cross-XCD cache staleness, guide G16).
//    Dead end in this harness; reverted.
//  - R18/R19: node side 4-wave nt-split + full-grid residency = -63 us.
//  - R20 fusions: k_node_u inlined into k_enc; k_dec inlined into k_svu
//    (l=4) with planes_out skipped = -6 us + 2 fewer dispatches.
//  - P hoisted once per dst-run (+bvec folded); permuted-column C layout
//    (weight slots: output col n = p*8 + nt').
//  - All GEMMs split-bf16 MFMA (AhBh+AlBh+AhBl), edge-U hi-only.
// ---------------------------------------------------------------------------

#define DEVI static __device__ __forceinline__

typedef __bf16 bf16_t;
typedef bf16_t bf16x8 __attribute__((ext_vector_type(8)));
typedef bf16_t bf16x4 __attribute__((ext_vector_type(4)));
typedef float f32x4v __attribute__((ext_vector_type(4)));

DEVI float4 ld4(const float* p) { return *(const float4*)p; }
DEVI void st4(float* p, float4 v) { *(float4*)p = v; }
DEVI float prelu1(float z, float a) { return z > 0.f ? z : a * z; }
DEVI void atomicAddF(float* p, float v) {
  __hip_atomic_fetch_add(p, v, __ATOMIC_RELAXED, __HIP_MEMORY_SCOPE_AGENT);
}
DEVI f32x4v mfma_bf16(bf16x8 a, bf16x8 b, f32x4v c) {
  return __builtin_amdgcn_mfma_f32_16x16x32_bf16(a, b, c, 0, 0, 0);
}
DEVI void mfma3(f32x4v& acc, bf16x8 ah, bf16x8 al, bf16x8 bh, bf16x8 bl) {
  acc = mfma_bf16(ah, bh, acc);
  acc = mfma_bf16(al, bh, acc);
  acc = mfma_bf16(ah, bl, acc);
}
DEVI void split2(float x, bf16_t& h, bf16_t& l) {
  h = (bf16_t)x;
  l = (bf16_t)(x - (float)h);
}
DEVI bf16x8 ldb8(const bf16_t* p) { return *(const bf16x8*)p; }

#define NST 136   // node staging row stride (bf16)
#define EST 72    // edge staging row stride (bf16)

// ======== 4-wave node tile building blocks ================================
// wave (h = wave&1) owns rows h*16..h*16+15; (cH = wave>>1) owns col-half
// cH*64..cH*64+63 (column tiles nt' = cH*4 + nt, nt in 0..3).

DEVI void stage_f32_c4(const float* __restrict__ src, int row0, int M,
                       int lane, int h, int cH, bf16_t* SAh, bf16_t* SAl)
{
  const int row = h * 16 + (lane >> 2);
  const int grow = row0 + row;
  const int colbase = cH * 64 + (lane & 3) * 16;
  #pragma unroll
  for (int j = 0; j < 4; ++j) {
    int kc = colbase + j * 4;
    float4 v = make_float4(0.f, 0.f, 0.f, 0.f);
    if (grow < M) v = ld4(src + (size_t)grow * 128 + kc);
    bf16_t h0,l0,h1,l1,h2,l2,h3,l3;
    split2(v.x,h0,l0); split2(v.y,h1,l1); split2(v.z,h2,l2); split2(v.w,h3,l3);
    *(bf16x4*)(SAh + row * NST + kc) = (bf16x4){h0,h1,h2,h3};
    *(bf16x4*)(SAl + row * NST + kc) = (bf16x4){l0,l1,l2,l3};
  }
}

DEVI void stage_planes_c4(const bf16_t* __restrict__ gh, const bf16_t* __restrict__ gl,
                          int row0, int M, int lane, int h, int cH,
                          bf16_t* SAh, bf16_t* SAl)
{
  const int row = h * 16 + (lane >> 2);
  const int grow = row0 + row;
  const int colbase = cH * 64 + (lane & 3) * 16;
  #pragma unroll
  for (int j = 0; j < 2; ++j) {
    int kc = colbase + j * 8;
    bf16x8 vh = {};
    bf16x8 vl = {};
    if (grow < M) {
      vh = ldb8(gh + (size_t)grow * 128 + kc);
      vl = ldb8(gl + (size_t)grow * 128 + kc);
    }
    *(bf16x8*)(SAh + row * NST + kc) = vh;
    *(bf16x8*)(SAl + row * NST + kc) = vl;
  }
}

// acc[4] over column tiles ntb..ntb+3; A rows h*16..+15 (full K=128)
DEVI void gemm_c4(const bf16_t* SAh, const bf16_t* SAl,
                  const bf16_t* __restrict__ BT, f32x4v acc[4],
                  int h, int ntb, int p, int q)
{
  #pragma unroll
  for (int ks = 0; ks < 4; ++ks) {
    const int k0 = ks * 32 + q * 8;
    bf16x8 aH = ldb8(SAh + (h * 16 + p) * NST + k0);
    bf16x8 aL = ldb8(SAl + (h * 16 + p) * NST + k0);
    #pragma unroll
    for (int nt = 0; nt < 4; ++nt) {
      const bf16_t* bp = BT + (size_t)((ntb + nt) * 16 + p) * 128 + k0;
      mfma3(acc[nt], aH, aL, ldb8(bp), ldb8(bp + 16384));
    }
  }
}

DEVI void store_c4(float* __restrict__ O, int row0, int M,
                   const f32x4v acc[4], int h, int cH, int p, int q)
{
  int rb = row0 + h * 16 + q * 4;
  #pragma unroll
  for (int r = 0; r < 4; ++r) {
    if (rb + r < M) {
      float* op = O + (size_t)(rb + r) * 128 + p * 8 + cH * 4;
      st4(op, make_float4(acc[0][r], acc[1][r], acc[2][r], acc[3][r]));
    }
  }
}

DEVI void stage_cregs_c4(const f32x4v acc[4], int h, int cH, int p, int q,
                         bf16_t* SAh, bf16_t* SAl)
{
  #pragma unroll
  for (int r = 0; r < 4; ++r) {
    int row = h * 16 + q * 4 + r;
    bf16x4 vh, vl;
    #pragma unroll
    for (int nt = 0; nt < 4; ++nt) {
      bf16_t hb, lb;
      split2(acc[nt][r], hb, lb);
      vh[nt] = hb; vl[nt] = lb;
    }
    *(bf16x4*)(SAh + row * NST + p * 8 + cH * 4) = vh;
    *(bf16x4*)(SAl + row * NST + p * 8 + cH * 4) = vl;
  }
}

DEVI void planes_out_c4(bf16_t* __restrict__ gh, bf16_t* __restrict__ gl,
                        int row0, int M, int lane, int h, int cH,
                        const bf16_t* SAh, const bf16_t* SAl)
{
  const int row = h * 16 + (lane >> 2);
  const int grow = row0 + row;
  const int colbase = cH * 64 + (lane & 3) * 16;
  if (grow < M) {
    #pragma unroll
    for (int j = 0; j < 2; ++j) {
      int kc = colbase + j * 8;
      *(bf16x8*)(gh + (size_t)grow * 128 + kc) = *(const bf16x8*)(SAh + row * NST + kc);
      *(bf16x8*)(gl + (size_t)grow * 128 + kc) = *(const bf16x8*)(SAl + row * NST + kc);
    }
  }
}

DEVI void ld8f(float dst[8], const float* __restrict__ src, int p) {
  *(float4*)(dst)     = ld4(src + p * 8);
  *(float4*)(dst + 4) = ld4(src + p * 8 + 4);
}

DEVI void ld4f(float dst[4], const float* __restrict__ src, int p, int cH) {
  *(float4*)(dst) = ld4(src + p * 8 + cH * 4);
}

// ---------------------------------------------------------------------------
// k_svu: 256 thr / 32-row tiles, 4 waves. Node update + P/Q for next layer;
// zeroes consumed S rows. l=4 (doDec): decoder fused from LDS h_new,
// planes_out skipped (h planes have no consumer after decode).
// ---------------------------------------------------------------------------
__global__ __launch_bounds__(256, 3) void k_svu(
    float* Sbuf,                      // read then zeroed (same buffer)
    bf16_t* __restrict__ hSh, bf16_t* __restrict__ hSl,
    const bf16_t* __restrict__ WtilT, const bf16_t* __restrict__ Wn1aT,
    const bf16_t* __restrict__ lnw2T, const bf16_t* __restrict__ W1nextT,
    const float* __restrict__ ln_b1_l, const float* __restrict__ btil_l,
    const int* __restrict__ deg, const float* __restrict__ ln_a_l,
    const float* __restrict__ ln_b2_l,
    float* __restrict__ P, float* __restrict__ Q, int doPQ,
    const bf16_t* __restrict__ dw1T, const float* __restrict__ de_b1,
    const float* __restrict__ de_a, const float* __restrict__ de_w2,
    const float* __restrict__ de_b2, float* __restrict__ outp,
    int doDec, int M)
{
  // SA planes; Cs (dec C-tile, 32x132 f32 = 16896 B) overlays them after
  // the dec GEMM has consumed h_new.
  __shared__ __align__(16) char SMEM[2 * 32 * NST * 2];   // 17408 B
  __shared__ __align__(16) float w2s[384];
  bf16_t* SAh = (bf16_t*)SMEM;
  bf16_t* SAl = (bf16_t*)(SMEM + 32 * NST * 2);
  float*  Cs  = (float*)SMEM;

  const int t = threadIdx.x, lane = t & 63, wave = t >> 6;
  const int h = wave & 1, cH = wave >> 1;
  const int p = lane & 15, q = lane >> 4;
  const int row0 = blockIdx.x * 32;

  f32x4v acc1[4];
  #pragma unroll
  for (int j = 0; j < 4; ++j) acc1[j] = (f32x4v){0.f, 0.f, 0.f, 0.f};

  stage_f32_c4(Sbuf, row0, M, lane, h, cH, SAh, SAl);
  // zero consumed S cells (per-lane same addresses as the loads -> ordered)
  {
    const int row = h * 16 + (lane >> 2);
    const int grow = row0 + row;
    const int colbase = cH * 64 + (lane & 3) * 16;
    if (grow < M) {
      float4 z4 = make_float4(0.f, 0.f, 0.f, 0.f);
      #pragma unroll
      for (int j = 0; j < 4; ++j)
        st4(Sbuf + (size_t)grow * 128 + colbase + j * 4, z4);
    }
  }
  __syncthreads();                       // S tile complete
  gemm_c4(SAh, SAl, WtilT, acc1, h, cH * 4, p, q);
  __syncthreads();                       // all S reads done before h overwrite
  stage_planes_c4(hSh, hSl, row0, M, lane, h, cH, SAh, SAl);
  __syncthreads();                       // h tile complete
  gemm_c4(SAh, SAl, Wn1aT, acc1, h, cH * 4, p, q);

  // h_old (feature-linear layout) from LDS — this wave's 4 cols
  float hold[4][4];
  #pragma unroll
  for (int r = 0; r < 4; ++r) {
    int row = h * 16 + q * 4 + r;
    bf16x4 vh = *(const bf16x4*)(SAh + row * NST + p * 8 + cH * 4);
    bf16x4 vl = *(const bf16x4*)(SAl + row * NST + p * 8 + cH * 4);
    #pragma unroll
    for (int nt = 0; nt < 4; ++nt)
      hold[nt][r] = (float)vh[nt] + (float)vl[nt];
  }
  __syncthreads();                       // all h reads done before V overwrite

  // V = prelu(acc1 + b1 + deg*btil)
  const float alpha = *ln_a_l;
  float degf[4];
  #pragma unroll
  for (int r = 0; r < 4; ++r) {
    int row = row0 + h * 16 + q * 4 + r;
    degf[r] = (row < M) ? (float)deg[row] : 0.f;
  }
  float b1c[4], btc[4];
  ld4f(b1c, ln_b1_l, p, cH);
  ld4f(btc, btil_l, p, cH);
  #pragma unroll
  for (int nt = 0; nt < 4; ++nt)
    #pragma unroll
    for (int r = 0; r < 4; ++r)
      acc1[nt][r] = prelu1(acc1[nt][r] + b1c[nt] + degf[r] * btc[nt], alpha);

  stage_cregs_c4(acc1, h, cH, p, q, SAh, SAl);   // V
  __syncthreads();                       // V tile complete
  f32x4v acc2[4];
  #pragma unroll
  for (int j = 0; j < 4; ++j) acc2[j] = (f32x4v){0.f, 0.f, 0.f, 0.f};
  gemm_c4(SAh, SAl, lnw2T, acc2, h, cH * 4, p, q);
  __syncthreads();                       // all V reads done before h_new overwrite

  // h_new = h_old + acc2 + b2
  float b2c[4];
  ld4f(b2c, ln_b2_l, p, cH);
  #pragma unroll
  for (int nt = 0; nt < 4; ++nt)
    #pragma unroll
    for (int r = 0; r < 4; ++r)
      acc2[nt][r] = hold[nt][r] + acc2[nt][r] + b2c[nt];

  stage_cregs_c4(acc2, h, cH, p, q, SAh, SAl);   // h_new

  if (doDec) {
    // ---- fused decoder (l=4): h1 = prelu(h_new@de_w1 + b1); out = h1@de_w2+b2
    if (t < 128) {
      w2s[t] = de_w2[t]; w2s[t + 128] = de_w2[t + 128]; w2s[t + 256] = de_w2[t + 256];
    }
    __syncthreads();                     // h_new tile complete (+ w2s staged)
    f32x4v acc3[4];
    #pragma unroll
    for (int j = 0; j < 4; ++j) acc3[j] = (f32x4v){0.f, 0.f, 0.f, 0.f};
    gemm_c4(SAh, SAl, dw1T, acc3, h, cH * 4, p, q);
    const float da = *de_a;
    float db1[4];
    ld4f(db1, de_b1, p, cH);
    #pragma unroll
    for (int nt = 0; nt < 4; ++nt)
      #pragma unroll
      for (int r = 0; r < 4; ++r)
        acc3[nt][r] = prelu1(acc3[nt][r] + db1[nt], da);
    __syncthreads();                     // all SA reads done before Cs overlay
    #pragma unroll
    for (int r = 0; r < 4; ++r) {
      int row = h * 16 + q * 4 + r;
      st4(&Cs[row * 132 + p * 8 + cH * 4],
          make_float4(acc3[0][r], acc3[1][r], acc3[2][r], acc3[3][r]));
    }
    __syncthreads();                     // Cs complete
    if (t < 32) {
      float s0 = de_b2[0], s1 = de_b2[1], s2 = de_b2[2];
      for (int k = 0; k < 128; ++k) {
        float vv = Cs[t * 132 + k];
        s0 = fmaf(vv, w2s[k * 3 + 0], s0);
        s1 = fmaf(vv, w2s[k * 3 + 1], s1);
        s2 = fmaf(vv, w2s[k * 3 + 2], s2);
      }
      int row = row0 + t;
      if (row < M) {
        outp[(size_t)row * 3 + 0] = s0;
        outp[(size_t)row * 3 + 1] = s1;
        outp[(size_t)row * 3 + 2] = s2;
      }
    }
    return;
  }

  __syncthreads();                       // h_new tile complete
  planes_out_c4(hSh, hSl, row0, M, lane, h, cH, SAh, SAl);

  if (doPQ) {
    f32x4v acc3[4];
    #pragma unroll
    for (int j = 0; j < 4; ++j) acc3[j] = (f32x4v){0.f, 0.f, 0.f, 0.f};
    gemm_c4(SAh, SAl, W1nextT, acc3, h, cH * 4, p, q);
    store_c4(P, row0, M, acc3, h, cH, p, q);
    #pragma unroll
    for (int j = 0; j < 4; ++j) acc3[j] = (f32x4v){0.f, 0.f, 0.f, 0.f};
    gemm_c4(SAh, SAl, W1nextT + 32768, acc3, h, cH * 4, p, q);
    store_c4(Q, row0, M, acc3, h, cH, p, q);
  }
}

// ---------------------------------------------------------------------------
// k_enc: 256 thr / 32-row tiles, 4 waves, lb(256,3). Fused node encoder:
// UN = prelu(x@ne_w1+b1) computed inline (LDS-staged x rows + ne_w1),
// h0 = UN@ne_w2 + b2 -> planes; + P/Q layer 0.
// ---------------------------------------------------------------------------
__global__ __launch_bounds__(256, 3) void k_enc(
    const float* __restrict__ x, const float* __restrict__ ne_w1,
    const float* __restrict__ ne_b1, const float* __restrict__ ne_a,
    const bf16_t* __restrict__ new2T,
    const float* __restrict__ b2, const bf16_t* __restrict__ W1T0,
    bf16_t* __restrict__ hSh, bf16_t* __restrict__ hSl,
    float* __restrict__ P, float* __restrict__ Q, int M)
{
  __shared__ __align__(16) bf16_t SAh[32 * NST];
  __shared__ __align__(16) bf16_t SAl[32 * NST];
  __shared__ __align__(16) float w1s[30 * 128];   // 15 KB
  __shared__ __align__(16) float xs[32 * 30];     // 3.75 KB
  __shared__ __align__(16) float b1s[128];
  const int t = threadIdx.x, lane = t & 63, wave = t >> 6;
  const int h = wave & 1, cH = wave >> 1;
  const int p = lane & 15, q = lane >> 4;
  const int row0 = blockIdx.x * 32;

  // stage ne_w1 / x rows / b1
  for (int i = t; i < 30 * 128; i += 256) w1s[i] = ne_w1[i];
  {
    int nrow = M - row0; if (nrow > 32) nrow = 32;
    int cnt = nrow * 30;
    for (int i = t; i < cnt; i += 256) xs[i] = x[(size_t)row0 * 30 + i];
  }
  if (t < 128) b1s[t] = ne_b1[t];
  __syncthreads();
  const float ua = *ne_a;

  // compute this thread's staged UN cells: row = h*16+(lane>>2), 16 cols
  {
    const int row = h * 16 + (lane >> 2);
    const int grow = row0 + row;
    const int colbase = cH * 64 + (lane & 3) * 16;
    #pragma unroll
    for (int jj = 0; jj < 4; ++jj) {
      int kc = colbase + jj * 4;
      float z0 = 0.f, z1 = 0.f, z2 = 0.f, z3 = 0.f;
      if (grow < M) {
        float4 bb = ld4(b1s + kc);
        z0 = bb.x; z1 = bb.y; z2 = bb.z; z3 = bb.w;
        #pragma unroll
        for (int j = 0; j < 30; ++j) {
          float xv = xs[row * 30 + j];
          float4 wv = ld4(w1s + j * 128 + kc);
          z0 = fmaf(xv, wv.x, z0); z1 = fmaf(xv, wv.y, z1);
          z2 = fmaf(xv, wv.z, z2); z3 = fmaf(xv, wv.w, z3);
        }
        z0 = prelu1(z0, ua); z1 = prelu1(z1, ua);
        z2 = prelu1(z2, ua); z3 = prelu1(z3, ua);
      }
      bf16_t h0,l0,h1,l1,h2,l2,h3,l3;
      split2(z0,h0,l0); split2(z1,h1,l1); split2(z2,h2,l2); split2(z3,h3,l3);
      *(bf16x4*)(SAh + row * NST + kc) = (bf16x4){h0,h1,h2,h3};
      *(bf16x4*)(SAl + row * NST + kc) = (bf16x4){l0,l1,l2,l3};
    }
  }
  __syncthreads();                       // UN tile complete

  f32x4v acc[4];
  #pragma unroll
  for (int j = 0; j < 4; ++j) acc[j] = (f32x4v){0.f, 0.f, 0.f, 0.f};
  gemm_c4(SAh, SAl, new2T, acc, h, cH * 4, p, q);
  __syncthreads();                       // all UN reads done before h0 overwrite
  float b2c[4];
  ld4f(b2c, b2, p, cH);
  #pragma unroll
  for (int nt = 0; nt < 4; ++nt)
    #pragma unroll
    for (int r = 0; r < 4; ++r) acc[nt][r] += b2c[nt];
  stage_cregs_c4(acc, h, cH, p, q, SAh, SAl);
  __syncthreads();                       // h0 tile complete
  planes_out_c4(hSh, hSl, row0, M, lane, h, cH, SAh, SAl);

  f32x4v acc3[4];
  #pragma unroll
  for (int j = 0; j < 4; ++j) acc3[j] = (f32x4v){0.f, 0.f, 0.f, 0.f};
  gemm_c4(SAh, SAl, W1T0, acc3, h, cH * 4, p, q);
  store_c4(P, row0, M, acc3, h, cH, p, q);
  #pragma unroll
  for (int j = 0; j < 4; ++j) acc3[j] = (f32x4v){0.f, 0.f, 0.f, 0.f};
  gemm_c4(SAh, SAl, W1T0 + 32768, acc3, h, cH * 4, p, q);
  store_c4(Q, row0, M, acc3, h, cH, p, q);
}

// ---------------------------------------------------------------------------
// k_edge: 128-edge tiles, lb(256,4), inline gathers, 32-row LDS S-tile.
// Inner structure = R11 verbatim. DO NOT TOUCH (see evidence log).
// ---------------------------------------------------------------------------
__global__ __launch_bounds__(256, 4) void k_edge(
    const float* __restrict__ sEa, const int* __restrict__ sSrc,
    const int* __restrict__ sDst,
    const int* __restrict__ rowStart, const int* __restrict__ deg,
    const float* __restrict__ ee_w1, const float* __restrict__ ee_b1,
    const float* __restrict__ ee_a,
    const bf16_t* __restrict__ WhatT, const float* __restrict__ bvec,
    const float* __restrict__ alpha_ptr,
    const float* __restrict__ P, const float* __restrict__ Q,
    float* __restrict__ S, int N, int E)
{
  __shared__ __align__(16) float Stile[32 * 132];     // 16.9 KB
  __shared__ __align__(16) float ew[640];             // ee_w1 + ee_b1
  __shared__ __align__(16) bf16_t Ast[128 * EST];     // 18.4 KB

  const int t = threadIdx.x, lane = t & 63, wave = t >> 6;
  const int p = lane & 15, q = lane >> 4;
  const int e0 = blockIdx.x * 128;
  const int dstLo = sDst[e0];

  for (int i = t; i < 640; i += 256)
    ew[i] = (i < 512) ? ee_w1[i] : ee_b1[i - 512];
  for (int i = t; i < 32 * 132; i += 256) Stile[i] = 0.f;
  __syncthreads();

  const float ua = *ee_a;
  const float alpha = *alpha_ptr;
  float bvc[8];
  ld8f(bvc, bvec, p);

  const int srow = wave * 32 + (lane >> 1);
  const int scb = (lane & 1) * 32;
  float4 eav = make_float4(0.f, 0.f, 0.f, 0.f);
  {
    int ed = e0 + srow;
    if (ed < E) eav = ld4(sEa + (size_t)ed * 4);
  }

  f32x4v acc[2][8];
  #pragma unroll
  for (int i = 0; i < 2; ++i)
    #pragma unroll
    for (int j = 0; j < 8; ++j) acc[i][j] = (f32x4v){0.f, 0.f, 0.f, 0.f};

  for (int c = 0; c < 2; ++c) {
    // stage U chunk (bf16-hi only), wave-private rows -> no barrier
    #pragma unroll
    for (int j = 0; j < 8; ++j) {
      int kc = scb + j * 4;
      int kg = c * 64 + kc;
      float4 w0 = ld4(ew + kg);
      float4 w1 = ld4(ew + 128 + kg);
      float4 w2 = ld4(ew + 256 + kg);
      float4 w3 = ld4(ew + 384 + kg);
      float4 bb = ld4(ew + 512 + kg);
      float ux = bb.x, uy = bb.y, uz = bb.z, uw = bb.w;
      ux = fmaf(eav.x, w0.x, ux); uy = fmaf(eav.x, w0.y, uy);
      uz = fmaf(eav.x, w0.z, uz); uw = fmaf(eav.x, w0.w, uw);
      ux = fmaf(eav.y, w1.x, ux); uy = fmaf(eav.y, w1.y, uy);
      uz = fmaf(eav.y, w1.z, uz); uw = fmaf(eav.y, w1.w, uw);
      ux = fmaf(eav.z, w2.x, ux); uy = fmaf(eav.z, w2.y, uy);
      uz = fmaf(eav.z, w2.z, uz); uw = fmaf(eav.z, w2.w, uw);
      ux = fmaf(eav.w, w3.x, ux); uy = fmaf(eav.w, w3.y, uy);
      uz = fmaf(eav.w, w3.z, uz); uw = fmaf(eav.w, w3.w, uw);
      *(bf16x4*)(Ast + srow * EST + kc) = (bf16x4){
          (bf16_t)prelu1(ux, ua), (bf16_t)prelu1(uy, ua),
          (bf16_t)prelu1(uz, ua), (bf16_t)prelu1(uw, ua)};
    }
    #pragma unroll
    for (int ks = 0; ks < 2; ++ks) {
      const int k0 = ks * 32 + q * 8;
      const int kg = c * 64 + k0;
      bf16x8 aH0 = ldb8(Ast + (wave * 32 + p) * EST + k0);
      bf16x8 aH1 = ldb8(Ast + (wave * 32 + 16 + p) * EST + k0);
      #pragma unroll
      for (int nt = 0; nt < 8; ++nt) {
        const bf16_t* bp = WhatT + (size_t)(nt * 16 + p) * 128 + kg;
        bf16x8 bH = ldb8(bp);
        bf16x8 bL = ldb8(bp + 16384);
        acc[0][nt] = mfma_bf16(aH0, bH, acc[0][nt]);
        acc[0][nt] = mfma_bf16(aH0, bL, acc[0][nt]);
        acc[1][nt] = mfma_bf16(aH1, bH, acc[1][nt]);
        acc[1][nt] = mfma_bf16(aH1, bL, acc[1][nt]);
      }
    }
  }

  // epilogue: run-reduce; indices loaded inline; P once per run (+bvec)
  #pragma unroll
  for (int mt = 0; mt < 2; ++mt) {
    float rs[8];
    #pragma unroll
    for (int nt = 0; nt < 8; ++nt) rs[nt] = 0.f;
    int curd = -1;
    float pv[8];
    #pragma unroll
    for (int nt = 0; nt < 8; ++nt) pv[nt] = 0.f;
    #pragma unroll
    for (int r = 0; r < 4; ++r) {
      int ed = e0 + wave * 32 + mt * 16 + q * 4 + r;
      if (ed < E) {
        int d = sDst[ed];
        int s = sSrc[ed];
        if (d != curd) {
          if (curd >= 0) {
            int rr = curd - dstLo;
            if (rr < 32) {
              #pragma unroll
              for (int nt = 0; nt < 8; ++nt)
                atomicAdd(&Stile[rr * 132 + p * 8 + nt], rs[nt]);
            } else {
              #pragma unroll
              for (int nt = 0; nt < 8; ++nt)
                atomicAddF(S + (size_t)curd * 128 + p * 8 + nt, rs[nt]);
            }
            #pragma unroll
            for (int nt = 0; nt < 8; ++nt) rs[nt] = 0.f;
          }
          curd = d;
          ld8f(pv, P + (size_t)d * 128, p);
          #pragma unroll
          for (int nt = 0; nt < 8; ++nt) pv[nt] += bvc[nt];
        }
        float qv[8];
        ld8f(qv, Q + (size_t)s * 128, p);
        #pragma unroll
        for (int nt = 0; nt < 8; ++nt) {
          float z = acc[mt][nt][r] + pv[nt] + qv[nt];
          rs[nt] += prelu1(z, alpha);
        }
      }
    }
    if (curd >= 0) {
      int rr = curd - dstLo;
      if (rr < 32) {
        #pragma unroll
        for (int nt = 0; nt < 8; ++nt)
          atomicAdd(&Stile[rr * 132 + p * 8 + nt], rs[nt]);
      } else {
        #pragma unroll
        for (int nt = 0; nt < 8; ++nt)
          atomicAddF(S + (size_t)curd * 128 + p * 8 + nt, rs[nt]);
      }
    }
  }
  __syncthreads();

  // writeback: interior rows plain-stored, boundary rows atomic
  const int lastE = (e0 + 127 < E) ? (e0 + 127) : (E - 1);
  const int dstHi = sDst[lastE];
  const int col4 = (t & 31) * 4;
  #pragma unroll
  for (int rr0 = 0; rr0 < 32; rr0 += 8) {
    int rr = rr0 + (t >> 5);
    int d = dstLo + rr;
    if (d <= dstHi && d < N) {
      float4 v = ld4(&Stile[rr * 132 + col4]);
      bool interior = (rowStart[d] >= e0) && (rowStart[d] + deg[d] <= e0 + 128);
      float* sp = S + (size_t)d * 128 + col4;
      if (interior) {
        st4(sp, v);
      } else {
        atomicAddF(sp + 0, v.x); atomicAddF(sp + 1, v.y);
        atomicAddF(sp + 2, v.z); atomicAddF(sp + 3, v.w);
      }
    }
  }
}

// --------- weight prep: transpose+split with PERMUTED col mapping -----------
__global__ __launch_bounds__(256) void k_tsplit(
    const float* __restrict__ ne_w2, const float* __restrict__ de_w1,
    const float* __restrict__ le_w1, const float* __restrict__ ln_w1,
    const float* __restrict__ ln_w2, bf16_t* __restrict__ WT)
{
  int jid = blockIdx.x;
  const float* src; int slot;
  if (jid == 0)      { src = ne_w2; slot = 0; }
  else if (jid == 1) { src = de_w1; slot = 1; }
  else {
    int l = (jid - 2) >> 2, wj = (jid - 2) & 3;
    slot = 2 + l * 6 + wj;
    src = (wj == 0) ? le_w1 + (size_t)l * 49152
        : (wj == 1) ? le_w1 + (size_t)l * 49152 + 16384
        : (wj == 2) ? ln_w1 + (size_t)l * 32768
                    : ln_w2 + (size_t)l * 16384;
  }
  bf16_t* oh = WT + (size_t)slot * 32768;
  bf16_t* ol = oh + 16384;
  const int base = blockIdx.y * 2048;
  for (int idx = base + threadIdx.x; idx < base + 2048; idx += 256) {
    int k = idx >> 7, n = idx & 127;
    bf16_t hb, lb;
    split2(src[idx], hb, lb);
    int pos = ((n & 7) * 16 + (n >> 3)) * 128 + k;
    oh[pos] = hb;
    ol[pos] = lb;
  }
}

__global__ __launch_bounds__(256) void k_fold(
    const float* __restrict__ ee_w2, const float* __restrict__ ee_b2,
    const float* __restrict__ le_w1, const float* __restrict__ le_b1,
    const float* __restrict__ le_w2, const float* __restrict__ le_b2,
    const float* __restrict__ ln_w1,
    bf16_t* __restrict__ WT, float* __restrict__ bvec, float* __restrict__ btil)
{
  const int l = blockIdx.x;
  const int which = blockIdx.y;
  const int z = blockIdx.z;
  const float* L; const float* Rm; const float* lb; const float* badd;
  int slot; float* bout;
  if (which == 0) {
    L = ee_w2; Rm = le_w1 + (size_t)l * 49152 + 256 * 128;
    lb = ee_b2; badd = le_b1 + l * 128;
    slot = 2 + l * 6 + 4; bout = bvec + l * 128;
  } else {
    L = le_w2 + (size_t)l * 16384; Rm = ln_w1 + (size_t)l * 32768 + 128 * 128;
    lb = le_b2 + l * 128; badd = nullptr;
    slot = 2 + l * 6 + 5; bout = btil + l * 128;
  }
  bf16_t* oh = WT + (size_t)slot * 32768;
  bf16_t* ol = oh + 16384;
  const int t = threadIdx.x;
  const int base = z * 512;
  for (int eidx = base + t; eidx < base + 512; eidx += 256) {
    int k = eidx >> 7, n = eidx & 127;
    float a = 0.f;
    for (int d = 0; d < 128; d += 4) {
      float4 lv = ld4(L + k * 128 + d);
      a = fmaf(lv.x, Rm[(d + 0) * 128 + n], a);
      a = fmaf(lv.y, Rm[(d + 1) * 128 + n], a);
      a = fmaf(lv.z, Rm[(d + 2) * 128 + n], a);
      a = fmaf(lv.w, Rm[(d + 3) * 128 + n], a);
    }
    bf16_t hb, lbv;
    split2(a, hb, lbv);
    int pos = ((n & 7) * 16 + (n >> 3)) * 128 + k;
    oh[pos] = hb;
    ol[pos] = lbv;
  }
  if (z == 0 && t < 128) {
    float a = badd ? badd[t] : 0.f;
    for (int d = 0; d < 128; ++d) a = fmaf(lb[d], Rm[d * 128 + t], a);
    bout[t] = a;
  }
}

// --------- counting sort by dst ---------------------------------------------
__global__ void k_hist(const int* __restrict__ dstIdx, int* __restrict__ deg, int E) {
  int i = blockIdx.x * 256 + threadIdx.x;
  if (i < E) atomicAdd(deg + dstIdx[i], 1);
}

__global__ __launch_bounds__(1024) void k_scan(
    const int* __restrict__ deg, int* __restrict__ cursor,
    int* __restrict__ rowStart, int N, int per)
{
  __shared__ int part[1024];
  const int t = threadIdx.x;
  const int base = t * per;
  int local = 0;
  for (int i = 0; i < per; ++i) {
    int idx = base + i;
    if (idx < N) local += deg[idx];
  }
  part[t] = local;
  __syncthreads();
  for (int off = 1; off < 1024; off <<= 1) {
    int v = (t >= off) ? part[t - off] : 0;
    __syncthreads();
    part[t] += v;
    __syncthreads();
  }
  int run = (t == 0) ? 0 : part[t - 1];
  for (int i = 0; i < per; ++i) {
    int idx = base + i;
    if (idx < N) {
      cursor[idx] = run;
      rowStart[idx] = run;
      run += deg[idx];
    }
  }
}

__global__ void k_scatter(const int* __restrict__ srcIdx, const int* __restrict__ dstIdx,
                          const float* __restrict__ ea, int* __restrict__ cursor,
                          int* __restrict__ sSrc, int* __restrict__ sDst,
                          float* __restrict__ sEa, int E)
{
  int e = blockIdx.x * 256 + threadIdx.x;
  if (e < E) {
    int d = dstIdx[e];
    int p = atomicAdd(cursor + d, 1);
    sSrc[p] = srcIdx[e];
    sDst[p] = d;
    st4(sEa + (size_t)p * 4, ld4(ea + (size_t)e * 4));
  }
}

// ---------------------------------------------------------------------------
extern "C" void kernel_launch(void* const* d_in, const int* in_sizes, int n_in,
                              void* d_out, int out_size, void* d_ws, size_t ws_size,
                              hipStream_t stream)
{
  const float* x     = (const float*)d_in[0];
  const float* ea    = (const float*)d_in[1];
  const int*   ei    = (const int*)  d_in[2];
  const float* ne_w1 = (const float*)d_in[3];
  const float* ne_b1 = (const float*)d_in[4];
  const float* ne_a  = (const float*)d_in[5];
  const float* ne_w2 = (const float*)d_in[6];
  const float* ne_b2 = (const float*)d_in[7];
  const float* ee_w1 = (const float*)d_in[8];
  const float* ee_b1 = (const float*)d_in[9];
  const float* ee_a  = (const float*)d_in[10];
  const float* ee_w2 = (const float*)d_in[11];
  const float* ee_b2 = (const float*)d_in[12];
  const float* le_w1 = (const float*)d_in[13];
  const float* le_b1 = (const float*)d_in[14];
  const float* le_a  = (const float*)d_in[15];
  const float* le_w2 = (const float*)d_in[16];
  const float* le_b2 = (const float*)d_in[17];
  const float* ln_w1 = (const float*)d_in[18];
  const float* ln_b1 = (const float*)d_in[19];
  const float* ln_a  = (const float*)d_in[20];
  const float* ln_w2 = (const float*)d_in[21];
  const float* ln_b2 = (const float*)d_in[22];
  const float* de_w1 = (const float*)d_in[23];
  const float* de_b1 = (const float*)d_in[24];
  const float* de_a  = (const float*)d_in[25];
  const float* de_w2 = (const float*)d_in[26];
  const float* de_b2 = (const float*)d_in[27];

  const int N = in_sizes[0] / 30;
  const int E = in_sizes[1] / 4;
  const int* srcIdx = ei;        // edge_index[0] = x_j (source)
  const int* dstIdx = ei + E;    // edge_index[1] = x_i (target / agg index)

  const int g32 = (N + 31) / 32;        // node tiles
  const int gE  = (E + 127) / 128;      // 128-edge tiles
  const int Np = g32 * 32;
  const size_t NNp = (size_t)Np * 128;

  float* w = (float*)d_ws;
  float* Pb   = w; w += NNp;
  float* Qb   = w; w += NNp;
  float* Sb   = w; w += NNp;
  float* bvec = w; w += 5 * 128;
  float* btil = w; w += 5 * 128;
  float* sEa  = w; w += (size_t)E * 4;
  bf16_t* hSh = (bf16_t*)w;
  bf16_t* hSl = hSh + NNp;  w += NNp;      // 2 bf16 planes
  bf16_t* WT  = (bf16_t*)w; w += 32 * 32768 / 2;
  int* ip     = (int*)w;
  int* deg    = ip; ip += N;
  int* cursor = ip; ip += N;
  int* rowStart = ip; ip += N;
  int* sSrc   = ip; ip += E;
  int* sDst   = ip; ip += E;

  float* out = (float*)d_out;

  // weight prep + sort
  k_tsplit<<<dim3(22, 8), dim3(256), 0, stream>>>(ne_w2, de_w1, le_w1, ln_w1, ln_w2, WT);
  k_fold<<<dim3(5, 2, 32), dim3(256), 0, stream>>>(ee_w2, ee_b2, le_w1, le_b1,
                                                   le_w2, le_b2, ln_w1, WT, bvec, btil);
  (void)hipMemsetAsync(deg, 0, (size_t)N * 4, stream);
  k_hist<<<dim3((E + 255) / 256), dim3(256), 0, stream>>>(dstIdx, deg, E);
  k_scan<<<dim3(1), dim3(1024), 0, stream>>>(deg, cursor, rowStart, N,
                                             (N + 1023) / 1024);
  k_scatter<<<dim3((E + 255) / 256), dim3(256), 0, stream>>>(
      srcIdx, dstIdx, ea, cursor, sSrc, sDst, sEa, E);

  // fused encoder (node MLP1 inline) + P/Q for layer 0
  k_enc<<<dim3(g32), dim3(256), 0, stream>>>(x, ne_w1, ne_b1, ne_a,
                                             WT, ne_b2, WT + 2 * 32768,
                                             hSh, hSl, Pb, Qb, N);

  // one-time zero of S (k_svu keeps it zeroed thereafter)
  (void)hipMemsetAsync(Sb, 0, (size_t)N * 128 * 4, stream);

  for (int l = 0; l < 5; ++l) {
    const bf16_t* slotL = WT + (size_t)(2 + l * 6) * 32768;
    k_edge<<<dim3(gE), dim3(256), 0, stream>>>(
        sEa, sSrc, sDst, rowStart, deg, ee_w1, ee_b1, ee_a,
        slotL + 4 * 32768, bvec + l * 128, le_a + l, Pb, Qb, Sb, N, E);
    const bf16_t* W1next = (l < 4) ? (WT + (size_t)(2 + (l + 1) * 6) * 32768) : WT;
    k_svu<<<dim3(g32), dim3(256), 0, stream>>>(
        Sb, hSh, hSl, slotL + 5 * 32768, slotL + 2 * 32768, slotL + 3 * 32768,
        W1next, ln_b1 + (size_t)l * 128, btil + l * 128, deg, ln_a + l,
        ln_b2 + (size_t)l * 128, Pb, Qb, (l < 4) ? 1 : 0,
        WT + 32768, de_b1, de_a, de_w2, de_b2, out,
        (l == 4) ? 1 : 0, N);
  }
}